// Round 8
// baseline (1440.691 us; speedup 1.0000x reference)
//
#include <hip/hip_runtime.h>

#define DEVFN static __device__ __forceinline__

typedef __attribute__((ext_vector_type(8))) short short8;
typedef __attribute__((ext_vector_type(4))) float f32x4;

// ---------- bf16 helpers (raw ushort storage) ----------
DEVFN unsigned short f2bf(float f) {
    union { float f; unsigned u; } a; a.f = f;
    unsigned u = a.u;
    unsigned r = (u + 0x7FFFu + ((u >> 16) & 1u)) >> 16;   // RNE
    return (unsigned short)r;
}
DEVFN float bf2f(unsigned short b) {
    union { unsigned u; float f; } a; a.u = ((unsigned)b) << 16;
    return a.f;
}
DEVFN float2 bfpair(unsigned v) {
    float2 r;
    union { unsigned u; float f; } a;
    a.u = (v & 0xFFFFu) << 16; r.x = a.f;
    a.u = v & 0xFFFF0000u;     r.y = a.f;
    return r;
}

// ---------- async global->LDS (16B per lane, wave-uniform LDS base) ----------
DEVFN void gload16(const void* g, void* lds) {
    __builtin_amdgcn_global_load_lds(
        (const __attribute__((address_space(1))) unsigned int*)g,
        (__attribute__((address_space(3))) unsigned int*)lds, 16, 0, 0);
}

#define SB0() __builtin_amdgcn_sched_barrier(0)
#define PH_BARRIER() do { SB0(); __builtin_amdgcn_s_barrier(); SB0(); } while (0)
#define VMCNT8() do { asm volatile("s_waitcnt vmcnt(8)" ::: "memory"); SB0(); } while (0)
#define VMCNT0() do { asm volatile("s_waitcnt vmcnt(0)" ::: "memory"); SB0(); } while (0)

// ---------- prep: xs = [x | rwkv] cast bf16 ----------
__global__ __launch_bounds__(256) void pack_xs_kernel(
        const float* __restrict__ x, const float* __restrict__ r,
        unsigned short* __restrict__ xs) {
    int i = blockIdx.x * 256 + threadIdx.x;
    int n  = i >> 10;
    int cw = i & 1023;
    const float* src = (cw < 512) ? (x + (size_t)n * 2048 + cw * 4)
                                  : (r + (size_t)n * 2048 + (cw - 512) * 4);
    float4 v = *(const float4*)src;
    ushort4 o;
    o.x = f2bf(v.x); o.y = f2bf(v.y); o.z = f2bf(v.z); o.w = f2bf(v.w);
    *(ushort4*)(xs + (size_t)n * 4096 + cw * 4) = o;
}

// ---------- prep: transpose + cast fp32[R][Cc] -> bf16[Cc][R] ----------
__global__ __launch_bounds__(256) void transpose_cast_kernel(
        const float* __restrict__ in, unsigned short* __restrict__ out,
        int R, int Cc) {
    __shared__ float tile[32][33];
    int tx = threadIdx.x & 31, ty = threadIdx.x >> 5;
    int tr = blockIdx.y * 32, tc = blockIdx.x * 32;
#pragma unroll
    for (int i = 0; i < 4; i++) {
        int rr = ty + i * 8;
        tile[rr][tx] = in[(size_t)(tr + rr) * Cc + tc + tx];
    }
    __syncthreads();
#pragma unroll
    for (int i = 0; i < 4; i++) {
        int rr = ty + i * 8;
        out[(size_t)(tc + rr) * R + tr + tx] = f2bf(tile[tx][rr]);
    }
}

// ============================================================================
// 256x256 8-phase GEMM: C[M,N] = A[M,K](bf16,row) * Bt[N,K](bf16,row)^T
// BK=64, 8 waves (2Mx4N), 128 KiB LDS, 8-slot XOR swizzle
// (phys = lin ^ ((lin>>7 & 7)<<4); pre-swizzled global src + swizzled ds_read).
// COLUMN-MAJOR block ordering (R8): bcol = swz/Mtiles, brow = swz%Mtiles --
// consecutive blocks (same XCD) share the B-panel (L2-resident) and stream
// A from L3; B is read once chip-wide (per-XCD column stripes are disjoint).
// Reads: ph1 = B+Aq0 (12), ph2 = Aq1, ph3 = Aq2+Aq3, ph4 = none.
// Stages (uniform late): ph2: T(t0+2).B0, ph3: .B1, ph4: .A0+.A1,
//                        ph6: T(t1+2).B0, ph7: .B1, ph8: .A0+.A1.
// Prologue stages T0+T1 fully (16 loads), vmcnt(8).
// Ckpt vmcnt(8) at ph4/ph8. LAST iteration stages nothing -> vmcnt(0).
// EPI: 0 = bf16 store, block-level col split (Cptr/Cptr2 at splitcol);
//      2 = loss: sum((acc - aux_f32)^2) -> atomicAdd;
//      3 = fp32 store acc * bf2f(aux_bf16);
//      4 = split: cols<splitcol bf16 -> Cptr, else sigmoid(acc+bg) -> Cptr2
// ============================================================================
template <int EPI>
__global__ __launch_bounds__(512, 2) void gemm256(
        const unsigned short* __restrict__ A, int lda,
        const unsigned short* __restrict__ Bt, int ldb,
        void* __restrict__ Cptr, void* __restrict__ Cptr2,
        int ldc, int splitcol, int K, int Mtiles,
        const float* __restrict__ aux_f32,
        const unsigned short* __restrict__ aux_bf16,
        float* __restrict__ loss_accum) {
    extern __shared__ char smem[];   // 131072 B
    const int tid  = threadIdx.x;
    const int wid  = tid >> 6, lane = tid & 63;
    const int wm   = wid >> 2, wn = wid & 3;
    const int l15  = lane & 15;
    const int lhi  = (lane >> 4) * 16;         // byte offset of k-group
    const int nkt  = K >> 6;                   // K-tiles of 64

    // bijective XCD swizzle (m204)
    const int nwg = gridDim.x;
    int wg = blockIdx.x;
    int q = nwg >> 3, r = nwg & 7;
    int xcd = wg & 7, idx = wg >> 3;
    int swz = (xcd < r ? xcd * (q + 1) : r * (q + 1) + (xcd - r) * q) + idx;
    // column-major tile mapping: same-XCD blocks share bcol (B-panel reuse)
    const int brow = (swz % Mtiles) << 8;
    const int bcol = (swz / Mtiles) << 8;

    // per-thread stage addressing: chunk c = wid*2+j covers LDS [c*1024, +1024)
    // linear dest; SOURCE pre-swizzled: phys = lin ^ ((lin>>7 & 7)<<4)
    const int lin0 = (wid * 2 + 0) * 1024 + lane * 16;
    const int lin1 = (wid * 2 + 1) * 1024 + lane * 16;
    const int ph0 = lin0 ^ (((lin0 >> 7) & 7) << 4);
    const int ph1v = lin1 ^ (((lin1 >> 7) & 7) << 4);
    const int srow0 = ph0 >> 7, scol0 = (ph0 & 127) >> 1;
    const int srow1 = ph1v >> 7, scol1 = (ph1v & 127) >> 1;
    const int dst0 = (wid * 2 + 0) * 1024;
    const int dst1 = (wid * 2 + 1) * 1024;

    // stage half-tile: tile t, mat 0=A 1=B, half h (128 rows x 64 k-cols)
#define STAGE(t, mat, h) do { \
        char* base_ = smem + (((t) & 1) * 65536) + ((mat) * 32768) + ((h) * 16384); \
        const unsigned short* G_ = (mat) ? Bt : A; \
        const int ld_ = (mat) ? ldb : lda; \
        const int rb_ = ((mat) ? bcol : brow) + (h) * 128; \
        gload16(G_ + (size_t)(rb_ + srow0) * ld_ + (t) * 64 + scol0, base_ + dst0); \
        gload16(G_ + (size_t)(rb_ + srow1) * ld_ + (t) * 64 + scol1, base_ + dst1); \
    } while (0)
#define STAGE_G(t, mat, h) do { if ((t) < nkt) STAGE(t, mat, h); } while (0)

    // swizzled fragment reads
#define LDA_FRAG(dst, buf, m, kk) do { \
        int lin_ = ((m) * 16 + l15) * 128 + (kk) * 64 + lhi; \
        int ph_  = lin_ ^ (((lin_ >> 7) & 7) << 4); \
        dst = *(const short8*)(smem + (buf) * 65536 + wm * 16384 + ph_); \
    } while (0)
#define LDB_FRAG(dst, buf, n, kk) do { \
        int lin_ = ((wn & 1) * 64 + (n) * 16 + l15) * 128 + (kk) * 64 + lhi; \
        int ph_  = lin_ ^ (((lin_ >> 7) & 7) << 4); \
        dst = *(const short8*)(smem + (buf) * 65536 + 32768 + (wn >> 1) * 16384 + ph_); \
    } while (0)

    f32x4 acc[8][4] = {};
    short8 afr[8][2], bfr[4][2];

#define MFMA_Q(mq) do { \
        __builtin_amdgcn_s_setprio(1); \
        _Pragma("unroll") \
        for (int n_ = 0; n_ < 4; ++n_) { \
            acc[2*(mq)][n_]   = __builtin_amdgcn_mfma_f32_16x16x32_bf16(afr[2*(mq)][0],   bfr[n_][0], acc[2*(mq)][n_],   0,0,0); \
            acc[2*(mq)][n_]   = __builtin_amdgcn_mfma_f32_16x16x32_bf16(afr[2*(mq)][1],   bfr[n_][1], acc[2*(mq)][n_],   0,0,0); \
            acc[2*(mq)+1][n_] = __builtin_amdgcn_mfma_f32_16x16x32_bf16(afr[2*(mq)+1][0], bfr[n_][0], acc[2*(mq)+1][n_], 0,0,0); \
            acc[2*(mq)+1][n_] = __builtin_amdgcn_mfma_f32_16x16x32_bf16(afr[2*(mq)+1][1], bfr[n_][1], acc[2*(mq)+1][n_], 0,0,0); \
        } \
        __builtin_amdgcn_s_setprio(0); \
    } while (0)

#define READ_B(b) do { \
        _Pragma("unroll") \
        for (int n_ = 0; n_ < 4; ++n_) { LDB_FRAG(bfr[n_][0], b, n_, 0); LDB_FRAG(bfr[n_][1], b, n_, 1); } \
    } while (0)
#define READ_QA(b, mq) do { \
        LDA_FRAG(afr[2*(mq)][0],   b, 2*(mq),   0); LDA_FRAG(afr[2*(mq)][1],   b, 2*(mq),   1); \
        LDA_FRAG(afr[2*(mq)+1][0], b, 2*(mq)+1, 0); LDA_FRAG(afr[2*(mq)+1][1], b, 2*(mq)+1, 1); \
    } while (0)

    // ---- prologue: T0 + T1 fully staged (16 loads); drain T0 ----
    STAGE(0, 1, 0); STAGE(0, 1, 1); STAGE(0, 0, 0); STAGE(0, 0, 1);
    STAGE_G(1, 1, 0); STAGE_G(1, 1, 1); STAGE_G(1, 0, 0); STAGE_G(1, 0, 1);
    VMCNT8();        // T0 landed (newest 8 = T1 full)
    PH_BARRIER();

    const int niter = nkt >> 1;
    for (int it = 0; it < niter; ++it) {
        const int t0 = it * 2, t1 = t0 + 1;
        const bool lastIt = (it == niter - 1);

        // ================= group A: tile t0 in buf 0 =================
        // ph1: read B + Aq0 (buf0); no stage
        READ_B(0); READ_QA(0, 0);
        PH_BARRIER();
        MFMA_Q(0);
        PH_BARRIER();
        // ph2: read Aq1; stage T(t0+2).B0 (buf0.B free after ph1)
        READ_QA(0, 1);
        STAGE_G(t0 + 2, 1, 0);
        PH_BARRIER();
        MFMA_Q(1);
        PH_BARRIER();
        // ph3: read Aq2 + Aq3; stage T(t0+2).B1
        READ_QA(0, 2); READ_QA(0, 3);
        STAGE_G(t0 + 2, 1, 1);
        PH_BARRIER();
        MFMA_Q(2);
        PH_BARRIER();
        // ph4: no reads; stage T(t0+2).A0+A1 (buf0.A free after ph3); ckpt
        STAGE_G(t0 + 2, 0, 0); STAGE_G(t0 + 2, 0, 1);
        PH_BARRIER();
        MFMA_Q(3);
        if (lastIt) { VMCNT0(); } else { VMCNT8(); }   // drain t1 (B 6-ph, A 4-ph lead)
        PH_BARRIER();

        // ================= group B: tile t1 in buf 1 =================
        // ph5: read B + Aq0 (buf1); no stage
        READ_B(1); READ_QA(1, 0);
        PH_BARRIER();
        MFMA_Q(0);
        PH_BARRIER();
        // ph6: read Aq1; stage T(t1+2).B0 (buf1.B free after ph5)
        READ_QA(1, 1);
        STAGE_G(t1 + 2, 1, 0);
        PH_BARRIER();
        MFMA_Q(1);
        PH_BARRIER();
        // ph7: read Aq2 + Aq3; stage T(t1+2).B1
        READ_QA(1, 2); READ_QA(1, 3);
        STAGE_G(t1 + 2, 1, 1);
        PH_BARRIER();
        MFMA_Q(2);
        PH_BARRIER();
        // ph8: no reads; stage T(t1+2).A0+A1 (buf1.A free after ph7); ckpt
        STAGE_G(t1 + 2, 0, 0); STAGE_G(t1 + 2, 0, 1);
        PH_BARRIER();
        MFMA_Q(3);
        if (lastIt) { VMCNT0(); } else { VMCNT8(); }   // drain t0+2 (next ph1)
        PH_BARRIER();
    }

    // ---- epilogue: C/D layout col = lane&15, row = (lane>>4)*4 + reg ----
    const int rl = (lane >> 4) * 4;
    const int cl = lane & 15;
    const int row0 = brow + wm * 128;

    if constexpr (EPI == 2) {
        const int col0 = bcol + wn * 64;
        float lsum = 0.f;
#pragma unroll
        for (int m = 0; m < 8; m++)
#pragma unroll
            for (int n = 0; n < 4; n++)
#pragma unroll
                for (int rg = 0; rg < 4; rg++) {
                    int gr = row0 + m * 16 + rl + rg;
                    int gc = col0 + n * 16 + cl;
                    float d = acc[m][n][rg] - aux_f32[(size_t)gr * ldc + gc];
                    lsum += d * d;
                }
#pragma unroll
        for (int msk = 1; msk < 64; msk <<= 1)
            lsum += __shfl_xor(lsum, msk, 64);
        if (lane == 0) atomicAdd(loss_accum, lsum);
        return;
    }

    // block-uniform output target (tiles are 256-wide; splitcol multiple of 256)
    void* Ceff = Cptr;
    bool second = false;
    int bcol_l = bcol;
    if constexpr (EPI == 0 || EPI == 4) {
        if (bcol >= splitcol) { Ceff = Cptr2; bcol_l = bcol - splitcol; second = true; }
    }
    const int col0 = bcol_l + wn * 64;

#pragma unroll
    for (int m = 0; m < 8; m++)
#pragma unroll
        for (int n = 0; n < 4; n++)
#pragma unroll
            for (int rg = 0; rg < 4; rg++) {
                int gr = row0 + m * 16 + rl + rg;
                int gc = col0 + n * 16 + cl;
                size_t idxo = (size_t)gr * ldc + gc;
                if constexpr (EPI == 0) {
                    ((unsigned short*)Ceff)[idxo] = f2bf(acc[m][n][rg]);
                } else if constexpr (EPI == 4) {
                    if (second) {
                        float t = acc[m][n][rg] + aux_f32[gc];
                        ((unsigned short*)Ceff)[idxo] = f2bf(1.f / (1.f + expf(-t)));
                    } else {
                        ((unsigned short*)Ceff)[idxo] = f2bf(acc[m][n][rg]);
                    }
                } else {  // EPI == 3
                    float gv = bf2f(aux_bf16[idxo]);
                    ((float*)Ceff)[idxo] = acc[m][n][rg] * gv;
                }
            }
#undef STAGE
#undef STAGE_G
#undef LDA_FRAG
#undef LDB_FRAG
#undef MFMA_Q
#undef READ_B
#undef READ_QA
}

// ---------- pmean[n][c] = mean_p prefix[n][p*2048 + c] ----------
__global__ __launch_bounds__(256) void pmean_kernel(
        const unsigned short* __restrict__ prefix, unsigned short* __restrict__ pm) {
    int i  = blockIdx.x * 256 + threadIdx.x;
    int n  = i >> 8;
    int c8 = (i & 255) * 8;
    float acc[8] = {0, 0, 0, 0, 0, 0, 0, 0};
#pragma unroll
    for (int p = 0; p < 8; p++) {
        const unsigned short* src = prefix + (size_t)n * 16384 + p * 2048 + c8;
        uint4 raw = *(const uint4*)src;
        unsigned w[4] = {raw.x, raw.y, raw.z, raw.w};
#pragma unroll
        for (int j = 0; j < 4; j++) {
            float2 fp = bfpair(w[j]);
            acc[2 * j] += fp.x; acc[2 * j + 1] += fp.y;
        }
    }
    uint4 o;
    unsigned* ow = (unsigned*)&o;
#pragma unroll
    for (int j = 0; j < 4; j++)
        ow[j] = (unsigned)f2bf(acc[2 * j] * 0.125f) |
                ((unsigned)f2bf(acc[2 * j + 1] * 0.125f) << 16);
    *(uint4*)(pm + (size_t)n * 2048 + c8) = o;
}

// ---------- attention: one wave per (n,h), P=8 keys, D=128 ----------
__global__ __launch_bounds__(256) void attn_kernel(
        const unsigned short* __restrict__ q, const unsigned short* __restrict__ k,
        const unsigned short* __restrict__ v, unsigned short* __restrict__ o) {
    int gw   = (blockIdx.x * 256 + threadIdx.x) >> 6;
    int lane = threadIdx.x & 63;
    int n = gw >> 4, h = gw & 15;
    size_t qoff = (size_t)n * 2048 + h * 128 + lane * 2;
    float2 qv = bfpair(*(const unsigned*)(q + qoff));
    float s[8];
#pragma unroll
    for (int p = 0; p < 8; p++) {
        size_t koff = (size_t)(n * 8 + p) * 2048 + h * 128 + lane * 2;
        float2 kv = bfpair(*(const unsigned*)(k + koff));
        float d = qv.x * kv.x + qv.y * kv.y;
#pragma unroll
        for (int msk = 1; msk < 64; msk <<= 1) d += __shfl_xor(d, msk, 64);
        s[p] = d * 0.08838834764831845f;
    }
    float mx = s[0];
#pragma unroll
    for (int p = 1; p < 8; p++) mx = fmaxf(mx, s[p]);
    float e[8], den = 0.f;
#pragma unroll
    for (int p = 0; p < 8; p++) { e[p] = expf(s[p] - mx); den += e[p]; }
    float inv = 1.f / den;
    float o0 = 0.f, o1 = 0.f;
#pragma unroll
    for (int p = 0; p < 8; p++) {
        size_t voff = (size_t)(n * 8 + p) * 2048 + h * 128 + lane * 2;
        float2 vv = bfpair(*(const unsigned*)(v + voff));
        float a = e[p] * inv;
        o0 += a * vv.x; o1 += a * vv.y;
    }
    *(unsigned*)(o + qoff) = (unsigned)f2bf(o0) | ((unsigned)f2bf(o1) << 16);
}

__global__ __launch_bounds__(64) void finalize_loss_kernel(
        const float* __restrict__ accum, float* __restrict__ dst) {
    if (threadIdx.x == 0) dst[0] = accum[0] * (1.0f / (4096.0f * 2048.0f));
}

// ---------- launch ----------
extern "C" void kernel_launch(void* const* d_in, const int* in_sizes, int n_in,
                              void* d_out, int out_size, void* d_ws, size_t ws_size,
                              hipStream_t stream) {
    const float* x    = (const float*)d_in[0];
    const float* rwkv = (const float*)d_in[1];
    const float* Wq   = (const float*)d_in[2];
    const float* Wk   = (const float*)d_in[3];
    const float* Wv   = (const float*)d_in[4];
    const float* Wo   = (const float*)d_in[5];
    const float* Wg   = (const float*)d_in[6];
    const float* bg   = (const float*)d_in[7];
    const float* Wb   = (const float*)d_in[8];
    const float* Wr   = (const float*)d_in[9];
    float* out = (float*)d_out;
    char*  ws  = (char*)d_ws;

    unsigned short* xs     = (unsigned short*)(ws + 0ull);
    unsigned short* wbT    = (unsigned short*)(ws + 33554432ull);    // 128MB, reused as kbuf
    unsigned short* wqT    = (unsigned short*)(ws + 167772160ull);   // qg pair adjacent
    unsigned short* wgT    = (unsigned short*)(ws + 176160768ull);
    unsigned short* wkT    = (unsigned short*)(ws + 184549376ull);   // kv pair adjacent
    unsigned short* wvT    = (unsigned short*)(ws + 192937984ull);
    unsigned short* wrT    = (unsigned short*)(ws + 201326592ull);
    unsigned short* woT    = (unsigned short*)(ws + 209715200ull);
    unsigned short* prefix = (unsigned short*)(ws + 218103808ull);   // 128MB
    unsigned short* vbuf   = (unsigned short*)(ws + 352321536ull);   // 128MB
    unsigned short* qbuf   = (unsigned short*)(ws + 486539264ull);
    unsigned short* gbuf   = (unsigned short*)(ws + 503316480ull);
    unsigned short* pmean  = (unsigned short*)(ws + 520093696ull);
    unsigned short* attno  = (unsigned short*)(ws + 536870912ull);
    float*          lossA  = (float*)(ws + 553648128ull);
    unsigned short* kbuf   = wbT;   // WbT dead after bridge GEMM

    const int SMEM = 131072;
    const int BIG = 1 << 30;
    hipFuncSetAttribute(reinterpret_cast<const void*>(gemm256<0>),
                        hipFuncAttributeMaxDynamicSharedMemorySize, SMEM);
    hipFuncSetAttribute(reinterpret_cast<const void*>(gemm256<2>),
                        hipFuncAttributeMaxDynamicSharedMemorySize, SMEM);
    hipFuncSetAttribute(reinterpret_cast<const void*>(gemm256<3>),
                        hipFuncAttributeMaxDynamicSharedMemorySize, SMEM);
    hipFuncSetAttribute(reinterpret_cast<const void*>(gemm256<4>),
                        hipFuncAttributeMaxDynamicSharedMemorySize, SMEM);

    hipMemsetAsync(lossA, 0, 16, stream);

    pack_xs_kernel<<<16384, 256, 0, stream>>>(x, rwkv, xs);
    transpose_cast_kernel<<<dim3(512, 128), 256, 0, stream>>>(Wb, wbT, 4096, 16384);
    transpose_cast_kernel<<<dim3(64, 64),  256, 0, stream>>>(Wq, wqT, 2048, 2048);
    transpose_cast_kernel<<<dim3(64, 64),  256, 0, stream>>>(Wg, wgT, 2048, 2048);
    transpose_cast_kernel<<<dim3(64, 64),  256, 0, stream>>>(Wk, wkT, 2048, 2048);
    transpose_cast_kernel<<<dim3(64, 64),  256, 0, stream>>>(Wv, wvT, 2048, 2048);
    transpose_cast_kernel<<<dim3(64, 64),  256, 0, stream>>>(Wr, wrT, 2048, 2048);
    transpose_cast_kernel<<<dim3(64, 64),  256, 0, stream>>>(Wo, woT, 2048, 2048);

    // prefix = xs @ Wb          M=4096 N=16384 K=4096 -> Mtiles=16 (16x64 grid)
    gemm256<0><<<dim3(1024), 512, SMEM, stream>>>(xs, 4096, wbT, 4096,
        prefix, nullptr, 16384, BIG, 4096, 16, nullptr, nullptr, nullptr);
    // [k|v] = prefix @ [Wk|Wv]  M=32768 N=4096 K=2048 -> Mtiles=128, split @2048
    gemm256<0><<<dim3(2048), 512, SMEM, stream>>>(prefix, 2048, wkT, 2048,
        kbuf, vbuf, 2048, 2048, 2048, 128, nullptr, nullptr, nullptr);
    // pmean = mean_p(prefix)
    pmean_kernel<<<4096, 256, 0, stream>>>(prefix, pmean);
    // [q|g] = x @ [Wq|Wg]       M=4096 N=4096 K=2048 -> Mtiles=16, split @2048
    gemm256<4><<<dim3(256), 512, SMEM, stream>>>(xs, 4096, wqT, 2048,
        qbuf, gbuf, 2048, 2048, 2048, 16, bg, nullptr, nullptr);
    // recon loss: sum((pmean @ Wr - x)^2)   Mtiles=16 (16x8 grid)
    gemm256<2><<<dim3(128), 512, SMEM, stream>>>(pmean, 2048, wrT, 2048,
        nullptr, nullptr, 2048, BIG, 2048, 16, x, nullptr, lossA);
    // attention
    attn_kernel<<<16384, 256, 0, stream>>>(qbuf, kbuf, vbuf, attno);
    // out = (attno @ Wo) * g    -> fp32 d_out   Mtiles=16
    gemm256<3><<<dim3(128), 512, SMEM, stream>>>(attno, 2048, woT, 2048,
        out, nullptr, 2048, BIG, 2048, 16, nullptr, gbuf, nullptr);

    finalize_loss_kernel<<<1, 64, 0, stream>>>(lossA, out + 8388608);
}

// Round 9
// 1432.841 us; speedup vs baseline: 1.0055x; 1.0055x over previous
//
#include <hip/hip_runtime.h>

#define DEVFN static __device__ __forceinline__

typedef __attribute__((ext_vector_type(8))) short short8;
typedef __attribute__((ext_vector_type(4))) float f32x4;

// ---------- bf16 helpers (raw ushort storage) ----------
DEVFN unsigned short f2bf(float f) {
    union { float f; unsigned u; } a; a.f = f;
    unsigned u = a.u;
    unsigned r = (u + 0x7FFFu + ((u >> 16) & 1u)) >> 16;   // RNE
    return (unsigned short)r;
}
DEVFN float bf2f(unsigned short b) {
    union { unsigned u; float f; } a; a.u = ((unsigned)b) << 16;
    return a.f;
}
DEVFN float2 bfpair(unsigned v) {
    float2 r;
    union { unsigned u; float f; } a;
    a.u = (v & 0xFFFFu) << 16; r.x = a.f;
    a.u = v & 0xFFFF0000u;     r.y = a.f;
    return r;
}

// ---------- async global->LDS (16B per lane, wave-uniform LDS base) ----------
DEVFN void gload16(const void* g, void* lds) {
    __builtin_amdgcn_global_load_lds(
        (const __attribute__((address_space(1))) unsigned int*)g,
        (__attribute__((address_space(3))) unsigned int*)lds, 16, 0, 0);
}

// NO sched_barrier(0) anywhere (m141: order-pinning defeats compiler sched).
// s_barrier has unmodeled side effects (memory ops don't cross); vmcnt asm
// carries "memory" clobber for ordering vs gload16/ds ops.
#define PH_BARRIER() __builtin_amdgcn_s_barrier()
#define VMCNT8() asm volatile("s_waitcnt vmcnt(8)" ::: "memory")
#define VMCNT0() asm volatile("s_waitcnt vmcnt(0)" ::: "memory")

// ---------- prep: xs = [x | rwkv] cast bf16 ----------
__global__ __launch_bounds__(256) void pack_xs_kernel(
        const float* __restrict__ x, const float* __restrict__ r,
        unsigned short* __restrict__ xs) {
    int i = blockIdx.x * 256 + threadIdx.x;
    int n  = i >> 10;
    int cw = i & 1023;
    const float* src = (cw < 512) ? (x + (size_t)n * 2048 + cw * 4)
                                  : (r + (size_t)n * 2048 + (cw - 512) * 4);
    float4 v = *(const float4*)src;
    ushort4 o;
    o.x = f2bf(v.x); o.y = f2bf(v.y); o.z = f2bf(v.z); o.w = f2bf(v.w);
    *(ushort4*)(xs + (size_t)n * 4096 + cw * 4) = o;
}

// ---------- prep: transpose + cast fp32[R][Cc] -> bf16[Cc][R] ----------
__global__ __launch_bounds__(256) void transpose_cast_kernel(
        const float* __restrict__ in, unsigned short* __restrict__ out,
        int R, int Cc) {
    __shared__ float tile[32][33];
    int tx = threadIdx.x & 31, ty = threadIdx.x >> 5;
    int tr = blockIdx.y * 32, tc = blockIdx.x * 32;
#pragma unroll
    for (int i = 0; i < 4; i++) {
        int rr = ty + i * 8;
        tile[rr][tx] = in[(size_t)(tr + rr) * Cc + tc + tx];
    }
    __syncthreads();
#pragma unroll
    for (int i = 0; i < 4; i++) {
        int rr = ty + i * 8;
        out[(size_t)(tc + rr) * R + tr + tx] = f2bf(tile[tx][rr]);
    }
}

// ============================================================================
// 256x256 8-phase GEMM: C[M,N] = A[M,K](bf16,row) * Bt[N,K](bf16,row)^T
// BK=64, 8 waves (2Mx4N), 128 KiB LDS, 8-slot XOR swizzle
// (phys = lin ^ ((lin>>7 & 7)<<4); pre-swizzled global src + swizzled ds_read).
// Column-major block ordering: bcol = swz/Mtiles, brow = swz%Mtiles.
// Reads: ph1 = B+Aq0 (12), ph2 = Aq1, ph3 = Aq2+Aq3, ph4 = none.
// Stages (uniform late): ph2: T(t0+2).B0, ph3: .B1, ph4: .A0+.A1,
//                        ph6: T(t1+2).B0, ph7: .B1, ph8: .A0+.A1.
// Prologue stages T0+T1 fully (16 loads), vmcnt(8).
// Ckpt vmcnt(8) at ph4/ph8. LAST iteration stages nothing -> vmcnt(0).
// EPI: 0 = bf16 store, block-level col split (Cptr/Cptr2 at splitcol);
//      2 = loss: sum((acc - aux_f32)^2) -> atomicAdd;
//      3 = fp32 store acc * bf2f(aux_bf16);
//      4 = split: cols<splitcol bf16 -> Cptr, else sigmoid(acc+bg) -> Cptr2
// ============================================================================
template <int EPI>
__global__ __launch_bounds__(512, 2) void gemm256(
        const unsigned short* __restrict__ A, int lda,
        const unsigned short* __restrict__ Bt, int ldb,
        void* __restrict__ Cptr, void* __restrict__ Cptr2,
        int ldc, int splitcol, int K, int Mtiles,
        const float* __restrict__ aux_f32,
        const unsigned short* __restrict__ aux_bf16,
        float* __restrict__ loss_accum) {
    extern __shared__ char smem[];   // 131072 B
    const int tid  = threadIdx.x;
    const int wid  = tid >> 6, lane = tid & 63;
    const int wm   = wid >> 2, wn = wid & 3;
    const int l15  = lane & 15;
    const int lhi  = (lane >> 4) * 16;         // byte offset of k-group
    const int nkt  = K >> 6;                   // K-tiles of 64

    // bijective XCD swizzle (m204)
    const int nwg = gridDim.x;
    int wg = blockIdx.x;
    int q = nwg >> 3, r = nwg & 7;
    int xcd = wg & 7, idx = wg >> 3;
    int swz = (xcd < r ? xcd * (q + 1) : r * (q + 1) + (xcd - r) * q) + idx;
    // column-major tile mapping: same-XCD blocks share bcol (B-panel reuse)
    const int brow = (swz % Mtiles) << 8;
    const int bcol = (swz / Mtiles) << 8;

    // per-thread stage addressing: chunk c = wid*2+j covers LDS [c*1024, +1024)
    // linear dest; SOURCE pre-swizzled: phys = lin ^ ((lin>>7 & 7)<<4)
    const int lin0 = (wid * 2 + 0) * 1024 + lane * 16;
    const int lin1 = (wid * 2 + 1) * 1024 + lane * 16;
    const int ph0 = lin0 ^ (((lin0 >> 7) & 7) << 4);
    const int ph1v = lin1 ^ (((lin1 >> 7) & 7) << 4);
    const int srow0 = ph0 >> 7, scol0 = (ph0 & 127) >> 1;
    const int srow1 = ph1v >> 7, scol1 = (ph1v & 127) >> 1;
    const int dst0 = (wid * 2 + 0) * 1024;
    const int dst1 = (wid * 2 + 1) * 1024;

    // stage half-tile: tile t, mat 0=A 1=B, half h (128 rows x 64 k-cols)
#define STAGE(t, mat, h) do { \
        char* base_ = smem + (((t) & 1) * 65536) + ((mat) * 32768) + ((h) * 16384); \
        const unsigned short* G_ = (mat) ? Bt : A; \
        const int ld_ = (mat) ? ldb : lda; \
        const int rb_ = ((mat) ? bcol : brow) + (h) * 128; \
        gload16(G_ + (size_t)(rb_ + srow0) * ld_ + (t) * 64 + scol0, base_ + dst0); \
        gload16(G_ + (size_t)(rb_ + srow1) * ld_ + (t) * 64 + scol1, base_ + dst1); \
    } while (0)
#define STAGE_G(t, mat, h) do { if ((t) < nkt) STAGE(t, mat, h); } while (0)

    // swizzled fragment reads
#define LDA_FRAG(dst, buf, m, kk) do { \
        int lin_ = ((m) * 16 + l15) * 128 + (kk) * 64 + lhi; \
        int ph_  = lin_ ^ (((lin_ >> 7) & 7) << 4); \
        dst = *(const short8*)(smem + (buf) * 65536 + wm * 16384 + ph_); \
    } while (0)
#define LDB_FRAG(dst, buf, n, kk) do { \
        int lin_ = ((wn & 1) * 64 + (n) * 16 + l15) * 128 + (kk) * 64 + lhi; \
        int ph_  = lin_ ^ (((lin_ >> 7) & 7) << 4); \
        dst = *(const short8*)(smem + (buf) * 65536 + 32768 + (wn >> 1) * 16384 + ph_); \
    } while (0)

    f32x4 acc[8][4] = {};
    short8 afr[8][2], bfr[4][2];

#define MFMA_Q(mq) do { \
        __builtin_amdgcn_s_setprio(1); \
        _Pragma("unroll") \
        for (int n_ = 0; n_ < 4; ++n_) { \
            acc[2*(mq)][n_]   = __builtin_amdgcn_mfma_f32_16x16x32_bf16(afr[2*(mq)][0],   bfr[n_][0], acc[2*(mq)][n_],   0,0,0); \
            acc[2*(mq)][n_]   = __builtin_amdgcn_mfma_f32_16x16x32_bf16(afr[2*(mq)][1],   bfr[n_][1], acc[2*(mq)][n_],   0,0,0); \
            acc[2*(mq)+1][n_] = __builtin_amdgcn_mfma_f32_16x16x32_bf16(afr[2*(mq)+1][0], bfr[n_][0], acc[2*(mq)+1][n_], 0,0,0); \
            acc[2*(mq)+1][n_] = __builtin_amdgcn_mfma_f32_16x16x32_bf16(afr[2*(mq)+1][1], bfr[n_][1], acc[2*(mq)+1][n_], 0,0,0); \
        } \
        __builtin_amdgcn_s_setprio(0); \
    } while (0)

#define READ_B(b) do { \
        _Pragma("unroll") \
        for (int n_ = 0; n_ < 4; ++n_) { LDB_FRAG(bfr[n_][0], b, n_, 0); LDB_FRAG(bfr[n_][1], b, n_, 1); } \
    } while (0)
#define READ_QA(b, mq) do { \
        LDA_FRAG(afr[2*(mq)][0],   b, 2*(mq),   0); LDA_FRAG(afr[2*(mq)][1],   b, 2*(mq),   1); \
        LDA_FRAG(afr[2*(mq)+1][0], b, 2*(mq)+1, 0); LDA_FRAG(afr[2*(mq)+1][1], b, 2*(mq)+1, 1); \
    } while (0)

    // ---- prologue: T0 + T1 fully staged (16 loads); drain T0 ----
    STAGE(0, 1, 0); STAGE(0, 1, 1); STAGE(0, 0, 0); STAGE(0, 0, 1);
    STAGE_G(1, 1, 0); STAGE_G(1, 1, 1); STAGE_G(1, 0, 0); STAGE_G(1, 0, 1);
    VMCNT8();        // T0 landed (newest 8 = T1 full)
    PH_BARRIER();

    const int niter = nkt >> 1;
    for (int it = 0; it < niter; ++it) {
        const int t0 = it * 2, t1 = t0 + 1;
        const bool lastIt = (it == niter - 1);

        // ================= group A: tile t0 in buf 0 =================
        // ph1: read B + Aq0 (buf0); no stage
        READ_B(0); READ_QA(0, 0);
        PH_BARRIER();
        MFMA_Q(0);
        PH_BARRIER();
        // ph2: read Aq1; stage T(t0+2).B0 (buf0.B free after ph1)
        READ_QA(0, 1);
        STAGE_G(t0 + 2, 1, 0);
        PH_BARRIER();
        MFMA_Q(1);
        PH_BARRIER();
        // ph3: read Aq2 + Aq3; stage T(t0+2).B1
        READ_QA(0, 2); READ_QA(0, 3);
        STAGE_G(t0 + 2, 1, 1);
        PH_BARRIER();
        MFMA_Q(2);
        PH_BARRIER();
        // ph4: no reads; stage T(t0+2).A0+A1 (buf0.A free after ph3); ckpt
        STAGE_G(t0 + 2, 0, 0); STAGE_G(t0 + 2, 0, 1);
        PH_BARRIER();
        MFMA_Q(3);
        if (lastIt) { VMCNT0(); } else { VMCNT8(); }   // drain t1 (B 6-ph, A 4-ph lead)
        PH_BARRIER();

        // ================= group B: tile t1 in buf 1 =================
        // ph5: read B + Aq0 (buf1); no stage
        READ_B(1); READ_QA(1, 0);
        PH_BARRIER();
        MFMA_Q(0);
        PH_BARRIER();
        // ph6: read Aq1; stage T(t1+2).B0 (buf1.B free after ph5)
        READ_QA(1, 1);
        STAGE_G(t1 + 2, 1, 0);
        PH_BARRIER();
        MFMA_Q(1);
        PH_BARRIER();
        // ph7: read Aq2 + Aq3; stage T(t1+2).B1
        READ_QA(1, 2); READ_QA(1, 3);
        STAGE_G(t1 + 2, 1, 1);
        PH_BARRIER();
        MFMA_Q(2);
        PH_BARRIER();
        // ph8: no reads; stage T(t1+2).A0+A1 (buf1.A free after ph7); ckpt
        STAGE_G(t1 + 2, 0, 0); STAGE_G(t1 + 2, 0, 1);
        PH_BARRIER();
        MFMA_Q(3);
        if (lastIt) { VMCNT0(); } else { VMCNT8(); }   // drain t0+2 (next ph1)
        PH_BARRIER();
    }

    // ---- epilogue: C/D layout col = lane&15, row = (lane>>4)*4 + reg ----
    const int rl = (lane >> 4) * 4;
    const int cl = lane & 15;
    const int row0 = brow + wm * 128;

    if constexpr (EPI == 2) {
        const int col0 = bcol + wn * 64;
        float lsum = 0.f;
#pragma unroll
        for (int m = 0; m < 8; m++)
#pragma unroll
            for (int n = 0; n < 4; n++)
#pragma unroll
                for (int rg = 0; rg < 4; rg++) {
                    int gr = row0 + m * 16 + rl + rg;
                    int gc = col0 + n * 16 + cl;
                    float d = acc[m][n][rg] - aux_f32[(size_t)gr * ldc + gc];
                    lsum += d * d;
                }
#pragma unroll
        for (int msk = 1; msk < 64; msk <<= 1)
            lsum += __shfl_xor(lsum, msk, 64);
        if (lane == 0) atomicAdd(loss_accum, lsum);
        return;
    }

    // block-uniform output target (tiles are 256-wide; splitcol multiple of 256)
    void* Ceff = Cptr;
    bool second = false;
    int bcol_l = bcol;
    if constexpr (EPI == 0 || EPI == 4) {
        if (bcol >= splitcol) { Ceff = Cptr2; bcol_l = bcol - splitcol; second = true; }
    }
    const int col0 = bcol_l + wn * 64;

#pragma unroll
    for (int m = 0; m < 8; m++)
#pragma unroll
        for (int n = 0; n < 4; n++)
#pragma unroll
            for (int rg = 0; rg < 4; rg++) {
                int gr = row0 + m * 16 + rl + rg;
                int gc = col0 + n * 16 + cl;
                size_t idxo = (size_t)gr * ldc + gc;
                if constexpr (EPI == 0) {
                    ((unsigned short*)Ceff)[idxo] = f2bf(acc[m][n][rg]);
                } else if constexpr (EPI == 4) {
                    if (second) {
                        float t = acc[m][n][rg] + aux_f32[gc];
                        ((unsigned short*)Ceff)[idxo] = f2bf(1.f / (1.f + expf(-t)));
                    } else {
                        ((unsigned short*)Ceff)[idxo] = f2bf(acc[m][n][rg]);
                    }
                } else {  // EPI == 3
                    float gv = bf2f(aux_bf16[idxo]);
                    ((float*)Ceff)[idxo] = acc[m][n][rg] * gv;
                }
            }
#undef STAGE
#undef STAGE_G
#undef LDA_FRAG
#undef LDB_FRAG
#undef MFMA_Q
#undef READ_B
#undef READ_QA
}

// ---------- pmean[n][c] = mean_p prefix[n][p*2048 + c] ----------
__global__ __launch_bounds__(256) void pmean_kernel(
        const unsigned short* __restrict__ prefix, unsigned short* __restrict__ pm) {
    int i  = blockIdx.x * 256 + threadIdx.x;
    int n  = i >> 8;
    int c8 = (i & 255) * 8;
    float acc[8] = {0, 0, 0, 0, 0, 0, 0, 0};
#pragma unroll
    for (int p = 0; p < 8; p++) {
        const unsigned short* src = prefix + (size_t)n * 16384 + p * 2048 + c8;
        uint4 raw = *(const uint4*)src;
        unsigned w[4] = {raw.x, raw.y, raw.z, raw.w};
#pragma unroll
        for (int j = 0; j < 4; j++) {
            float2 fp = bfpair(w[j]);
            acc[2 * j] += fp.x; acc[2 * j + 1] += fp.y;
        }
    }
    uint4 o;
    unsigned* ow = (unsigned*)&o;
#pragma unroll
    for (int j = 0; j < 4; j++)
        ow[j] = (unsigned)f2bf(acc[2 * j] * 0.125f) |
                ((unsigned)f2bf(acc[2 * j + 1] * 0.125f) << 16);
    *(uint4*)(pm + (size_t)n * 2048 + c8) = o;
}

// ---------- attention: one wave per (n,h), P=8 keys, D=128 ----------
__global__ __launch_bounds__(256) void attn_kernel(
        const unsigned short* __restrict__ q, const unsigned short* __restrict__ k,
        const unsigned short* __restrict__ v, unsigned short* __restrict__ o) {
    int gw   = (blockIdx.x * 256 + threadIdx.x) >> 6;
    int lane = threadIdx.x & 63;
    int n = gw >> 4, h = gw & 15;
    size_t qoff = (size_t)n * 2048 + h * 128 + lane * 2;
    float2 qv = bfpair(*(const unsigned*)(q + qoff));
    float s[8];
#pragma unroll
    for (int p = 0; p < 8; p++) {
        size_t koff = (size_t)(n * 8 + p) * 2048 + h * 128 + lane * 2;
        float2 kv = bfpair(*(const unsigned*)(k + koff));
        float d = qv.x * kv.x + qv.y * kv.y;
#pragma unroll
        for (int msk = 1; msk < 64; msk <<= 1) d += __shfl_xor(d, msk, 64);
        s[p] = d * 0.08838834764831845f;
    }
    float mx = s[0];
#pragma unroll
    for (int p = 1; p < 8; p++) mx = fmaxf(mx, s[p]);
    float e[8], den = 0.f;
#pragma unroll
    for (int p = 0; p < 8; p++) { e[p] = expf(s[p] - mx); den += e[p]; }
    float inv = 1.f / den;
    float o0 = 0.f, o1 = 0.f;
#pragma unroll
    for (int p = 0; p < 8; p++) {
        size_t voff = (size_t)(n * 8 + p) * 2048 + h * 128 + lane * 2;
        float2 vv = bfpair(*(const unsigned*)(v + voff));
        float a = e[p] * inv;
        o0 += a * vv.x; o1 += a * vv.y;
    }
    *(unsigned*)(o + qoff) = (unsigned)f2bf(o0) | ((unsigned)f2bf(o1) << 16);
}

__global__ __launch_bounds__(64) void finalize_loss_kernel(
        const float* __restrict__ accum, float* __restrict__ dst) {
    if (threadIdx.x == 0) dst[0] = accum[0] * (1.0f / (4096.0f * 2048.0f));
}

// ---------- launch ----------
extern "C" void kernel_launch(void* const* d_in, const int* in_sizes, int n_in,
                              void* d_out, int out_size, void* d_ws, size_t ws_size,
                              hipStream_t stream) {
    const float* x    = (const float*)d_in[0];
    const float* rwkv = (const float*)d_in[1];
    const float* Wq   = (const float*)d_in[2];
    const float* Wk   = (const float*)d_in[3];
    const float* Wv   = (const float*)d_in[4];
    const float* Wo   = (const float*)d_in[5];
    const float* Wg   = (const float*)d_in[6];
    const float* bg   = (const float*)d_in[7];
    const float* Wb   = (const float*)d_in[8];
    const float* Wr   = (const float*)d_in[9];
    float* out = (float*)d_out;
    char*  ws  = (char*)d_ws;

    unsigned short* xs     = (unsigned short*)(ws + 0ull);
    unsigned short* wbT    = (unsigned short*)(ws + 33554432ull);    // 128MB, reused as kbuf
    unsigned short* wqT    = (unsigned short*)(ws + 167772160ull);   // qg pair adjacent
    unsigned short* wgT    = (unsigned short*)(ws + 176160768ull);
    unsigned short* wkT    = (unsigned short*)(ws + 184549376ull);   // kv pair adjacent
    unsigned short* wvT    = (unsigned short*)(ws + 192937984ull);
    unsigned short* wrT    = (unsigned short*)(ws + 201326592ull);
    unsigned short* woT    = (unsigned short*)(ws + 209715200ull);
    unsigned short* prefix = (unsigned short*)(ws + 218103808ull);   // 128MB
    unsigned short* vbuf   = (unsigned short*)(ws + 352321536ull);   // 128MB
    unsigned short* qbuf   = (unsigned short*)(ws + 486539264ull);
    unsigned short* gbuf   = (unsigned short*)(ws + 503316480ull);
    unsigned short* pmean  = (unsigned short*)(ws + 520093696ull);
    unsigned short* attno  = (unsigned short*)(ws + 536870912ull);
    float*          lossA  = (float*)(ws + 553648128ull);
    unsigned short* kbuf   = wbT;   // WbT dead after bridge GEMM

    const int SMEM = 131072;
    const int BIG = 1 << 30;
    hipFuncSetAttribute(reinterpret_cast<const void*>(gemm256<0>),
                        hipFuncAttributeMaxDynamicSharedMemorySize, SMEM);
    hipFuncSetAttribute(reinterpret_cast<const void*>(gemm256<2>),
                        hipFuncAttributeMaxDynamicSharedMemorySize, SMEM);
    hipFuncSetAttribute(reinterpret_cast<const void*>(gemm256<3>),
                        hipFuncAttributeMaxDynamicSharedMemorySize, SMEM);
    hipFuncSetAttribute(reinterpret_cast<const void*>(gemm256<4>),
                        hipFuncAttributeMaxDynamicSharedMemorySize, SMEM);

    hipMemsetAsync(lossA, 0, 16, stream);

    pack_xs_kernel<<<16384, 256, 0, stream>>>(x, rwkv, xs);
    transpose_cast_kernel<<<dim3(512, 128), 256, 0, stream>>>(Wb, wbT, 4096, 16384);
    transpose_cast_kernel<<<dim3(64, 64),  256, 0, stream>>>(Wq, wqT, 2048, 2048);
    transpose_cast_kernel<<<dim3(64, 64),  256, 0, stream>>>(Wg, wgT, 2048, 2048);
    transpose_cast_kernel<<<dim3(64, 64),  256, 0, stream>>>(Wk, wkT, 2048, 2048);
    transpose_cast_kernel<<<dim3(64, 64),  256, 0, stream>>>(Wv, wvT, 2048, 2048);
    transpose_cast_kernel<<<dim3(64, 64),  256, 0, stream>>>(Wr, wrT, 2048, 2048);
    transpose_cast_kernel<<<dim3(64, 64),  256, 0, stream>>>(Wo, woT, 2048, 2048);

    // prefix = xs @ Wb          M=4096 N=16384 K=4096 -> Mtiles=16 (16x64 grid)
    gemm256<0><<<dim3(1024), 512, SMEM, stream>>>(xs, 4096, wbT, 4096,
        prefix, nullptr, 16384, BIG, 4096, 16, nullptr, nullptr, nullptr);
    // [k|v] = prefix @ [Wk|Wv]  M=32768 N=4096 K=2048 -> Mtiles=128, split @2048
    gemm256<0><<<dim3(2048), 512, SMEM, stream>>>(prefix, 2048, wkT, 2048,
        kbuf, vbuf, 2048, 2048, 2048, 128, nullptr, nullptr, nullptr);
    // pmean = mean_p(prefix)
    pmean_kernel<<<4096, 256, 0, stream>>>(prefix, pmean);
    // [q|g] = x @ [Wq|Wg]       M=4096 N=4096 K=2048 -> Mtiles=16, split @2048
    gemm256<4><<<dim3(256), 512, SMEM, stream>>>(xs, 4096, wqT, 2048,
        qbuf, gbuf, 2048, 2048, 2048, 16, bg, nullptr, nullptr);
    // recon loss: sum((pmean @ Wr - x)^2)   Mtiles=16 (16x8 grid)
    gemm256<2><<<dim3(128), 512, SMEM, stream>>>(pmean, 2048, wrT, 2048,
        nullptr, nullptr, 2048, BIG, 2048, 16, x, nullptr, lossA);
    // attention
    attn_kernel<<<16384, 256, 0, stream>>>(qbuf, kbuf, vbuf, attno);
    // out = (attno @ Wo) * g    -> fp32 d_out   Mtiles=16
    gemm256<3><<<dim3(128), 512, SMEM, stream>>>(attno, 2048, woT, 2048,
        out, nullptr, 2048, BIG, 2048, 16, nullptr, gbuf, nullptr);

    finalize_loss_kernel<<<1, 64, 0, stream>>>(lossA, out + 8388608);
}

// Round 10
// 1344.478 us; speedup vs baseline: 1.0716x; 1.0657x over previous
//
#include <hip/hip_runtime.h>

#define DEVFN static __device__ __forceinline__

typedef __attribute__((ext_vector_type(8))) short short8;
typedef __attribute__((ext_vector_type(4))) float f32x4;

// ---------- bf16 helpers (raw ushort storage) ----------
DEVFN unsigned short f2bf(float f) {
    union { float f; unsigned u; } a; a.f = f;
    unsigned u = a.u;
    unsigned r = (u + 0x7FFFu + ((u >> 16) & 1u)) >> 16;   // RNE
    return (unsigned short)r;
}
DEVFN float bf2f(unsigned short b) {
    union { unsigned u; float f; } a; a.u = ((unsigned)b) << 16;
    return a.f;
}
DEVFN float2 bfpair(unsigned v) {
    float2 r;
    union { unsigned u; float f; } a;
    a.u = (v & 0xFFFFu) << 16; r.x = a.f;
    a.u = v & 0xFFFF0000u;     r.y = a.f;
    return r;
}

// ---------- async global->LDS (16B per lane, wave-uniform LDS base) ----------
DEVFN void gload16(const void* g, void* lds) {
    __builtin_amdgcn_global_load_lds(
        (const __attribute__((address_space(1))) unsigned int*)g,
        (__attribute__((address_space(3))) unsigned int*)lds, 16, 0, 0);
}

#define BAR() __builtin_amdgcn_s_barrier()
#define VMCNT8() asm volatile("s_waitcnt vmcnt(8)" ::: "memory")
#define VMCNT0() asm volatile("s_waitcnt vmcnt(0)" ::: "memory")

// ---------- prep: xs = [x | rwkv] cast bf16 ----------
__global__ __launch_bounds__(256) void pack_xs_kernel(
        const float* __restrict__ x, const float* __restrict__ r,
        unsigned short* __restrict__ xs) {
    int i = blockIdx.x * 256 + threadIdx.x;
    int n  = i >> 10;
    int cw = i & 1023;
    const float* src = (cw < 512) ? (x + (size_t)n * 2048 + cw * 4)
                                  : (r + (size_t)n * 2048 + (cw - 512) * 4);
    float4 v = *(const float4*)src;
    ushort4 o;
    o.x = f2bf(v.x); o.y = f2bf(v.y); o.z = f2bf(v.z); o.w = f2bf(v.w);
    *(ushort4*)(xs + (size_t)n * 4096 + cw * 4) = o;
}

// ---------- prep: transpose + cast fp32[R][Cc] -> bf16[Cc][R] ----------
__global__ __launch_bounds__(256) void transpose_cast_kernel(
        const float* __restrict__ in, unsigned short* __restrict__ out,
        int R, int Cc) {
    __shared__ float tile[32][33];
    int tx = threadIdx.x & 31, ty = threadIdx.x >> 5;
    int tr = blockIdx.y * 32, tc = blockIdx.x * 32;
#pragma unroll
    for (int i = 0; i < 4; i++) {
        int rr = ty + i * 8;
        tile[rr][tx] = in[(size_t)(tr + rr) * Cc + tc + tx];
    }
    __syncthreads();
#pragma unroll
    for (int i = 0; i < 4; i++) {
        int rr = ty + i * 8;
        out[(size_t)(tc + rr) * R + tr + tx] = f2bf(tile[tx][rr]);
    }
}

// ============================================================================
// 256x256 8-phase GEMM: C[M,N] = A[M,K](bf16,row) * Bt[N,K](bf16,row)^T
// BK=64, 8 waves (2Mx4N), 128 KiB LDS, 8-slot XOR swizzle
// (phys = lin ^ ((lin>>7 & 7)<<4); pre-swizzled global src + swizzled ds_read).
// SINGLE BARRIER PER PHASE (m201 template): {reads, stage, BAR, MFMA} --
// phase-p MFMAs overlap wave-locally with phase-p+1 read/stage issue.
// WAR-safe: every staged region's reads are >=1 barrier older.
// Reads: ph1 = B+Aq0, ph2 = Aq1, ph3 = Aq2+Aq3, ph4 = none (mirror ph5-8).
// Stages: ph2: T(t0+2).B0, ph3: .B1, ph4: .A0+.A1 (mirror ph6-8 for t1+2).
// Ckpt vmcnt(8) after ph4/ph8 stages, pre-barrier: 16 outstanding -> drains
// exactly the 8 loads of the tile the next group reads. Prologue: T0+T1
// (16 loads) + vmcnt(8). LAST iteration stages nothing -> vmcnt(0) (R5).
// EPI: 0 = bf16 store, block-level col split (Cptr/Cptr2 at splitcol);
//      2 = loss: sum((acc - aux_f32)^2) -> atomicAdd;
//      3 = fp32 store acc * bf2f(aux_bf16);
//      4 = split: cols<splitcol bf16 -> Cptr, else sigmoid(acc+bg) -> Cptr2
// ============================================================================
template <int EPI>
__global__ __launch_bounds__(512, 2) void gemm256(
        const unsigned short* __restrict__ A, int lda,
        const unsigned short* __restrict__ Bt, int ldb,
        void* __restrict__ Cptr, void* __restrict__ Cptr2,
        int ldc, int splitcol, int K, int Mtiles,
        const float* __restrict__ aux_f32,
        const unsigned short* __restrict__ aux_bf16,
        float* __restrict__ loss_accum) {
    extern __shared__ char smem[];   // 131072 B
    const int tid  = threadIdx.x;
    const int wid  = tid >> 6, lane = tid & 63;
    const int wm   = wid >> 2, wn = wid & 3;
    const int l15  = lane & 15;
    const int lhi  = (lane >> 4) * 16;         // byte offset of k-group
    const int nkt  = K >> 6;                   // K-tiles of 64

    // bijective XCD swizzle (m204)
    const int nwg = gridDim.x;
    int wg = blockIdx.x;
    int q = nwg >> 3, r = nwg & 7;
    int xcd = wg & 7, idx = wg >> 3;
    int swz = (xcd < r ? xcd * (q + 1) : r * (q + 1) + (xcd - r) * q) + idx;
    // column-major tile mapping: same-XCD blocks share bcol (B-panel reuse)
    const int brow = (swz % Mtiles) << 8;
    const int bcol = (swz / Mtiles) << 8;

    // per-thread stage addressing: chunk c = wid*2+j covers LDS [c*1024, +1024)
    // linear dest; SOURCE pre-swizzled: phys = lin ^ ((lin>>7 & 7)<<4)
    const int lin0 = (wid * 2 + 0) * 1024 + lane * 16;
    const int lin1 = (wid * 2 + 1) * 1024 + lane * 16;
    const int ph0 = lin0 ^ (((lin0 >> 7) & 7) << 4);
    const int ph1v = lin1 ^ (((lin1 >> 7) & 7) << 4);
    const int srow0 = ph0 >> 7, scol0 = (ph0 & 127) >> 1;
    const int srow1 = ph1v >> 7, scol1 = (ph1v & 127) >> 1;
    const int dst0 = (wid * 2 + 0) * 1024;
    const int dst1 = (wid * 2 + 1) * 1024;

    // stage half-tile: tile t, mat 0=A 1=B, half h (128 rows x 64 k-cols)
#define STAGE(t, mat, h) do { \
        char* base_ = smem + (((t) & 1) * 65536) + ((mat) * 32768) + ((h) * 16384); \
        const unsigned short* G_ = (mat) ? Bt : A; \
        const int ld_ = (mat) ? ldb : lda; \
        const int rb_ = ((mat) ? bcol : brow) + (h) * 128; \
        gload16(G_ + (size_t)(rb_ + srow0) * ld_ + (t) * 64 + scol0, base_ + dst0); \
        gload16(G_ + (size_t)(rb_ + srow1) * ld_ + (t) * 64 + scol1, base_ + dst1); \
    } while (0)
#define STAGE_G(t, mat, h) do { if ((t) < nkt) STAGE(t, mat, h); } while (0)

    // swizzled fragment reads
#define LDA_FRAG(dst, buf, m, kk) do { \
        int lin_ = ((m) * 16 + l15) * 128 + (kk) * 64 + lhi; \
        int ph_  = lin_ ^ (((lin_ >> 7) & 7) << 4); \
        dst = *(const short8*)(smem + (buf) * 65536 + wm * 16384 + ph_); \
    } while (0)
#define LDB_FRAG(dst, buf, n, kk) do { \
        int lin_ = ((wn & 1) * 64 + (n) * 16 + l15) * 128 + (kk) * 64 + lhi; \
        int ph_  = lin_ ^ (((lin_ >> 7) & 7) << 4); \
        dst = *(const short8*)(smem + (buf) * 65536 + 32768 + (wn >> 1) * 16384 + ph_); \
    } while (0)

    f32x4 acc[8][4] = {};
    short8 afr[8][2], bfr[4][2];

#define MFMA_Q(mq) do { \
        __builtin_amdgcn_s_setprio(1); \
        _Pragma("unroll") \
        for (int n_ = 0; n_ < 4; ++n_) { \
            acc[2*(mq)][n_]   = __builtin_amdgcn_mfma_f32_16x16x32_bf16(afr[2*(mq)][0],   bfr[n_][0], acc[2*(mq)][n_],   0,0,0); \
            acc[2*(mq)][n_]   = __builtin_amdgcn_mfma_f32_16x16x32_bf16(afr[2*(mq)][1],   bfr[n_][1], acc[2*(mq)][n_],   0,0,0); \
            acc[2*(mq)+1][n_] = __builtin_amdgcn_mfma_f32_16x16x32_bf16(afr[2*(mq)+1][0], bfr[n_][0], acc[2*(mq)+1][n_], 0,0,0); \
            acc[2*(mq)+1][n_] = __builtin_amdgcn_mfma_f32_16x16x32_bf16(afr[2*(mq)+1][1], bfr[n_][1], acc[2*(mq)+1][n_], 0,0,0); \
        } \
        __builtin_amdgcn_s_setprio(0); \
    } while (0)

#define READ_B(b) do { \
        _Pragma("unroll") \
        for (int n_ = 0; n_ < 4; ++n_) { LDB_FRAG(bfr[n_][0], b, n_, 0); LDB_FRAG(bfr[n_][1], b, n_, 1); } \
    } while (0)
#define READ_QA(b, mq) do { \
        LDA_FRAG(afr[2*(mq)][0],   b, 2*(mq),   0); LDA_FRAG(afr[2*(mq)][1],   b, 2*(mq),   1); \
        LDA_FRAG(afr[2*(mq)+1][0], b, 2*(mq)+1, 0); LDA_FRAG(afr[2*(mq)+1][1], b, 2*(mq)+1, 1); \
    } while (0)

    // ---- prologue: T0 + T1 fully staged (16 loads); drain T0 ----
    STAGE(0, 1, 0); STAGE(0, 1, 1); STAGE(0, 0, 0); STAGE(0, 0, 1);
    STAGE_G(1, 1, 0); STAGE_G(1, 1, 1); STAGE_G(1, 0, 0); STAGE_G(1, 0, 1);
    VMCNT8();        // T0 landed (newest 8 = T1 full)
    BAR();

    const int niter = nkt >> 1;
    for (int it = 0; it < niter; ++it) {
        const int t0 = it * 2, t1 = t0 + 1;
        const bool lastIt = (it == niter - 1);

        // ===== group A: tile t0 in buf 0 (one barrier per phase) =====
        // ph1: {read B+Aq0 | no stage | BAR | MFMA q0}
        READ_B(0); READ_QA(0, 0);
        BAR();
        MFMA_Q(0);
        // ph2: {read Aq1 | stage T(t0+2).B0 | BAR | MFMA q1}
        READ_QA(0, 1);
        STAGE_G(t0 + 2, 1, 0);
        BAR();
        MFMA_Q(1);
        // ph3: {read Aq2+Aq3 | stage T(t0+2).B1 | BAR | MFMA q2}
        READ_QA(0, 2); READ_QA(0, 3);
        STAGE_G(t0 + 2, 1, 1);
        BAR();
        MFMA_Q(2);
        // ph4: {stage T(t0+2).A0+A1 | ckpt | BAR | MFMA q3}
        STAGE_G(t0 + 2, 0, 0); STAGE_G(t0 + 2, 0, 1);
        if (lastIt) { VMCNT0(); } else { VMCNT8(); }   // drain tile t1 (buf1)
        BAR();
        MFMA_Q(3);

        // ===== group B: tile t1 in buf 1 =====
        // ph5
        READ_B(1); READ_QA(1, 0);
        BAR();
        MFMA_Q(0);
        // ph6
        READ_QA(1, 1);
        STAGE_G(t1 + 2, 1, 0);
        BAR();
        MFMA_Q(1);
        // ph7
        READ_QA(1, 2); READ_QA(1, 3);
        STAGE_G(t1 + 2, 1, 1);
        BAR();
        MFMA_Q(2);
        // ph8
        STAGE_G(t1 + 2, 0, 0); STAGE_G(t1 + 2, 0, 1);
        if (lastIt) { VMCNT0(); } else { VMCNT8(); }   // drain tile t0+2 (buf0)
        BAR();
        MFMA_Q(3);
    }

    // ---- epilogue: C/D layout col = lane&15, row = (lane>>4)*4 + reg ----
    const int rl = (lane >> 4) * 4;
    const int cl = lane & 15;
    const int row0 = brow + wm * 128;

    if constexpr (EPI == 2) {
        const int col0 = bcol + wn * 64;
        float lsum = 0.f;
#pragma unroll
        for (int m = 0; m < 8; m++)
#pragma unroll
            for (int n = 0; n < 4; n++)
#pragma unroll
                for (int rg = 0; rg < 4; rg++) {
                    int gr = row0 + m * 16 + rl + rg;
                    int gc = col0 + n * 16 + cl;
                    float d = acc[m][n][rg] - aux_f32[(size_t)gr * ldc + gc];
                    lsum += d * d;
                }
#pragma unroll
        for (int msk = 1; msk < 64; msk <<= 1)
            lsum += __shfl_xor(lsum, msk, 64);
        if (lane == 0) atomicAdd(loss_accum, lsum);
        return;
    }

    // block-uniform output target (tiles are 256-wide; splitcol multiple of 256)
    void* Ceff = Cptr;
    bool second = false;
    int bcol_l = bcol;
    if constexpr (EPI == 0 || EPI == 4) {
        if (bcol >= splitcol) { Ceff = Cptr2; bcol_l = bcol - splitcol; second = true; }
    }
    const int col0 = bcol_l + wn * 64;

#pragma unroll
    for (int m = 0; m < 8; m++)
#pragma unroll
        for (int n = 0; n < 4; n++)
#pragma unroll
            for (int rg = 0; rg < 4; rg++) {
                int gr = row0 + m * 16 + rl + rg;
                int gc = col0 + n * 16 + cl;
                size_t idxo = (size_t)gr * ldc + gc;
                if constexpr (EPI == 0) {
                    ((unsigned short*)Ceff)[idxo] = f2bf(acc[m][n][rg]);
                } else if constexpr (EPI == 4) {
                    if (second) {
                        float t = acc[m][n][rg] + aux_f32[gc];
                        ((unsigned short*)Ceff)[idxo] = f2bf(1.f / (1.f + expf(-t)));
                    } else {
                        ((unsigned short*)Ceff)[idxo] = f2bf(acc[m][n][rg]);
                    }
                } else {  // EPI == 3
                    float gv = bf2f(aux_bf16[idxo]);
                    ((float*)Ceff)[idxo] = acc[m][n][rg] * gv;
                }
            }
#undef STAGE
#undef STAGE_G
#undef LDA_FRAG
#undef LDB_FRAG
#undef MFMA_Q
#undef READ_B
#undef READ_QA
}

// ---------- pmean[n][c] = mean_p prefix[n][p*2048 + c] ----------
__global__ __launch_bounds__(256) void pmean_kernel(
        const unsigned short* __restrict__ prefix, unsigned short* __restrict__ pm) {
    int i  = blockIdx.x * 256 + threadIdx.x;
    int n  = i >> 8;
    int c8 = (i & 255) * 8;
    float acc[8] = {0, 0, 0, 0, 0, 0, 0, 0};
#pragma unroll
    for (int p = 0; p < 8; p++) {
        const unsigned short* src = prefix + (size_t)n * 16384 + p * 2048 + c8;
        uint4 raw = *(const uint4*)src;
        unsigned w[4] = {raw.x, raw.y, raw.z, raw.w};
#pragma unroll
        for (int j = 0; j < 4; j++) {
            float2 fp = bfpair(w[j]);
            acc[2 * j] += fp.x; acc[2 * j + 1] += fp.y;
        }
    }
    uint4 o;
    unsigned* ow = (unsigned*)&o;
#pragma unroll
    for (int j = 0; j < 4; j++)
        ow[j] = (unsigned)f2bf(acc[2 * j] * 0.125f) |
                ((unsigned)f2bf(acc[2 * j + 1] * 0.125f) << 16);
    *(uint4*)(pm + (size_t)n * 2048 + c8) = o;
}

// ---------- attention: one wave per (n,h), P=8 keys, D=128 ----------
__global__ __launch_bounds__(256) void attn_kernel(
        const unsigned short* __restrict__ q, const unsigned short* __restrict__ k,
        const unsigned short* __restrict__ v, unsigned short* __restrict__ o) {
    int gw   = (blockIdx.x * 256 + threadIdx.x) >> 6;
    int lane = threadIdx.x & 63;
    int n = gw >> 4, h = gw & 15;
    size_t qoff = (size_t)n * 2048 + h * 128 + lane * 2;
    float2 qv = bfpair(*(const unsigned*)(q + qoff));
    float s[8];
#pragma unroll
    for (int p = 0; p < 8; p++) {
        size_t koff = (size_t)(n * 8 + p) * 2048 + h * 128 + lane * 2;
        float2 kv = bfpair(*(const unsigned*)(k + koff));
        float d = qv.x * kv.x + qv.y * kv.y;
#pragma unroll
        for (int msk = 1; msk < 64; msk <<= 1) d += __shfl_xor(d, msk, 64);
        s[p] = d * 0.08838834764831845f;
    }
    float mx = s[0];
#pragma unroll
    for (int p = 1; p < 8; p++) mx = fmaxf(mx, s[p]);
    float e[8], den = 0.f;
#pragma unroll
    for (int p = 0; p < 8; p++) { e[p] = expf(s[p] - mx); den += e[p]; }
    float inv = 1.f / den;
    float o0 = 0.f, o1 = 0.f;
#pragma unroll
    for (int p = 0; p < 8; p++) {
        size_t voff = (size_t)(n * 8 + p) * 2048 + h * 128 + lane * 2;
        float2 vv = bfpair(*(const unsigned*)(v + voff));
        float a = e[p] * inv;
        o0 += a * vv.x; o1 += a * vv.y;
    }
    *(unsigned*)(o + qoff) = (unsigned)f2bf(o0) | ((unsigned)f2bf(o1) << 16);
}

__global__ __launch_bounds__(64) void finalize_loss_kernel(
        const float* __restrict__ accum, float* __restrict__ dst) {
    if (threadIdx.x == 0) dst[0] = accum[0] * (1.0f / (4096.0f * 2048.0f));
}

// ---------- launch ----------
extern "C" void kernel_launch(void* const* d_in, const int* in_sizes, int n_in,
                              void* d_out, int out_size, void* d_ws, size_t ws_size,
                              hipStream_t stream) {
    const float* x    = (const float*)d_in[0];
    const float* rwkv = (const float*)d_in[1];
    const float* Wq   = (const float*)d_in[2];
    const float* Wk   = (const float*)d_in[3];
    const float* Wv   = (const float*)d_in[4];
    const float* Wo   = (const float*)d_in[5];
    const float* Wg   = (const float*)d_in[6];
    const float* bg   = (const float*)d_in[7];
    const float* Wb   = (const float*)d_in[8];
    const float* Wr   = (const float*)d_in[9];
    float* out = (float*)d_out;
    char*  ws  = (char*)d_ws;

    unsigned short* xs     = (unsigned short*)(ws + 0ull);
    unsigned short* wbT    = (unsigned short*)(ws + 33554432ull);    // 128MB, reused as kbuf
    unsigned short* wqT    = (unsigned short*)(ws + 167772160ull);   // qg pair adjacent
    unsigned short* wgT    = (unsigned short*)(ws + 176160768ull);
    unsigned short* wkT    = (unsigned short*)(ws + 184549376ull);   // kv pair adjacent
    unsigned short* wvT    = (unsigned short*)(ws + 192937984ull);
    unsigned short* wrT    = (unsigned short*)(ws + 201326592ull);
    unsigned short* woT    = (unsigned short*)(ws + 209715200ull);
    unsigned short* prefix = (unsigned short*)(ws + 218103808ull);   // 128MB
    unsigned short* vbuf   = (unsigned short*)(ws + 352321536ull);   // 128MB
    unsigned short* qbuf   = (unsigned short*)(ws + 486539264ull);
    unsigned short* gbuf   = (unsigned short*)(ws + 503316480ull);
    unsigned short* pmean  = (unsigned short*)(ws + 520093696ull);
    unsigned short* attno  = (unsigned short*)(ws + 536870912ull);
    float*          lossA  = (float*)(ws + 553648128ull);
    unsigned short* kbuf   = wbT;   // WbT dead after bridge GEMM

    const int SMEM = 131072;
    const int BIG = 1 << 30;
    hipFuncSetAttribute(reinterpret_cast<const void*>(gemm256<0>),
                        hipFuncAttributeMaxDynamicSharedMemorySize, SMEM);
    hipFuncSetAttribute(reinterpret_cast<const void*>(gemm256<2>),
                        hipFuncAttributeMaxDynamicSharedMemorySize, SMEM);
    hipFuncSetAttribute(reinterpret_cast<const void*>(gemm256<3>),
                        hipFuncAttributeMaxDynamicSharedMemorySize, SMEM);
    hipFuncSetAttribute(reinterpret_cast<const void*>(gemm256<4>),
                        hipFuncAttributeMaxDynamicSharedMemorySize, SMEM);

    hipMemsetAsync(lossA, 0, 16, stream);

    pack_xs_kernel<<<16384, 256, 0, stream>>>(x, rwkv, xs);
    transpose_cast_kernel<<<dim3(512, 128), 256, 0, stream>>>(Wb, wbT, 4096, 16384);
    transpose_cast_kernel<<<dim3(64, 64),  256, 0, stream>>>(Wq, wqT, 2048, 2048);
    transpose_cast_kernel<<<dim3(64, 64),  256, 0, stream>>>(Wg, wgT, 2048, 2048);
    transpose_cast_kernel<<<dim3(64, 64),  256, 0, stream>>>(Wk, wkT, 2048, 2048);
    transpose_cast_kernel<<<dim3(64, 64),  256, 0, stream>>>(Wv, wvT, 2048, 2048);
    transpose_cast_kernel<<<dim3(64, 64),  256, 0, stream>>>(Wr, wrT, 2048, 2048);
    transpose_cast_kernel<<<dim3(64, 64),  256, 0, stream>>>(Wo, woT, 2048, 2048);

    // prefix = xs @ Wb          M=4096 N=16384 K=4096 -> Mtiles=16 (16x64 grid)
    gemm256<0><<<dim3(1024), 512, SMEM, stream>>>(xs, 4096, wbT, 4096,
        prefix, nullptr, 16384, BIG, 4096, 16, nullptr, nullptr, nullptr);
    // [k|v] = prefix @ [Wk|Wv]  M=32768 N=4096 K=2048 -> Mtiles=128, split @2048
    gemm256<0><<<dim3(2048), 512, SMEM, stream>>>(prefix, 2048, wkT, 2048,
        kbuf, vbuf, 2048, 2048, 2048, 128, nullptr, nullptr, nullptr);
    // pmean = mean_p(prefix)
    pmean_kernel<<<4096, 256, 0, stream>>>(prefix, pmean);
    // [q|g] = x @ [Wq|Wg]       M=4096 N=4096 K=2048 -> Mtiles=16, split @2048
    gemm256<4><<<dim3(256), 512, SMEM, stream>>>(xs, 4096, wqT, 2048,
        qbuf, gbuf, 2048, 2048, 2048, 16, bg, nullptr, nullptr);
    // recon loss: sum((pmean @ Wr - x)^2)   Mtiles=16 (16x8 grid)
    gemm256<2><<<dim3(128), 512, SMEM, stream>>>(pmean, 2048, wrT, 2048,
        nullptr, nullptr, 2048, BIG, 2048, 16, x, nullptr, lossA);
    // attention
    attn_kernel<<<16384, 256, 0, stream>>>(qbuf, kbuf, vbuf, attno);
    // out = (attno @ Wo) * g    -> fp32 d_out   Mtiles=16
    gemm256<3><<<dim3(128), 512, SMEM, stream>>>(attno, 2048, woT, 2048,
        out, nullptr, 2048, BIG, 2048, 16, nullptr, gbuf, nullptr);

    finalize_loss_kernel<<<1, 64, 0, stream>>>(lossA, out + 8388608);
}

// Round 11
// 1327.195 us; speedup vs baseline: 1.0855x; 1.0130x over previous
//
#include <hip/hip_runtime.h>

#define DEVFN static __device__ __forceinline__

typedef __attribute__((ext_vector_type(8))) short short8;
typedef __attribute__((ext_vector_type(4))) float f32x4;

// ---------- bf16 helpers (raw ushort storage) ----------
DEVFN unsigned short f2bf(float f) {
    union { float f; unsigned u; } a; a.f = f;
    unsigned u = a.u;
    unsigned r = (u + 0x7FFFu + ((u >> 16) & 1u)) >> 16;   // RNE
    return (unsigned short)r;
}
DEVFN float bf2f(unsigned short b) {
    union { unsigned u; float f; } a; a.u = ((unsigned)b) << 16;
    return a.f;
}
DEVFN float2 bfpair(unsigned v) {
    float2 r;
    union { unsigned u; float f; } a;
    a.u = (v & 0xFFFFu) << 16; r.x = a.f;
    a.u = v & 0xFFFF0000u;     r.y = a.f;
    return r;
}

// ---------- async global->LDS (16B per lane, wave-uniform LDS base) ----------
DEVFN void gload16(const void* g, void* lds) {
    __builtin_amdgcn_global_load_lds(
        (const __attribute__((address_space(1))) unsigned int*)g,
        (__attribute__((address_space(3))) unsigned int*)lds, 16, 0, 0);
}

#define BAR() __builtin_amdgcn_s_barrier()
#define VMCNT8() asm volatile("s_waitcnt vmcnt(8)" ::: "memory")
#define VMCNT0() asm volatile("s_waitcnt vmcnt(0)" ::: "memory")

// ---------- prep: xs = [x | rwkv] cast bf16 ----------
__global__ __launch_bounds__(256) void pack_xs_kernel(
        const float* __restrict__ x, const float* __restrict__ r,
        unsigned short* __restrict__ xs) {
    int i = blockIdx.x * 256 + threadIdx.x;
    int n  = i >> 10;
    int cw = i & 1023;
    const float* src = (cw < 512) ? (x + (size_t)n * 2048 + cw * 4)
                                  : (r + (size_t)n * 2048 + (cw - 512) * 4);
    float4 v = *(const float4*)src;
    ushort4 o;
    o.x = f2bf(v.x); o.y = f2bf(v.y); o.z = f2bf(v.z); o.w = f2bf(v.w);
    *(ushort4*)(xs + (size_t)n * 4096 + cw * 4) = o;
}

// ---------- prep: transpose + cast fp32[R][Cc] -> bf16[Cc][R] ----------
__global__ __launch_bounds__(256) void transpose_cast_kernel(
        const float* __restrict__ in, unsigned short* __restrict__ out,
        int R, int Cc) {
    __shared__ float tile[32][33];
    int tx = threadIdx.x & 31, ty = threadIdx.x >> 5;
    int tr = blockIdx.y * 32, tc = blockIdx.x * 32;
#pragma unroll
    for (int i = 0; i < 4; i++) {
        int rr = ty + i * 8;
        tile[rr][tx] = in[(size_t)(tr + rr) * Cc + tc + tx];
    }
    __syncthreads();
#pragma unroll
    for (int i = 0; i < 4; i++) {
        int rr = ty + i * 8;
        out[(size_t)(tc + rr) * R + tr + tx] = f2bf(tile[tx][rr]);
    }
}

// ============================================================================
// 256x256 8-phase GEMM: C[M,N] = A[M,K](bf16,row) * Bt[N,K](bf16,row)^T
// BK=64, 8 waves (2Mx4N), 128 KiB LDS, 8-slot XOR swizzle
// (phys = lin ^ ((lin>>7 & 7)<<4); pre-swizzled global src + swizzled ds_read).
// BANDED XCD MAPPING (R11): XCD x owns Mtiles/8-row band; column-major within
// band. Requires nwg%8==0 and Mtiles%8==0 (true for all launches here).
// Bridge: A-band 4MB L2-resident, B L3-resident after 1st pass. k|v: 2 B-panels
// L2 + A-slices L2 -> staged loads become cache hits, ckpt stalls shrink.
// SINGLE BARRIER PER PHASE (R10): {reads, stage, BAR, MFMA}.
// Reads: ph1 = B+Aq0, ph2 = Aq1, ph3 = Aq2+Aq3, ph4 = none (mirror ph5-8).
// Stages: ph2: T(t0+2).B0, ph3: .B1, ph4: .A0+.A1 (mirror ph6-8 for t1+2).
// Ckpt vmcnt(8) after ph4/ph8 stages: drains tile needed next group.
// Prologue T0+T1 (16 loads) + vmcnt(8). LAST iteration -> vmcnt(0) (R5).
// EPI: 0 = bf16 store, block-level col split (Cptr/Cptr2 at splitcol);
//      2 = loss: sum((acc - aux_f32)^2) -> atomicAdd;
//      3 = fp32 store acc * bf2f(aux_bf16);
//      4 = split: cols<splitcol bf16 -> Cptr, else sigmoid(acc+bg) -> Cptr2
// ============================================================================
template <int EPI>
__global__ __launch_bounds__(512, 2) void gemm256(
        const unsigned short* __restrict__ A, int lda,
        const unsigned short* __restrict__ Bt, int ldb,
        void* __restrict__ Cptr, void* __restrict__ Cptr2,
        int ldc, int splitcol, int K, int Mtiles,
        const float* __restrict__ aux_f32,
        const unsigned short* __restrict__ aux_bf16,
        float* __restrict__ loss_accum) {
    extern __shared__ char smem[];   // 131072 B
    const int tid  = threadIdx.x;
    const int wid  = tid >> 6, lane = tid & 63;
    const int wm   = wid >> 2, wn = wid & 3;
    const int l15  = lane & 15;
    const int lhi  = (lane >> 4) * 16;         // byte offset of k-group
    const int nkt  = K >> 6;                   // K-tiles of 64

    // banded XCD mapping: nwg%8==0, Mtiles%8==0 guaranteed by caller
    const int bandH = Mtiles >> 3;
    const int xcd = blockIdx.x & 7, idx = blockIdx.x >> 3;
    const int brow = (xcd * bandH + (idx % bandH)) << 8;
    const int bcol = (idx / bandH) << 8;

    // per-thread stage addressing: chunk c = wid*2+j covers LDS [c*1024, +1024)
    // linear dest; SOURCE pre-swizzled: phys = lin ^ ((lin>>7 & 7)<<4)
    const int lin0 = (wid * 2 + 0) * 1024 + lane * 16;
    const int lin1 = (wid * 2 + 1) * 1024 + lane * 16;
    const int ph0 = lin0 ^ (((lin0 >> 7) & 7) << 4);
    const int ph1v = lin1 ^ (((lin1 >> 7) & 7) << 4);
    const int srow0 = ph0 >> 7, scol0 = (ph0 & 127) >> 1;
    const int srow1 = ph1v >> 7, scol1 = (ph1v & 127) >> 1;
    const int dst0 = (wid * 2 + 0) * 1024;
    const int dst1 = (wid * 2 + 1) * 1024;

    // stage half-tile: tile t, mat 0=A 1=B, half h (128 rows x 64 k-cols)
#define STAGE(t, mat, h) do { \
        char* base_ = smem + (((t) & 1) * 65536) + ((mat) * 32768) + ((h) * 16384); \
        const unsigned short* G_ = (mat) ? Bt : A; \
        const int ld_ = (mat) ? ldb : lda; \
        const int rb_ = ((mat) ? bcol : brow) + (h) * 128; \
        gload16(G_ + (size_t)(rb_ + srow0) * ld_ + (t) * 64 + scol0, base_ + dst0); \
        gload16(G_ + (size_t)(rb_ + srow1) * ld_ + (t) * 64 + scol1, base_ + dst1); \
    } while (0)
#define STAGE_G(t, mat, h) do { if ((t) < nkt) STAGE(t, mat, h); } while (0)

    // swizzled fragment reads
#define LDA_FRAG(dst, buf, m, kk) do { \
        int lin_ = ((m) * 16 + l15) * 128 + (kk) * 64 + lhi; \
        int ph_  = lin_ ^ (((lin_ >> 7) & 7) << 4); \
        dst = *(const short8*)(smem + (buf) * 65536 + wm * 16384 + ph_); \
    } while (0)
#define LDB_FRAG(dst, buf, n, kk) do { \
        int lin_ = ((wn & 1) * 64 + (n) * 16 + l15) * 128 + (kk) * 64 + lhi; \
        int ph_  = lin_ ^ (((lin_ >> 7) & 7) << 4); \
        dst = *(const short8*)(smem + (buf) * 65536 + 32768 + (wn >> 1) * 16384 + ph_); \
    } while (0)

    f32x4 acc[8][4] = {};
    short8 afr[8][2], bfr[4][2];

#define MFMA_Q(mq) do { \
        __builtin_amdgcn_s_setprio(1); \
        _Pragma("unroll") \
        for (int n_ = 0; n_ < 4; ++n_) { \
            acc[2*(mq)][n_]   = __builtin_amdgcn_mfma_f32_16x16x32_bf16(afr[2*(mq)][0],   bfr[n_][0], acc[2*(mq)][n_],   0,0,0); \
            acc[2*(mq)][n_]   = __builtin_amdgcn_mfma_f32_16x16x32_bf16(afr[2*(mq)][1],   bfr[n_][1], acc[2*(mq)][n_],   0,0,0); \
            acc[2*(mq)+1][n_] = __builtin_amdgcn_mfma_f32_16x16x32_bf16(afr[2*(mq)+1][0], bfr[n_][0], acc[2*(mq)+1][n_], 0,0,0); \
            acc[2*(mq)+1][n_] = __builtin_amdgcn_mfma_f32_16x16x32_bf16(afr[2*(mq)+1][1], bfr[n_][1], acc[2*(mq)+1][n_], 0,0,0); \
        } \
        __builtin_amdgcn_s_setprio(0); \
    } while (0)

#define READ_B(b) do { \
        _Pragma("unroll") \
        for (int n_ = 0; n_ < 4; ++n_) { LDB_FRAG(bfr[n_][0], b, n_, 0); LDB_FRAG(bfr[n_][1], b, n_, 1); } \
    } while (0)
#define READ_QA(b, mq) do { \
        LDA_FRAG(afr[2*(mq)][0],   b, 2*(mq),   0); LDA_FRAG(afr[2*(mq)][1],   b, 2*(mq),   1); \
        LDA_FRAG(afr[2*(mq)+1][0], b, 2*(mq)+1, 0); LDA_FRAG(afr[2*(mq)+1][1], b, 2*(mq)+1, 1); \
    } while (0)

    // ---- prologue: T0 + T1 fully staged (16 loads); drain T0 ----
    STAGE(0, 1, 0); STAGE(0, 1, 1); STAGE(0, 0, 0); STAGE(0, 0, 1);
    STAGE_G(1, 1, 0); STAGE_G(1, 1, 1); STAGE_G(1, 0, 0); STAGE_G(1, 0, 1);
    VMCNT8();        // T0 landed (newest 8 = T1 full)
    BAR();

    const int niter = nkt >> 1;
    for (int it = 0; it < niter; ++it) {
        const int t0 = it * 2, t1 = t0 + 1;
        const bool lastIt = (it == niter - 1);

        // ===== group A: tile t0 in buf 0 (one barrier per phase) =====
        // ph1: {read B+Aq0 | no stage | BAR | MFMA q0}
        READ_B(0); READ_QA(0, 0);
        BAR();
        MFMA_Q(0);
        // ph2: {read Aq1 | stage T(t0+2).B0 | BAR | MFMA q1}
        READ_QA(0, 1);
        STAGE_G(t0 + 2, 1, 0);
        BAR();
        MFMA_Q(1);
        // ph3: {read Aq2+Aq3 | stage T(t0+2).B1 | BAR | MFMA q2}
        READ_QA(0, 2); READ_QA(0, 3);
        STAGE_G(t0 + 2, 1, 1);
        BAR();
        MFMA_Q(2);
        // ph4: {stage T(t0+2).A0+A1 | ckpt | BAR | MFMA q3}
        STAGE_G(t0 + 2, 0, 0); STAGE_G(t0 + 2, 0, 1);
        if (lastIt) { VMCNT0(); } else { VMCNT8(); }   // drain tile t1 (buf1)
        BAR();
        MFMA_Q(3);

        // ===== group B: tile t1 in buf 1 =====
        // ph5
        READ_B(1); READ_QA(1, 0);
        BAR();
        MFMA_Q(0);
        // ph6
        READ_QA(1, 1);
        STAGE_G(t1 + 2, 1, 0);
        BAR();
        MFMA_Q(1);
        // ph7
        READ_QA(1, 2); READ_QA(1, 3);
        STAGE_G(t1 + 2, 1, 1);
        BAR();
        MFMA_Q(2);
        // ph8
        STAGE_G(t1 + 2, 0, 0); STAGE_G(t1 + 2, 0, 1);
        if (lastIt) { VMCNT0(); } else { VMCNT8(); }   // drain tile t0+2 (buf0)
        BAR();
        MFMA_Q(3);
    }

    // ---- epilogue: C/D layout col = lane&15, row = (lane>>4)*4 + reg ----
    const int rl = (lane >> 4) * 4;
    const int cl = lane & 15;
    const int row0 = brow + wm * 128;

    if constexpr (EPI == 2) {
        const int col0 = bcol + wn * 64;
        float lsum = 0.f;
#pragma unroll
        for (int m = 0; m < 8; m++)
#pragma unroll
            for (int n = 0; n < 4; n++)
#pragma unroll
                for (int rg = 0; rg < 4; rg++) {
                    int gr = row0 + m * 16 + rl + rg;
                    int gc = col0 + n * 16 + cl;
                    float d = acc[m][n][rg] - aux_f32[(size_t)gr * ldc + gc];
                    lsum += d * d;
                }
#pragma unroll
        for (int msk = 1; msk < 64; msk <<= 1)
            lsum += __shfl_xor(lsum, msk, 64);
        if (lane == 0) atomicAdd(loss_accum, lsum);
        return;
    }

    // block-uniform output target (tiles are 256-wide; splitcol multiple of 256)
    void* Ceff = Cptr;
    bool second = false;
    int bcol_l = bcol;
    if constexpr (EPI == 0 || EPI == 4) {
        if (bcol >= splitcol) { Ceff = Cptr2; bcol_l = bcol - splitcol; second = true; }
    }
    const int col0 = bcol_l + wn * 64;

#pragma unroll
    for (int m = 0; m < 8; m++)
#pragma unroll
        for (int n = 0; n < 4; n++)
#pragma unroll
            for (int rg = 0; rg < 4; rg++) {
                int gr = row0 + m * 16 + rl + rg;
                int gc = col0 + n * 16 + cl;
                size_t idxo = (size_t)gr * ldc + gc;
                if constexpr (EPI == 0) {
                    ((unsigned short*)Ceff)[idxo] = f2bf(acc[m][n][rg]);
                } else if constexpr (EPI == 4) {
                    if (second) {
                        float t = acc[m][n][rg] + aux_f32[gc];
                        ((unsigned short*)Ceff)[idxo] = f2bf(1.f / (1.f + expf(-t)));
                    } else {
                        ((unsigned short*)Ceff)[idxo] = f2bf(acc[m][n][rg]);
                    }
                } else {  // EPI == 3
                    float gv = bf2f(aux_bf16[idxo]);
                    ((float*)Ceff)[idxo] = acc[m][n][rg] * gv;
                }
            }
#undef STAGE
#undef STAGE_G
#undef LDA_FRAG
#undef LDB_FRAG
#undef MFMA_Q
#undef READ_B
#undef READ_QA
}

// ---------- pmean[n][c] = mean_p prefix[n][p*2048 + c] ----------
__global__ __launch_bounds__(256) void pmean_kernel(
        const unsigned short* __restrict__ prefix, unsigned short* __restrict__ pm) {
    int i  = blockIdx.x * 256 + threadIdx.x;
    int n  = i >> 8;
    int c8 = (i & 255) * 8;
    float acc[8] = {0, 0, 0, 0, 0, 0, 0, 0};
#pragma unroll
    for (int p = 0; p < 8; p++) {
        const unsigned short* src = prefix + (size_t)n * 16384 + p * 2048 + c8;
        uint4 raw = *(const uint4*)src;
        unsigned w[4] = {raw.x, raw.y, raw.z, raw.w};
#pragma unroll
        for (int j = 0; j < 4; j++) {
            float2 fp = bfpair(w[j]);
            acc[2 * j] += fp.x; acc[2 * j + 1] += fp.y;
        }
    }
    uint4 o;
    unsigned* ow = (unsigned*)&o;
#pragma unroll
    for (int j = 0; j < 4; j++)
        ow[j] = (unsigned)f2bf(acc[2 * j] * 0.125f) |
                ((unsigned)f2bf(acc[2 * j + 1] * 0.125f) << 16);
    *(uint4*)(pm + (size_t)n * 2048 + c8) = o;
}

// ---------- attention: one wave per (n,h), P=8 keys, D=128 ----------
__global__ __launch_bounds__(256) void attn_kernel(
        const unsigned short* __restrict__ q, const unsigned short* __restrict__ k,
        const unsigned short* __restrict__ v, unsigned short* __restrict__ o) {
    int gw   = (blockIdx.x * 256 + threadIdx.x) >> 6;
    int lane = threadIdx.x & 63;
    int n = gw >> 4, h = gw & 15;
    size_t qoff = (size_t)n * 2048 + h * 128 + lane * 2;
    float2 qv = bfpair(*(const unsigned*)(q + qoff));
    float s[8];
#pragma unroll
    for (int p = 0; p < 8; p++) {
        size_t koff = (size_t)(n * 8 + p) * 2048 + h * 128 + lane * 2;
        float2 kv = bfpair(*(const unsigned*)(k + koff));
        float d = qv.x * kv.x + qv.y * kv.y;
#pragma unroll
        for (int msk = 1; msk < 64; msk <<= 1) d += __shfl_xor(d, msk, 64);
        s[p] = d * 0.08838834764831845f;
    }
    float mx = s[0];
#pragma unroll
    for (int p = 1; p < 8; p++) mx = fmaxf(mx, s[p]);
    float e[8], den = 0.f;
#pragma unroll
    for (int p = 0; p < 8; p++) { e[p] = expf(s[p] - mx); den += e[p]; }
    float inv = 1.f / den;
    float o0 = 0.f, o1 = 0.f;
#pragma unroll
    for (int p = 0; p < 8; p++) {
        size_t voff = (size_t)(n * 8 + p) * 2048 + h * 128 + lane * 2;
        float2 vv = bfpair(*(const unsigned*)(v + voff));
        float a = e[p] * inv;
        o0 += a * vv.x; o1 += a * vv.y;
    }
    *(unsigned*)(o + qoff) = (unsigned)f2bf(o0) | ((unsigned)f2bf(o1) << 16);
}

__global__ __launch_bounds__(64) void finalize_loss_kernel(
        const float* __restrict__ accum, float* __restrict__ dst) {
    if (threadIdx.x == 0) dst[0] = accum[0] * (1.0f / (4096.0f * 2048.0f));
}

// ---------- launch ----------
extern "C" void kernel_launch(void* const* d_in, const int* in_sizes, int n_in,
                              void* d_out, int out_size, void* d_ws, size_t ws_size,
                              hipStream_t stream) {
    const float* x    = (const float*)d_in[0];
    const float* rwkv = (const float*)d_in[1];
    const float* Wq   = (const float*)d_in[2];
    const float* Wk   = (const float*)d_in[3];
    const float* Wv   = (const float*)d_in[4];
    const float* Wo   = (const float*)d_in[5];
    const float* Wg   = (const float*)d_in[6];
    const float* bg   = (const float*)d_in[7];
    const float* Wb   = (const float*)d_in[8];
    const float* Wr   = (const float*)d_in[9];
    float* out = (float*)d_out;
    char*  ws  = (char*)d_ws;

    unsigned short* xs     = (unsigned short*)(ws + 0ull);
    unsigned short* wbT    = (unsigned short*)(ws + 33554432ull);    // 128MB, reused as kbuf
    unsigned short* wqT    = (unsigned short*)(ws + 167772160ull);   // qg pair adjacent
    unsigned short* wgT    = (unsigned short*)(ws + 176160768ull);
    unsigned short* wkT    = (unsigned short*)(ws + 184549376ull);   // kv pair adjacent
    unsigned short* wvT    = (unsigned short*)(ws + 192937984ull);
    unsigned short* wrT    = (unsigned short*)(ws + 201326592ull);
    unsigned short* woT    = (unsigned short*)(ws + 209715200ull);
    unsigned short* prefix = (unsigned short*)(ws + 218103808ull);   // 128MB
    unsigned short* vbuf   = (unsigned short*)(ws + 352321536ull);   // 128MB
    unsigned short* qbuf   = (unsigned short*)(ws + 486539264ull);
    unsigned short* gbuf   = (unsigned short*)(ws + 503316480ull);
    unsigned short* pmean  = (unsigned short*)(ws + 520093696ull);
    unsigned short* attno  = (unsigned short*)(ws + 536870912ull);
    float*          lossA  = (float*)(ws + 553648128ull);
    unsigned short* kbuf   = wbT;   // WbT dead after bridge GEMM

    const int SMEM = 131072;
    const int BIG = 1 << 30;
    hipFuncSetAttribute(reinterpret_cast<const void*>(gemm256<0>),
                        hipFuncAttributeMaxDynamicSharedMemorySize, SMEM);
    hipFuncSetAttribute(reinterpret_cast<const void*>(gemm256<2>),
                        hipFuncAttributeMaxDynamicSharedMemorySize, SMEM);
    hipFuncSetAttribute(reinterpret_cast<const void*>(gemm256<3>),
                        hipFuncAttributeMaxDynamicSharedMemorySize, SMEM);
    hipFuncSetAttribute(reinterpret_cast<const void*>(gemm256<4>),
                        hipFuncAttributeMaxDynamicSharedMemorySize, SMEM);

    hipMemsetAsync(lossA, 0, 16, stream);

    pack_xs_kernel<<<16384, 256, 0, stream>>>(x, rwkv, xs);
    transpose_cast_kernel<<<dim3(512, 128), 256, 0, stream>>>(Wb, wbT, 4096, 16384);
    transpose_cast_kernel<<<dim3(64, 64),  256, 0, stream>>>(Wq, wqT, 2048, 2048);
    transpose_cast_kernel<<<dim3(64, 64),  256, 0, stream>>>(Wg, wgT, 2048, 2048);
    transpose_cast_kernel<<<dim3(64, 64),  256, 0, stream>>>(Wk, wkT, 2048, 2048);
    transpose_cast_kernel<<<dim3(64, 64),  256, 0, stream>>>(Wv, wvT, 2048, 2048);
    transpose_cast_kernel<<<dim3(64, 64),  256, 0, stream>>>(Wr, wrT, 2048, 2048);
    transpose_cast_kernel<<<dim3(64, 64),  256, 0, stream>>>(Wo, woT, 2048, 2048);

    // prefix = xs @ Wb          M=4096 N=16384 K=4096 -> Mtiles=16 (bandH=2)
    gemm256<0><<<dim3(1024), 512, SMEM, stream>>>(xs, 4096, wbT, 4096,
        prefix, nullptr, 16384, BIG, 4096, 16, nullptr, nullptr, nullptr);
    // [k|v] = prefix @ [Wk|Wv]  M=32768 N=4096 K=2048 -> Mtiles=128 (bandH=16)
    gemm256<0><<<dim3(2048), 512, SMEM, stream>>>(prefix, 2048, wkT, 2048,
        kbuf, vbuf, 2048, 2048, 2048, 128, nullptr, nullptr, nullptr);
    // pmean = mean_p(prefix)
    pmean_kernel<<<4096, 256, 0, stream>>>(prefix, pmean);
    // [q|g] = x @ [Wq|Wg]       M=4096 N=4096 K=2048 -> Mtiles=16 (bandH=2)
    gemm256<4><<<dim3(256), 512, SMEM, stream>>>(xs, 4096, wqT, 2048,
        qbuf, gbuf, 2048, 2048, 2048, 16, bg, nullptr, nullptr);
    // recon loss: sum((pmean @ Wr - x)^2)   Mtiles=16 (bandH=2)
    gemm256<2><<<dim3(128), 512, SMEM, stream>>>(pmean, 2048, wrT, 2048,
        nullptr, nullptr, 2048, BIG, 2048, 16, x, nullptr, lossA);
    // attention
    attn_kernel<<<16384, 256, 0, stream>>>(qbuf, kbuf, vbuf, attno);
    // out = (attno @ Wo) * g    -> fp32 d_out   Mtiles=16 (bandH=2)
    gemm256<3><<<dim3(128), 512, SMEM, stream>>>(attno, 2048, woT, 2048,
        out, nullptr, 2048, BIG, 2048, 16, nullptr, gbuf, nullptr);

    finalize_loss_kernel<<<1, 64, 0, stream>>>(lossA, out + 8388608);
}

// Round 12
// 1324.297 us; speedup vs baseline: 1.0879x; 1.0022x over previous
//
#include <hip/hip_runtime.h>

#define DEVFN static __device__ __forceinline__

typedef __attribute__((ext_vector_type(8))) short short8;
typedef __attribute__((ext_vector_type(4))) float f32x4;

// ---------- bf16 helpers (raw ushort storage) ----------
DEVFN unsigned short f2bf(float f) {
    union { float f; unsigned u; } a; a.f = f;
    unsigned u = a.u;
    unsigned r = (u + 0x7FFFu + ((u >> 16) & 1u)) >> 16;   // RNE
    return (unsigned short)r;
}
DEVFN float bf2f(unsigned short b) {
    union { unsigned u; float f; } a; a.u = ((unsigned)b) << 16;
    return a.f;
}
DEVFN float2 bfpair(unsigned v) {
    float2 r;
    union { unsigned u; float f; } a;
    a.u = (v & 0xFFFFu) << 16; r.x = a.f;
    a.u = v & 0xFFFF0000u;     r.y = a.f;
    return r;
}

// ---------- async global->LDS (16B per lane, wave-uniform LDS base) ----------
DEVFN void gload16(const void* g, void* lds) {
    __builtin_amdgcn_global_load_lds(
        (const __attribute__((address_space(1))) unsigned int*)g,
        (__attribute__((address_space(3))) unsigned int*)lds, 16, 0, 0);
}

#define BAR() __builtin_amdgcn_s_barrier()
#define VMCNT8() asm volatile("s_waitcnt vmcnt(8)" ::: "memory")
#define VMCNT0() asm volatile("s_waitcnt vmcnt(0)" ::: "memory")

// ---------- prep: xs = [x | rwkv] cast bf16 ----------
__global__ __launch_bounds__(256) void pack_xs_kernel(
        const float* __restrict__ x, const float* __restrict__ r,
        unsigned short* __restrict__ xs) {
    int i = blockIdx.x * 256 + threadIdx.x;
    int n  = i >> 10;
    int cw = i & 1023;
    const float* src = (cw < 512) ? (x + (size_t)n * 2048 + cw * 4)
                                  : (r + (size_t)n * 2048 + (cw - 512) * 4);
    float4 v = *(const float4*)src;
    ushort4 o;
    o.x = f2bf(v.x); o.y = f2bf(v.y); o.z = f2bf(v.z); o.w = f2bf(v.w);
    *(ushort4*)(xs + (size_t)n * 4096 + cw * 4) = o;
}

// ---------- prep: transpose + cast fp32[R][Cc] -> bf16[Cc][R] ----------
// Vectorized (R12): one float4 load + one ushort4 store per thread.
// 32x32 tile, 256 threads. LDS read bank = (4i+j+orow)%32 -> worst 2-way (free).
__global__ __launch_bounds__(256) void transpose_cast_kernel(
        const float* __restrict__ in, unsigned short* __restrict__ out,
        int R, int Cc) {
    __shared__ float tile[32][33];
    const int t  = threadIdx.x;
    const int r  = t >> 3;          // 0..31
    const int c4 = (t & 7) * 4;     // 0,4,...,28
    const int tr = blockIdx.y * 32, tc = blockIdx.x * 32;
    float4 v = *(const float4*)(in + (size_t)(tr + r) * Cc + tc + c4);
    tile[r][c4 + 0] = v.x; tile[r][c4 + 1] = v.y;
    tile[r][c4 + 2] = v.z; tile[r][c4 + 3] = v.w;
    __syncthreads();
    // out[(tc+orow)*R + tr+oc+j] = in[tr+oc+j][tc+orow] = tile[oc+j][orow]
    const int orow = r, oc = c4;
    ushort4 o;
    o.x = f2bf(tile[oc + 0][orow]);
    o.y = f2bf(tile[oc + 1][orow]);
    o.z = f2bf(tile[oc + 2][orow]);
    o.w = f2bf(tile[oc + 3][orow]);
    *(ushort4*)(out + (size_t)(tc + orow) * R + tr + oc) = o;
}

// ============================================================================
// 256x256 8-phase GEMM: C[M,N] = A[M,K](bf16,row) * Bt[N,K](bf16,row)^T
// BK=64, 8 waves (2Mx4N), 128 KiB LDS, 8-slot XOR swizzle
// (phys = lin ^ ((lin>>7 & 7)<<4); pre-swizzled global src + swizzled ds_read).
// BANDED XCD MAPPING (R11): XCD x owns Mtiles/8-row band; column-major within
// band. Requires nwg%8==0 and Mtiles%8==0 (true for all launches here).
// SINGLE BARRIER PER PHASE (R10): {reads, stage, BAR, MFMA}.
// Reads: ph1 = B+Aq0, ph2 = Aq1, ph3 = Aq2+Aq3, ph4 = none (mirror ph5-8).
// Stages: ph2: T(t0+2).B0, ph3: .B1, ph4: .A0+.A1 (mirror ph6-8 for t1+2).
// Ckpt vmcnt(8) after ph4/ph8 stages: drains tile needed next group.
// Prologue T0+T1 (16 loads) + vmcnt(8). LAST iteration -> vmcnt(0) (R5).
// EPI: 0 = bf16 store, block-level col split (Cptr/Cptr2 at splitcol);
//      2 = loss: sum((acc - aux_f32)^2) -> atomicAdd;
//      3 = fp32 store acc * bf2f(aux_bf16);
//      4 = split: cols<splitcol bf16 -> Cptr, else sigmoid(acc+bg) -> Cptr2
// ============================================================================
template <int EPI>
__global__ __launch_bounds__(512, 2) void gemm256(
        const unsigned short* __restrict__ A, int lda,
        const unsigned short* __restrict__ Bt, int ldb,
        void* __restrict__ Cptr, void* __restrict__ Cptr2,
        int ldc, int splitcol, int K, int Mtiles,
        const float* __restrict__ aux_f32,
        const unsigned short* __restrict__ aux_bf16,
        float* __restrict__ loss_accum) {
    extern __shared__ char smem[];   // 131072 B
    const int tid  = threadIdx.x;
    const int wid  = tid >> 6, lane = tid & 63;
    const int wm   = wid >> 2, wn = wid & 3;
    const int l15  = lane & 15;
    const int lhi  = (lane >> 4) * 16;         // byte offset of k-group
    const int nkt  = K >> 6;                   // K-tiles of 64

    // banded XCD mapping: nwg%8==0, Mtiles%8==0 guaranteed by caller
    const int bandH = Mtiles >> 3;
    const int xcd = blockIdx.x & 7, idx = blockIdx.x >> 3;
    const int brow = (xcd * bandH + (idx % bandH)) << 8;
    const int bcol = (idx / bandH) << 8;

    // per-thread stage addressing: chunk c = wid*2+j covers LDS [c*1024, +1024)
    // linear dest; SOURCE pre-swizzled: phys = lin ^ ((lin>>7 & 7)<<4)
    const int lin0 = (wid * 2 + 0) * 1024 + lane * 16;
    const int lin1 = (wid * 2 + 1) * 1024 + lane * 16;
    const int ph0 = lin0 ^ (((lin0 >> 7) & 7) << 4);
    const int ph1v = lin1 ^ (((lin1 >> 7) & 7) << 4);
    const int srow0 = ph0 >> 7, scol0 = (ph0 & 127) >> 1;
    const int srow1 = ph1v >> 7, scol1 = (ph1v & 127) >> 1;
    const int dst0 = (wid * 2 + 0) * 1024;
    const int dst1 = (wid * 2 + 1) * 1024;

    // stage half-tile: tile t, mat 0=A 1=B, half h (128 rows x 64 k-cols)
#define STAGE(t, mat, h) do { \
        char* base_ = smem + (((t) & 1) * 65536) + ((mat) * 32768) + ((h) * 16384); \
        const unsigned short* G_ = (mat) ? Bt : A; \
        const int ld_ = (mat) ? ldb : lda; \
        const int rb_ = ((mat) ? bcol : brow) + (h) * 128; \
        gload16(G_ + (size_t)(rb_ + srow0) * ld_ + (t) * 64 + scol0, base_ + dst0); \
        gload16(G_ + (size_t)(rb_ + srow1) * ld_ + (t) * 64 + scol1, base_ + dst1); \
    } while (0)
#define STAGE_G(t, mat, h) do { if ((t) < nkt) STAGE(t, mat, h); } while (0)

    // swizzled fragment reads
#define LDA_FRAG(dst, buf, m, kk) do { \
        int lin_ = ((m) * 16 + l15) * 128 + (kk) * 64 + lhi; \
        int ph_  = lin_ ^ (((lin_ >> 7) & 7) << 4); \
        dst = *(const short8*)(smem + (buf) * 65536 + wm * 16384 + ph_); \
    } while (0)
#define LDB_FRAG(dst, buf, n, kk) do { \
        int lin_ = ((wn & 1) * 64 + (n) * 16 + l15) * 128 + (kk) * 64 + lhi; \
        int ph_  = lin_ ^ (((lin_ >> 7) & 7) << 4); \
        dst = *(const short8*)(smem + (buf) * 65536 + 32768 + (wn >> 1) * 16384 + ph_); \
    } while (0)

    f32x4 acc[8][4] = {};
    short8 afr[8][2], bfr[4][2];

#define MFMA_Q(mq) do { \
        __builtin_amdgcn_s_setprio(1); \
        _Pragma("unroll") \
        for (int n_ = 0; n_ < 4; ++n_) { \
            acc[2*(mq)][n_]   = __builtin_amdgcn_mfma_f32_16x16x32_bf16(afr[2*(mq)][0],   bfr[n_][0], acc[2*(mq)][n_],   0,0,0); \
            acc[2*(mq)][n_]   = __builtin_amdgcn_mfma_f32_16x16x32_bf16(afr[2*(mq)][1],   bfr[n_][1], acc[2*(mq)][n_],   0,0,0); \
            acc[2*(mq)+1][n_] = __builtin_amdgcn_mfma_f32_16x16x32_bf16(afr[2*(mq)+1][0], bfr[n_][0], acc[2*(mq)+1][n_], 0,0,0); \
            acc[2*(mq)+1][n_] = __builtin_amdgcn_mfma_f32_16x16x32_bf16(afr[2*(mq)+1][1], bfr[n_][1], acc[2*(mq)+1][n_], 0,0,0); \
        } \
        __builtin_amdgcn_s_setprio(0); \
    } while (0)

#define READ_B(b) do { \
        _Pragma("unroll") \
        for (int n_ = 0; n_ < 4; ++n_) { LDB_FRAG(bfr[n_][0], b, n_, 0); LDB_FRAG(bfr[n_][1], b, n_, 1); } \
    } while (0)
#define READ_QA(b, mq) do { \
        LDA_FRAG(afr[2*(mq)][0],   b, 2*(mq),   0); LDA_FRAG(afr[2*(mq)][1],   b, 2*(mq),   1); \
        LDA_FRAG(afr[2*(mq)+1][0], b, 2*(mq)+1, 0); LDA_FRAG(afr[2*(mq)+1][1], b, 2*(mq)+1, 1); \
    } while (0)

    // ---- prologue: T0 + T1 fully staged (16 loads); drain T0 ----
    STAGE(0, 1, 0); STAGE(0, 1, 1); STAGE(0, 0, 0); STAGE(0, 0, 1);
    STAGE_G(1, 1, 0); STAGE_G(1, 1, 1); STAGE_G(1, 0, 0); STAGE_G(1, 0, 1);
    VMCNT8();        // T0 landed (newest 8 = T1 full)
    BAR();

    const int niter = nkt >> 1;
    for (int it = 0; it < niter; ++it) {
        const int t0 = it * 2, t1 = t0 + 1;
        const bool lastIt = (it == niter - 1);

        // ===== group A: tile t0 in buf 0 (one barrier per phase) =====
        // ph1: {read B+Aq0 | no stage | BAR | MFMA q0}
        READ_B(0); READ_QA(0, 0);
        BAR();
        MFMA_Q(0);
        // ph2: {read Aq1 | stage T(t0+2).B0 | BAR | MFMA q1}
        READ_QA(0, 1);
        STAGE_G(t0 + 2, 1, 0);
        BAR();
        MFMA_Q(1);
        // ph3: {read Aq2+Aq3 | stage T(t0+2).B1 | BAR | MFMA q2}
        READ_QA(0, 2); READ_QA(0, 3);
        STAGE_G(t0 + 2, 1, 1);
        BAR();
        MFMA_Q(2);
        // ph4: {stage T(t0+2).A0+A1 | ckpt | BAR | MFMA q3}
        STAGE_G(t0 + 2, 0, 0); STAGE_G(t0 + 2, 0, 1);
        if (lastIt) { VMCNT0(); } else { VMCNT8(); }   // drain tile t1 (buf1)
        BAR();
        MFMA_Q(3);

        // ===== group B: tile t1 in buf 1 =====
        // ph5
        READ_B(1); READ_QA(1, 0);
        BAR();
        MFMA_Q(0);
        // ph6
        READ_QA(1, 1);
        STAGE_G(t1 + 2, 1, 0);
        BAR();
        MFMA_Q(1);
        // ph7
        READ_QA(1, 2); READ_QA(1, 3);
        STAGE_G(t1 + 2, 1, 1);
        BAR();
        MFMA_Q(2);
        // ph8
        STAGE_G(t1 + 2, 0, 0); STAGE_G(t1 + 2, 0, 1);
        if (lastIt) { VMCNT0(); } else { VMCNT8(); }   // drain tile t0+2 (buf0)
        BAR();
        MFMA_Q(3);
    }

    // ---- epilogue: C/D layout col = lane&15, row = (lane>>4)*4 + reg ----
    const int rl = (lane >> 4) * 4;
    const int cl = lane & 15;
    const int row0 = brow + wm * 128;

    if constexpr (EPI == 2) {
        const int col0 = bcol + wn * 64;
        float lsum = 0.f;
#pragma unroll
        for (int m = 0; m < 8; m++)
#pragma unroll
            for (int n = 0; n < 4; n++)
#pragma unroll
                for (int rg = 0; rg < 4; rg++) {
                    int gr = row0 + m * 16 + rl + rg;
                    int gc = col0 + n * 16 + cl;
                    float d = acc[m][n][rg] - aux_f32[(size_t)gr * ldc + gc];
                    lsum += d * d;
                }
#pragma unroll
        for (int msk = 1; msk < 64; msk <<= 1)
            lsum += __shfl_xor(lsum, msk, 64);
        if (lane == 0) atomicAdd(loss_accum, lsum);
        return;
    }

    // block-uniform output target (tiles are 256-wide; splitcol multiple of 256)
    void* Ceff = Cptr;
    bool second = false;
    int bcol_l = bcol;
    if constexpr (EPI == 0 || EPI == 4) {
        if (bcol >= splitcol) { Ceff = Cptr2; bcol_l = bcol - splitcol; second = true; }
    }
    const int col0 = bcol_l + wn * 64;

#pragma unroll
    for (int m = 0; m < 8; m++)
#pragma unroll
        for (int n = 0; n < 4; n++)
#pragma unroll
            for (int rg = 0; rg < 4; rg++) {
                int gr = row0 + m * 16 + rl + rg;
                int gc = col0 + n * 16 + cl;
                size_t idxo = (size_t)gr * ldc + gc;
                if constexpr (EPI == 0) {
                    ((unsigned short*)Ceff)[idxo] = f2bf(acc[m][n][rg]);
                } else if constexpr (EPI == 4) {
                    if (second) {
                        float t = acc[m][n][rg] + aux_f32[gc];
                        ((unsigned short*)Ceff)[idxo] = f2bf(1.f / (1.f + expf(-t)));
                    } else {
                        ((unsigned short*)Ceff)[idxo] = f2bf(acc[m][n][rg]);
                    }
                } else {  // EPI == 3
                    float gv = bf2f(aux_bf16[idxo]);
                    ((float*)Ceff)[idxo] = acc[m][n][rg] * gv;
                }
            }
#undef STAGE
#undef STAGE_G
#undef LDA_FRAG
#undef LDB_FRAG
#undef MFMA_Q
#undef READ_B
#undef READ_QA
}

// ---------- pmean[n][c] = mean_p prefix[n][p*2048 + c] ----------
__global__ __launch_bounds__(256) void pmean_kernel(
        const unsigned short* __restrict__ prefix, unsigned short* __restrict__ pm) {
    int i  = blockIdx.x * 256 + threadIdx.x;
    int n  = i >> 8;
    int c8 = (i & 255) * 8;
    float acc[8] = {0, 0, 0, 0, 0, 0, 0, 0};
#pragma unroll
    for (int p = 0; p < 8; p++) {
        const unsigned short* src = prefix + (size_t)n * 16384 + p * 2048 + c8;
        uint4 raw = *(const uint4*)src;
        unsigned w[4] = {raw.x, raw.y, raw.z, raw.w};
#pragma unroll
        for (int j = 0; j < 4; j++) {
            float2 fp = bfpair(w[j]);
            acc[2 * j] += fp.x; acc[2 * j + 1] += fp.y;
        }
    }
    uint4 o;
    unsigned* ow = (unsigned*)&o;
#pragma unroll
    for (int j = 0; j < 4; j++)
        ow[j] = (unsigned)f2bf(acc[2 * j] * 0.125f) |
                ((unsigned)f2bf(acc[2 * j + 1] * 0.125f) << 16);
    *(uint4*)(pm + (size_t)n * 2048 + c8) = o;
}

// ---------- attention: one wave per (n,h), P=8 keys, D=128 ----------
__global__ __launch_bounds__(256) void attn_kernel(
        const unsigned short* __restrict__ q, const unsigned short* __restrict__ k,
        const unsigned short* __restrict__ v, unsigned short* __restrict__ o) {
    int gw   = (blockIdx.x * 256 + threadIdx.x) >> 6;
    int lane = threadIdx.x & 63;
    int n = gw >> 4, h = gw & 15;
    size_t qoff = (size_t)n * 2048 + h * 128 + lane * 2;
    float2 qv = bfpair(*(const unsigned*)(q + qoff));
    float s[8];
#pragma unroll
    for (int p = 0; p < 8; p++) {
        size_t koff = (size_t)(n * 8 + p) * 2048 + h * 128 + lane * 2;
        float2 kv = bfpair(*(const unsigned*)(k + koff));
        float d = qv.x * kv.x + qv.y * kv.y;
#pragma unroll
        for (int msk = 1; msk < 64; msk <<= 1) d += __shfl_xor(d, msk, 64);
        s[p] = d * 0.08838834764831845f;
    }
    float mx = s[0];
#pragma unroll
    for (int p = 1; p < 8; p++) mx = fmaxf(mx, s[p]);
    float e[8], den = 0.f;
#pragma unroll
    for (int p = 0; p < 8; p++) { e[p] = expf(s[p] - mx); den += e[p]; }
    float inv = 1.f / den;
    float o0 = 0.f, o1 = 0.f;
#pragma unroll
    for (int p = 0; p < 8; p++) {
        size_t voff = (size_t)(n * 8 + p) * 2048 + h * 128 + lane * 2;
        float2 vv = bfpair(*(const unsigned*)(v + voff));
        float a = e[p] * inv;
        o0 += a * vv.x; o1 += a * vv.y;
    }
    *(unsigned*)(o + qoff) = (unsigned)f2bf(o0) | ((unsigned)f2bf(o1) << 16);
}

__global__ __launch_bounds__(64) void finalize_loss_kernel(
        const float* __restrict__ accum, float* __restrict__ dst) {
    if (threadIdx.x == 0) dst[0] = accum[0] * (1.0f / (4096.0f * 2048.0f));
}

// ---------- launch ----------
extern "C" void kernel_launch(void* const* d_in, const int* in_sizes, int n_in,
                              void* d_out, int out_size, void* d_ws, size_t ws_size,
                              hipStream_t stream) {
    const float* x    = (const float*)d_in[0];
    const float* rwkv = (const float*)d_in[1];
    const float* Wq   = (const float*)d_in[2];
    const float* Wk   = (const float*)d_in[3];
    const float* Wv   = (const float*)d_in[4];
    const float* Wo   = (const float*)d_in[5];
    const float* Wg   = (const float*)d_in[6];
    const float* bg   = (const float*)d_in[7];
    const float* Wb   = (const float*)d_in[8];
    const float* Wr   = (const float*)d_in[9];
    float* out = (float*)d_out;
    char*  ws  = (char*)d_ws;

    unsigned short* xs     = (unsigned short*)(ws + 0ull);
    unsigned short* wbT    = (unsigned short*)(ws + 33554432ull);    // 128MB, reused as kbuf
    unsigned short* wqT    = (unsigned short*)(ws + 167772160ull);   // qg pair adjacent
    unsigned short* wgT    = (unsigned short*)(ws + 176160768ull);
    unsigned short* wkT    = (unsigned short*)(ws + 184549376ull);   // kv pair adjacent
    unsigned short* wvT    = (unsigned short*)(ws + 192937984ull);
    unsigned short* wrT    = (unsigned short*)(ws + 201326592ull);
    unsigned short* woT    = (unsigned short*)(ws + 209715200ull);
    unsigned short* prefix = (unsigned short*)(ws + 218103808ull);   // 128MB
    unsigned short* vbuf   = (unsigned short*)(ws + 352321536ull);   // 128MB
    unsigned short* qbuf   = (unsigned short*)(ws + 486539264ull);
    unsigned short* gbuf   = (unsigned short*)(ws + 503316480ull);
    unsigned short* pmean  = (unsigned short*)(ws + 520093696ull);
    unsigned short* attno  = (unsigned short*)(ws + 536870912ull);
    float*          lossA  = (float*)(ws + 553648128ull);
    unsigned short* kbuf   = wbT;   // WbT dead after bridge GEMM

    const int SMEM = 131072;
    const int BIG = 1 << 30;
    hipFuncSetAttribute(reinterpret_cast<const void*>(gemm256<0>),
                        hipFuncAttributeMaxDynamicSharedMemorySize, SMEM);
    hipFuncSetAttribute(reinterpret_cast<const void*>(gemm256<2>),
                        hipFuncAttributeMaxDynamicSharedMemorySize, SMEM);
    hipFuncSetAttribute(reinterpret_cast<const void*>(gemm256<3>),
                        hipFuncAttributeMaxDynamicSharedMemorySize, SMEM);
    hipFuncSetAttribute(reinterpret_cast<const void*>(gemm256<4>),
                        hipFuncAttributeMaxDynamicSharedMemorySize, SMEM);

    hipMemsetAsync(lossA, 0, 16, stream);

    pack_xs_kernel<<<16384, 256, 0, stream>>>(x, rwkv, xs);
    transpose_cast_kernel<<<dim3(512, 128), 256, 0, stream>>>(Wb, wbT, 4096, 16384);
    transpose_cast_kernel<<<dim3(64, 64),  256, 0, stream>>>(Wq, wqT, 2048, 2048);
    transpose_cast_kernel<<<dim3(64, 64),  256, 0, stream>>>(Wg, wgT, 2048, 2048);
    transpose_cast_kernel<<<dim3(64, 64),  256, 0, stream>>>(Wk, wkT, 2048, 2048);
    transpose_cast_kernel<<<dim3(64, 64),  256, 0, stream>>>(Wv, wvT, 2048, 2048);
    transpose_cast_kernel<<<dim3(64, 64),  256, 0, stream>>>(Wr, wrT, 2048, 2048);
    transpose_cast_kernel<<<dim3(64, 64),  256, 0, stream>>>(Wo, woT, 2048, 2048);

    // prefix = xs @ Wb          M=4096 N=16384 K=4096 -> Mtiles=16 (bandH=2)
    gemm256<0><<<dim3(1024), 512, SMEM, stream>>>(xs, 4096, wbT, 4096,
        prefix, nullptr, 16384, BIG, 4096, 16, nullptr, nullptr, nullptr);
    // [k|v] = prefix @ [Wk|Wv]  M=32768 N=4096 K=2048 -> Mtiles=128 (bandH=16)
    gemm256<0><<<dim3(2048), 512, SMEM, stream>>>(prefix, 2048, wkT, 2048,
        kbuf, vbuf, 2048, 2048, 2048, 128, nullptr, nullptr, nullptr);
    // pmean = mean_p(prefix)
    pmean_kernel<<<4096, 256, 0, stream>>>(prefix, pmean);
    // [q|g] = x @ [Wq|Wg]       M=4096 N=4096 K=2048 -> Mtiles=16 (bandH=2)
    gemm256<4><<<dim3(256), 512, SMEM, stream>>>(xs, 4096, wqT, 2048,
        qbuf, gbuf, 2048, 2048, 2048, 16, bg, nullptr, nullptr);
    // recon loss: sum((pmean @ Wr - x)^2)   Mtiles=16 (bandH=2)
    gemm256<2><<<dim3(128), 512, SMEM, stream>>>(pmean, 2048, wrT, 2048,
        nullptr, nullptr, 2048, BIG, 2048, 16, x, nullptr, lossA);
    // attention
    attn_kernel<<<16384, 256, 0, stream>>>(qbuf, kbuf, vbuf, attno);
    // out = (attno @ Wo) * g    -> fp32 d_out   Mtiles=16 (bandH=2)
    gemm256<3><<<dim3(128), 512, SMEM, stream>>>(attno, 2048, woT, 2048,
        out, nullptr, 2048, BIG, 2048, 16, nullptr, gbuf, nullptr);

    finalize_loss_kernel<<<1, 64, 0, stream>>>(lossA, out + 8388608);
}

// Round 13
// 1267.941 us; speedup vs baseline: 1.1362x; 1.0444x over previous
//
#include <hip/hip_runtime.h>

#define DEVFN static __device__ __forceinline__

typedef __attribute__((ext_vector_type(8))) short short8;
typedef __attribute__((ext_vector_type(4))) float f32x4;

// ---------- bf16 helpers (raw ushort storage) ----------
DEVFN unsigned short f2bf(float f) {
    union { float f; unsigned u; } a; a.f = f;
    unsigned u = a.u;
    unsigned r = (u + 0x7FFFu + ((u >> 16) & 1u)) >> 16;   // RNE
    return (unsigned short)r;
}
DEVFN float bf2f(unsigned short b) {
    union { unsigned u; float f; } a; a.u = ((unsigned)b) << 16;
    return a.f;
}
DEVFN float2 bfpair(unsigned v) {
    float2 r;
    union { unsigned u; float f; } a;
    a.u = (v & 0xFFFFu) << 16; r.x = a.f;
    a.u = v & 0xFFFF0000u;     r.y = a.f;
    return r;
}

// ---------- async global->LDS (16B per lane, wave-uniform LDS base) ----------
DEVFN void gload16(const void* g, void* lds) {
    __builtin_amdgcn_global_load_lds(
        (const __attribute__((address_space(1))) unsigned int*)g,
        (__attribute__((address_space(3))) unsigned int*)lds, 16, 0, 0);
}

#define BAR() __builtin_amdgcn_s_barrier()
#define VMCNT8() asm volatile("s_waitcnt vmcnt(8)" ::: "memory")
#define VMCNT0() asm volatile("s_waitcnt vmcnt(0)" ::: "memory")

// ---------- prep: xs = [x | rwkv] cast bf16 ----------
__global__ __launch_bounds__(256) void pack_xs_kernel(
        const float* __restrict__ x, const float* __restrict__ r,
        unsigned short* __restrict__ xs) {
    int i = blockIdx.x * 256 + threadIdx.x;
    int n  = i >> 10;
    int cw = i & 1023;
    const float* src = (cw < 512) ? (x + (size_t)n * 2048 + cw * 4)
                                  : (r + (size_t)n * 2048 + (cw - 512) * 4);
    float4 v = *(const float4*)src;
    ushort4 o;
    o.x = f2bf(v.x); o.y = f2bf(v.y); o.z = f2bf(v.z); o.w = f2bf(v.w);
    *(ushort4*)(xs + (size_t)n * 4096 + cw * 4) = o;
}

// ---------- transpose+cast body (vectorized, R12) ----------
DEVFN void transpose_body(const float* __restrict__ in,
                          unsigned short* __restrict__ out,
                          int R, int Cc, int bx, int by) {
    __shared__ float tile[32][33];
    const int t  = threadIdx.x;
    const int r  = t >> 3;          // 0..31
    const int c4 = (t & 7) * 4;     // 0,4,...,28
    const int tr = by * 32, tc = bx * 32;
    float4 v = *(const float4*)(in + (size_t)(tr + r) * Cc + tc + c4);
    tile[r][c4 + 0] = v.x; tile[r][c4 + 1] = v.y;
    tile[r][c4 + 2] = v.z; tile[r][c4 + 3] = v.w;
    __syncthreads();
    const int orow = r, oc = c4;
    ushort4 o;
    o.x = f2bf(tile[oc + 0][orow]);
    o.y = f2bf(tile[oc + 1][orow]);
    o.z = f2bf(tile[oc + 2][orow]);
    o.w = f2bf(tile[oc + 3][orow]);
    *(ushort4*)(out + (size_t)(tc + orow) * R + tr + oc) = o;
}

__global__ __launch_bounds__(256) void transpose_cast_kernel(
        const float* __restrict__ in, unsigned short* __restrict__ out,
        int R, int Cc) {
    transpose_body(in, out, R, Cc, blockIdx.x, blockIdx.y);
}

// batched: six 2048x2048 weights in one launch (blockIdx.z selects)
__global__ __launch_bounds__(256) void transpose_cast6_kernel(
        const float* __restrict__ i0, const float* __restrict__ i1,
        const float* __restrict__ i2, const float* __restrict__ i3,
        const float* __restrict__ i4, const float* __restrict__ i5,
        unsigned short* __restrict__ o0, unsigned short* __restrict__ o1,
        unsigned short* __restrict__ o2, unsigned short* __restrict__ o3,
        unsigned short* __restrict__ o4, unsigned short* __restrict__ o5) {
    const float* in; unsigned short* out;
    switch (blockIdx.z) {
        case 0: in = i0; out = o0; break;
        case 1: in = i1; out = o1; break;
        case 2: in = i2; out = o2; break;
        case 3: in = i3; out = o3; break;
        case 4: in = i4; out = o4; break;
        default: in = i5; out = o5; break;
    }
    transpose_body(in, out, 2048, 2048, blockIdx.x, blockIdx.y);
}

// ============================================================================
// 256x256 8-phase GEMM: C[M,N] = A[M,K](bf16,row) * Bt[N,K](bf16,row)^T
// BK=64, 8 waves (2Mx4N), 128 KiB LDS, 8-slot XOR swizzle
// (phys = lin ^ ((lin>>7 & 7)<<4); pre-swizzled global src + swizzled ds_read).
// BANDED XCD MAPPING (R11) + SINGLE BARRIER PER PHASE (R10).
// Reads: ph1 = B+Aq0, ph2 = Aq1, ph3 = Aq2+Aq3, ph4 = none (mirror ph5-8).
// Stages: ph2: T(t0+2).B0, ph3: .B1, ph4: .A0+.A1 (mirror ph6-8 for t1+2).
// Ckpt vmcnt(8) after ph4/ph8 stages. LAST iteration -> vmcnt(0) (R5).
// EPI: 0 = bf16 store, block-level col split (Cptr/Cptr2 at splitcol);
//      4 = split: cols<splitcol bf16 -> Cptr, else sigmoid(acc+bg) -> Cptr2;
//      5 = TAIL MERGE (R13): blocks [0,G/2): loss sum((A@Bt - aux_f32)^2)
//          -> atomicAdd(loss_accum); blocks [G/2,G): (A2@Bt2)*bf2f(aux_bf16)
//          -> fp32 Cptr. Same geometry both halves (M=4096,N=2048,K=2048).
// ============================================================================
template <int EPI>
__global__ __launch_bounds__(512, 2) void gemm256(
        const unsigned short* __restrict__ A, int lda,
        const unsigned short* __restrict__ Bt, int ldb,
        void* __restrict__ Cptr, void* __restrict__ Cptr2,
        int ldc, int splitcol, int K, int Mtiles,
        const float* __restrict__ aux_f32,
        const unsigned short* __restrict__ aux_bf16,
        float* __restrict__ loss_accum,
        const unsigned short* __restrict__ A2,
        const unsigned short* __restrict__ Bt2) {
    extern __shared__ char smem[];   // 131072 B
    const int tid  = threadIdx.x;
    const int wid  = tid >> 6, lane = tid & 63;
    const int wm   = wid >> 2, wn = wid & 3;
    const int l15  = lane & 15;
    const int lhi  = (lane >> 4) * 16;         // byte offset of k-group
    const int nkt  = K >> 6;                   // K-tiles of 64

    int bid = blockIdx.x;
    bool sub1 = false;
    if constexpr (EPI == 5) {
        const int half = gridDim.x >> 1;
        if (bid >= half) { sub1 = true; bid -= half; A = A2; Bt = Bt2; }
    }

    // banded XCD mapping: nwg%8==0, Mtiles%8==0 guaranteed by caller
    const int bandH = Mtiles >> 3;
    const int xcd = bid & 7, idx = bid >> 3;
    const int brow = (xcd * bandH + (idx % bandH)) << 8;
    const int bcol = (idx / bandH) << 8;

    // per-thread stage addressing: chunk c = wid*2+j covers LDS [c*1024, +1024)
    // linear dest; SOURCE pre-swizzled: phys = lin ^ ((lin>>7 & 7)<<4)
    const int lin0 = (wid * 2 + 0) * 1024 + lane * 16;
    const int lin1 = (wid * 2 + 1) * 1024 + lane * 16;
    const int ph0 = lin0 ^ (((lin0 >> 7) & 7) << 4);
    const int ph1v = lin1 ^ (((lin1 >> 7) & 7) << 4);
    const int srow0 = ph0 >> 7, scol0 = (ph0 & 127) >> 1;
    const int srow1 = ph1v >> 7, scol1 = (ph1v & 127) >> 1;
    const int dst0 = (wid * 2 + 0) * 1024;
    const int dst1 = (wid * 2 + 1) * 1024;

    // stage half-tile: tile t, mat 0=A 1=B, half h (128 rows x 64 k-cols)
#define STAGE(t, mat, h) do { \
        char* base_ = smem + (((t) & 1) * 65536) + ((mat) * 32768) + ((h) * 16384); \
        const unsigned short* G_ = (mat) ? Bt : A; \
        const int ld_ = (mat) ? ldb : lda; \
        const int rb_ = ((mat) ? bcol : brow) + (h) * 128; \
        gload16(G_ + (size_t)(rb_ + srow0) * ld_ + (t) * 64 + scol0, base_ + dst0); \
        gload16(G_ + (size_t)(rb_ + srow1) * ld_ + (t) * 64 + scol1, base_ + dst1); \
    } while (0)
#define STAGE_G(t, mat, h) do { if ((t) < nkt) STAGE(t, mat, h); } while (0)

    // swizzled fragment reads
#define LDA_FRAG(dst, buf, m, kk) do { \
        int lin_ = ((m) * 16 + l15) * 128 + (kk) * 64 + lhi; \
        int ph_  = lin_ ^ (((lin_ >> 7) & 7) << 4); \
        dst = *(const short8*)(smem + (buf) * 65536 + wm * 16384 + ph_); \
    } while (0)
#define LDB_FRAG(dst, buf, n, kk) do { \
        int lin_ = ((wn & 1) * 64 + (n) * 16 + l15) * 128 + (kk) * 64 + lhi; \
        int ph_  = lin_ ^ (((lin_ >> 7) & 7) << 4); \
        dst = *(const short8*)(smem + (buf) * 65536 + 32768 + (wn >> 1) * 16384 + ph_); \
    } while (0)

    f32x4 acc[8][4] = {};
    short8 afr[8][2], bfr[4][2];

#define MFMA_Q(mq) do { \
        __builtin_amdgcn_s_setprio(1); \
        _Pragma("unroll") \
        for (int n_ = 0; n_ < 4; ++n_) { \
            acc[2*(mq)][n_]   = __builtin_amdgcn_mfma_f32_16x16x32_bf16(afr[2*(mq)][0],   bfr[n_][0], acc[2*(mq)][n_],   0,0,0); \
            acc[2*(mq)][n_]   = __builtin_amdgcn_mfma_f32_16x16x32_bf16(afr[2*(mq)][1],   bfr[n_][1], acc[2*(mq)][n_],   0,0,0); \
            acc[2*(mq)+1][n_] = __builtin_amdgcn_mfma_f32_16x16x32_bf16(afr[2*(mq)+1][0], bfr[n_][0], acc[2*(mq)+1][n_], 0,0,0); \
            acc[2*(mq)+1][n_] = __builtin_amdgcn_mfma_f32_16x16x32_bf16(afr[2*(mq)+1][1], bfr[n_][1], acc[2*(mq)+1][n_], 0,0,0); \
        } \
        __builtin_amdgcn_s_setprio(0); \
    } while (0)

#define READ_B(b) do { \
        _Pragma("unroll") \
        for (int n_ = 0; n_ < 4; ++n_) { LDB_FRAG(bfr[n_][0], b, n_, 0); LDB_FRAG(bfr[n_][1], b, n_, 1); } \
    } while (0)
#define READ_QA(b, mq) do { \
        LDA_FRAG(afr[2*(mq)][0],   b, 2*(mq),   0); LDA_FRAG(afr[2*(mq)][1],   b, 2*(mq),   1); \
        LDA_FRAG(afr[2*(mq)+1][0], b, 2*(mq)+1, 0); LDA_FRAG(afr[2*(mq)+1][1], b, 2*(mq)+1, 1); \
    } while (0)

    // ---- prologue: T0 + T1 fully staged (16 loads); drain T0 ----
    STAGE(0, 1, 0); STAGE(0, 1, 1); STAGE(0, 0, 0); STAGE(0, 0, 1);
    STAGE_G(1, 1, 0); STAGE_G(1, 1, 1); STAGE_G(1, 0, 0); STAGE_G(1, 0, 1);
    VMCNT8();        // T0 landed (newest 8 = T1 full)
    BAR();

    const int niter = nkt >> 1;
    for (int it = 0; it < niter; ++it) {
        const int t0 = it * 2, t1 = t0 + 1;
        const bool lastIt = (it == niter - 1);

        // ===== group A: tile t0 in buf 0 (one barrier per phase) =====
        READ_B(0); READ_QA(0, 0);
        BAR();
        MFMA_Q(0);
        READ_QA(0, 1);
        STAGE_G(t0 + 2, 1, 0);
        BAR();
        MFMA_Q(1);
        READ_QA(0, 2); READ_QA(0, 3);
        STAGE_G(t0 + 2, 1, 1);
        BAR();
        MFMA_Q(2);
        STAGE_G(t0 + 2, 0, 0); STAGE_G(t0 + 2, 0, 1);
        if (lastIt) { VMCNT0(); } else { VMCNT8(); }   // drain tile t1 (buf1)
        BAR();
        MFMA_Q(3);

        // ===== group B: tile t1 in buf 1 =====
        READ_B(1); READ_QA(1, 0);
        BAR();
        MFMA_Q(0);
        READ_QA(1, 1);
        STAGE_G(t1 + 2, 1, 0);
        BAR();
        MFMA_Q(1);
        READ_QA(1, 2); READ_QA(1, 3);
        STAGE_G(t1 + 2, 1, 1);
        BAR();
        MFMA_Q(2);
        STAGE_G(t1 + 2, 0, 0); STAGE_G(t1 + 2, 0, 1);
        if (lastIt) { VMCNT0(); } else { VMCNT8(); }   // drain tile t0+2 (buf0)
        BAR();
        MFMA_Q(3);
    }

    // ---- epilogue: C/D layout col = lane&15, row = (lane>>4)*4 + reg ----
    const int rl = (lane >> 4) * 4;
    const int cl = lane & 15;
    const int row0 = brow + wm * 128;

    if constexpr (EPI == 5) {
        const int col0 = bcol + wn * 64;
        if (!sub1) {
            // loss: sum((acc - x)^2) -> atomicAdd
            float lsum = 0.f;
#pragma unroll
            for (int m = 0; m < 8; m++)
#pragma unroll
                for (int n = 0; n < 4; n++)
#pragma unroll
                    for (int rg = 0; rg < 4; rg++) {
                        int gr = row0 + m * 16 + rl + rg;
                        int gc = col0 + n * 16 + cl;
                        float d = acc[m][n][rg] - aux_f32[(size_t)gr * ldc + gc];
                        lsum += d * d;
                    }
#pragma unroll
            for (int msk = 1; msk < 64; msk <<= 1)
                lsum += __shfl_xor(lsum, msk, 64);
            if (lane == 0) atomicAdd(loss_accum, lsum);
        } else {
            // wo: fp32 store acc * bf2f(g)
#pragma unroll
            for (int m = 0; m < 8; m++)
#pragma unroll
                for (int n = 0; n < 4; n++)
#pragma unroll
                    for (int rg = 0; rg < 4; rg++) {
                        int gr = row0 + m * 16 + rl + rg;
                        int gc = col0 + n * 16 + cl;
                        size_t idxo = (size_t)gr * ldc + gc;
                        float gv = bf2f(aux_bf16[idxo]);
                        ((float*)Cptr)[idxo] = acc[m][n][rg] * gv;
                    }
        }
        return;
    }

    // block-uniform output target (tiles are 256-wide; splitcol multiple of 256)
    void* Ceff = Cptr;
    bool second = false;
    int bcol_l = bcol;
    if constexpr (EPI == 0 || EPI == 4) {
        if (bcol >= splitcol) { Ceff = Cptr2; bcol_l = bcol - splitcol; second = true; }
    }
    const int col0 = bcol_l + wn * 64;

#pragma unroll
    for (int m = 0; m < 8; m++)
#pragma unroll
        for (int n = 0; n < 4; n++)
#pragma unroll
            for (int rg = 0; rg < 4; rg++) {
                int gr = row0 + m * 16 + rl + rg;
                int gc = col0 + n * 16 + cl;
                size_t idxo = (size_t)gr * ldc + gc;
                if constexpr (EPI == 0) {
                    ((unsigned short*)Ceff)[idxo] = f2bf(acc[m][n][rg]);
                } else {  // EPI == 4
                    if (second) {
                        float t = acc[m][n][rg] + aux_f32[gc];
                        ((unsigned short*)Ceff)[idxo] = f2bf(1.f / (1.f + expf(-t)));
                    } else {
                        ((unsigned short*)Ceff)[idxo] = f2bf(acc[m][n][rg]);
                    }
                }
            }
#undef STAGE
#undef STAGE_G
#undef LDA_FRAG
#undef LDB_FRAG
#undef MFMA_Q
#undef READ_B
#undef READ_QA
}

// ---------- pmean[n][c] = mean_p prefix[n][p*2048 + c] ----------
__global__ __launch_bounds__(256) void pmean_kernel(
        const unsigned short* __restrict__ prefix, unsigned short* __restrict__ pm) {
    int i  = blockIdx.x * 256 + threadIdx.x;
    int n  = i >> 8;
    int c8 = (i & 255) * 8;
    float acc[8] = {0, 0, 0, 0, 0, 0, 0, 0};
#pragma unroll
    for (int p = 0; p < 8; p++) {
        const unsigned short* src = prefix + (size_t)n * 16384 + p * 2048 + c8;
        uint4 raw = *(const uint4*)src;
        unsigned w[4] = {raw.x, raw.y, raw.z, raw.w};
#pragma unroll
        for (int j = 0; j < 4; j++) {
            float2 fp = bfpair(w[j]);
            acc[2 * j] += fp.x; acc[2 * j + 1] += fp.y;
        }
    }
    uint4 o;
    unsigned* ow = (unsigned*)&o;
#pragma unroll
    for (int j = 0; j < 4; j++)
        ow[j] = (unsigned)f2bf(acc[2 * j] * 0.125f) |
                ((unsigned)f2bf(acc[2 * j + 1] * 0.125f) << 16);
    *(uint4*)(pm + (size_t)n * 2048 + c8) = o;
}

// ---------- attention: one wave per (n,h), P=8 keys, D=128 ----------
__global__ __launch_bounds__(256) void attn_kernel(
        const unsigned short* __restrict__ q, const unsigned short* __restrict__ k,
        const unsigned short* __restrict__ v, unsigned short* __restrict__ o) {
    int gw   = (blockIdx.x * 256 + threadIdx.x) >> 6;
    int lane = threadIdx.x & 63;
    int n = gw >> 4, h = gw & 15;
    size_t qoff = (size_t)n * 2048 + h * 128 + lane * 2;
    float2 qv = bfpair(*(const unsigned*)(q + qoff));
    float s[8];
#pragma unroll
    for (int p = 0; p < 8; p++) {
        size_t koff = (size_t)(n * 8 + p) * 2048 + h * 128 + lane * 2;
        float2 kv = bfpair(*(const unsigned*)(k + koff));
        float d = qv.x * kv.x + qv.y * kv.y;
#pragma unroll
        for (int msk = 1; msk < 64; msk <<= 1) d += __shfl_xor(d, msk, 64);
        s[p] = d * 0.08838834764831845f;
    }
    float mx = s[0];
#pragma unroll
    for (int p = 1; p < 8; p++) mx = fmaxf(mx, s[p]);
    float e[8], den = 0.f;
#pragma unroll
    for (int p = 0; p < 8; p++) { e[p] = expf(s[p] - mx); den += e[p]; }
    float inv = 1.f / den;
    float o0 = 0.f, o1 = 0.f;
#pragma unroll
    for (int p = 0; p < 8; p++) {
        size_t voff = (size_t)(n * 8 + p) * 2048 + h * 128 + lane * 2;
        float2 vv = bfpair(*(const unsigned*)(v + voff));
        float a = e[p] * inv;
        o0 += a * vv.x; o1 += a * vv.y;
    }
    *(unsigned*)(o + qoff) = (unsigned)f2bf(o0) | ((unsigned)f2bf(o1) << 16);
}

__global__ __launch_bounds__(64) void finalize_loss_kernel(
        const float* __restrict__ accum, float* __restrict__ dst) {
    if (threadIdx.x == 0) dst[0] = accum[0] * (1.0f / (4096.0f * 2048.0f));
}

// ---------- launch ----------
extern "C" void kernel_launch(void* const* d_in, const int* in_sizes, int n_in,
                              void* d_out, int out_size, void* d_ws, size_t ws_size,
                              hipStream_t stream) {
    const float* x    = (const float*)d_in[0];
    const float* rwkv = (const float*)d_in[1];
    const float* Wq   = (const float*)d_in[2];
    const float* Wk   = (const float*)d_in[3];
    const float* Wv   = (const float*)d_in[4];
    const float* Wo   = (const float*)d_in[5];
    const float* Wg   = (const float*)d_in[6];
    const float* bg   = (const float*)d_in[7];
    const float* Wb   = (const float*)d_in[8];
    const float* Wr   = (const float*)d_in[9];
    float* out = (float*)d_out;
    char*  ws  = (char*)d_ws;

    unsigned short* xs     = (unsigned short*)(ws + 0ull);
    unsigned short* wbT    = (unsigned short*)(ws + 33554432ull);    // 128MB, reused as kbuf
    unsigned short* wqT    = (unsigned short*)(ws + 167772160ull);   // qg pair adjacent
    unsigned short* wgT    = (unsigned short*)(ws + 176160768ull);
    unsigned short* wkT    = (unsigned short*)(ws + 184549376ull);   // kv pair adjacent
    unsigned short* wvT    = (unsigned short*)(ws + 192937984ull);
    unsigned short* wrT    = (unsigned short*)(ws + 201326592ull);
    unsigned short* woT    = (unsigned short*)(ws + 209715200ull);
    unsigned short* prefix = (unsigned short*)(ws + 218103808ull);   // 128MB
    unsigned short* vbuf   = (unsigned short*)(ws + 352321536ull);   // 128MB
    unsigned short* qbuf   = (unsigned short*)(ws + 486539264ull);
    unsigned short* gbuf   = (unsigned short*)(ws + 503316480ull);
    unsigned short* pmean  = (unsigned short*)(ws + 520093696ull);
    unsigned short* attno  = (unsigned short*)(ws + 536870912ull);
    float*          lossA  = (float*)(ws + 553648128ull);
    unsigned short* kbuf   = wbT;   // WbT dead after bridge GEMM

    const int SMEM = 131072;
    const int BIG = 1 << 30;
    hipFuncSetAttribute(reinterpret_cast<const void*>(gemm256<0>),
                        hipFuncAttributeMaxDynamicSharedMemorySize, SMEM);
    hipFuncSetAttribute(reinterpret_cast<const void*>(gemm256<4>),
                        hipFuncAttributeMaxDynamicSharedMemorySize, SMEM);
    hipFuncSetAttribute(reinterpret_cast<const void*>(gemm256<5>),
                        hipFuncAttributeMaxDynamicSharedMemorySize, SMEM);

    hipMemsetAsync(lossA, 0, 16, stream);

    pack_xs_kernel<<<16384, 256, 0, stream>>>(x, rwkv, xs);
    transpose_cast_kernel<<<dim3(512, 128), 256, 0, stream>>>(Wb, wbT, 4096, 16384);
    transpose_cast6_kernel<<<dim3(64, 64, 6), 256, 0, stream>>>(
        Wq, Wg, Wk, Wv, Wr, Wo, wqT, wgT, wkT, wvT, wrT, woT);

    // prefix = xs @ Wb          M=4096 N=16384 K=4096 -> Mtiles=16 (bandH=2)
    gemm256<0><<<dim3(1024), 512, SMEM, stream>>>(xs, 4096, wbT, 4096,
        prefix, nullptr, 16384, BIG, 4096, 16, nullptr, nullptr, nullptr,
        nullptr, nullptr);
    // [k|v] = prefix @ [Wk|Wv]  M=32768 N=4096 K=2048 -> Mtiles=128 (bandH=16)
    gemm256<0><<<dim3(2048), 512, SMEM, stream>>>(prefix, 2048, wkT, 2048,
        kbuf, vbuf, 2048, 2048, 2048, 128, nullptr, nullptr, nullptr,
        nullptr, nullptr);
    // pmean = mean_p(prefix)
    pmean_kernel<<<4096, 256, 0, stream>>>(prefix, pmean);
    // [q|g] = x @ [Wq|Wg]       M=4096 N=4096 K=2048 -> Mtiles=16 (bandH=2)
    gemm256<4><<<dim3(256), 512, SMEM, stream>>>(xs, 4096, wqT, 2048,
        qbuf, gbuf, 2048, 2048, 2048, 16, bg, nullptr, nullptr,
        nullptr, nullptr);
    // attention
    attn_kernel<<<16384, 256, 0, stream>>>(qbuf, kbuf, vbuf, attno);
    // TAIL (R13): blocks 0-127: loss sum((pmean@Wr - x)^2);
    //             blocks 128-255: out = (attno@Wo)*g -> fp32 d_out
    gemm256<5><<<dim3(256), 512, SMEM, stream>>>(pmean, 2048, wrT, 2048,
        out, nullptr, 2048, BIG, 2048, 16, x, gbuf, lossA,
        attno, woT);

    finalize_loss_kernel<<<1, 64, 0, stream>>>(lossA, out + 8388608);
}

// Round 14
// 1267.218 us; speedup vs baseline: 1.1369x; 1.0006x over previous
//
#include <hip/hip_runtime.h>

#define DEVFN static __device__ __forceinline__

typedef __attribute__((ext_vector_type(8))) short short8;
typedef __attribute__((ext_vector_type(4))) float f32x4;

// ---------- bf16 helpers (raw ushort storage) ----------
DEVFN unsigned short f2bf(float f) {
    union { float f; unsigned u; } a; a.f = f;
    unsigned u = a.u;
    unsigned r = (u + 0x7FFFu + ((u >> 16) & 1u)) >> 16;   // RNE
    return (unsigned short)r;
}
DEVFN float bf2f(unsigned short b) {
    union { unsigned u; float f; } a; a.u = ((unsigned)b) << 16;
    return a.f;
}
DEVFN float2 bfpair(unsigned v) {
    float2 r;
    union { unsigned u; float f; } a;
    a.u = (v & 0xFFFFu) << 16; r.x = a.f;
    a.u = v & 0xFFFF0000u;     r.y = a.f;
    return r;
}

// ---------- async global->LDS (16B per lane, wave-uniform LDS base) ----------
DEVFN void gload16(const void* g, void* lds) {
    __builtin_amdgcn_global_load_lds(
        (const __attribute__((address_space(1))) unsigned int*)g,
        (__attribute__((address_space(3))) unsigned int*)lds, 16, 0, 0);
}

#define BAR() __builtin_amdgcn_s_barrier()
#define VMCNT4() asm volatile("s_waitcnt vmcnt(4)" ::: "memory")
#define VMCNT0() asm volatile("s_waitcnt vmcnt(0)" ::: "memory")

// ---------- merged prep kernel bodies ----------
DEVFN void pack_xs_body(const float* __restrict__ x, const float* __restrict__ r,
                        unsigned short* __restrict__ xs, int blk) {
    int i = blk * 256 + threadIdx.x;
    int n  = i >> 10;
    int cw = i & 1023;
    const float* src = (cw < 512) ? (x + (size_t)n * 2048 + cw * 4)
                                  : (r + (size_t)n * 2048 + (cw - 512) * 4);
    float4 v = *(const float4*)src;
    ushort4 o;
    o.x = f2bf(v.x); o.y = f2bf(v.y); o.z = f2bf(v.z); o.w = f2bf(v.w);
    *(ushort4*)(xs + (size_t)n * 4096 + cw * 4) = o;
}

DEVFN void transpose_body(const float* __restrict__ in,
                          unsigned short* __restrict__ out,
                          int R, int Cc, int bx, int by) {
    __shared__ float tile[32][33];
    const int t  = threadIdx.x;
    const int r  = t >> 3;          // 0..31
    const int c4 = (t & 7) * 4;     // 0,4,...,28
    const int tr = by * 32, tc = bx * 32;
    float4 v = *(const float4*)(in + (size_t)(tr + r) * Cc + tc + c4);
    tile[r][c4 + 0] = v.x; tile[r][c4 + 1] = v.y;
    tile[r][c4 + 2] = v.z; tile[r][c4 + 3] = v.w;
    __syncthreads();
    const int orow = r, oc = c4;
    ushort4 o;
    o.x = f2bf(tile[oc + 0][orow]);
    o.y = f2bf(tile[oc + 1][orow]);
    o.z = f2bf(tile[oc + 2][orow]);
    o.w = f2bf(tile[oc + 3][orow]);
    *(ushort4*)(out + (size_t)(tc + orow) * R + tr + oc) = o;
}

// one launch: pack_xs (16384) + Wb transpose (65536) + six 2048^2 (24576)
__global__ __launch_bounds__(256) void prep_kernel(
        const float* __restrict__ x, const float* __restrict__ rwkv,
        unsigned short* __restrict__ xs,
        const float* __restrict__ Wb, unsigned short* __restrict__ wbT,
        const float* __restrict__ i0, const float* __restrict__ i1,
        const float* __restrict__ i2, const float* __restrict__ i3,
        const float* __restrict__ i4, const float* __restrict__ i5,
        unsigned short* __restrict__ o0, unsigned short* __restrict__ o1,
        unsigned short* __restrict__ o2, unsigned short* __restrict__ o3,
        unsigned short* __restrict__ o4, unsigned short* __restrict__ o5) {
    int b = blockIdx.x;
    if (b < 16384) { pack_xs_body(x, rwkv, xs, b); return; }
    b -= 16384;
    if (b < 65536) { transpose_body(Wb, wbT, 4096, 16384, b & 511, b >> 9); return; }
    b -= 65536;
    const int z = b >> 12, rem = b & 4095;
    const float* in; unsigned short* out;
    switch (z) {
        case 0: in = i0; out = o0; break;
        case 1: in = i1; out = o1; break;
        case 2: in = i2; out = o2; break;
        case 3: in = i3; out = o3; break;
        case 4: in = i4; out = o4; break;
        default: in = i5; out = o5; break;
    }
    transpose_body(in, out, 2048, 2048, rem & 63, rem >> 6);
}

// ============================================================================
// 256x256 GEMM, 4-PHASE K-tile-pair schedule (R14): C = A * Bt^T
// BK=64, 8 waves (2Mx4N), 128 KiB LDS, 8-slot XOR swizzle, banded XCD map,
// single barrier per phase, 32-MFMA clusters.
//   P1: read B+Aq0+Aq1(buf0) | stage t1.A0+A1->buf1    | BAR | MFMA Q0,Q1
//   P2: read Aq2+Aq3(buf0)   | stage t0+2.B0+B1->buf0  | a=vmcnt(4) | BAR | Q2,Q3
//   P3: read B+Aq0+Aq1(buf1) | stage t0+2.A0+A1->buf0  | BAR | MFMA Q0,Q1
//   P4: read Aq2+Aq3(buf1)   | stage t1+2.B0+B1->buf1  | b=vmcnt(4) | BAR | Q2,Q3
// a drains t1 (for P3); b drains t0+2 (for next P1). WAR: every staged
// region's reads issued >=1 phase (barrier) earlier — same contract as R13.
// LAST iteration: stages skipped -> both ckpts vmcnt(0) (R5 lesson).
// Prologue: T0 full + T1.B (12 loads), vmcnt(4).
// EPI: 0 = bf16 store (col split Cptr/Cptr2 at splitcol);
//      4 = split: plain bf16 | sigmoid(acc+bg);
//      5 = tail merge: half loss->atomicAdd, half (A2@Bt2)*g -> fp32.
// ============================================================================
template <int EPI>
__global__ __launch_bounds__(512, 2) void gemm256(
        const unsigned short* __restrict__ A, int lda,
        const unsigned short* __restrict__ Bt, int ldb,
        void* __restrict__ Cptr, void* __restrict__ Cptr2,
        int ldc, int splitcol, int K, int Mtiles,
        const float* __restrict__ aux_f32,
        const unsigned short* __restrict__ aux_bf16,
        float* __restrict__ loss_accum,
        const unsigned short* __restrict__ A2,
        const unsigned short* __restrict__ Bt2) {
    extern __shared__ char smem[];   // 131072 B
    const int tid  = threadIdx.x;
    const int wid  = tid >> 6, lane = tid & 63;
    const int wm   = wid >> 2, wn = wid & 3;
    const int l15  = lane & 15;
    const int lhi  = (lane >> 4) * 16;
    const int nkt  = K >> 6;

    int bid = blockIdx.x;
    bool sub1 = false;
    if constexpr (EPI == 5) {
        const int half = gridDim.x >> 1;
        if (bid >= half) { sub1 = true; bid -= half; A = A2; Bt = Bt2; }
    }

    // banded XCD mapping: nwg%8==0, Mtiles%8==0 guaranteed by caller
    const int bandH = Mtiles >> 3;
    const int xcd = bid & 7, idx = bid >> 3;
    const int brow = (xcd * bandH + (idx % bandH)) << 8;
    const int bcol = (idx / bandH) << 8;

    // stage addressing: linear dest; SOURCE pre-swizzled (lin ^ ((lin>>7&7)<<4))
    const int lin0 = (wid * 2 + 0) * 1024 + lane * 16;
    const int lin1 = (wid * 2 + 1) * 1024 + lane * 16;
    const int ph0 = lin0 ^ (((lin0 >> 7) & 7) << 4);
    const int ph1v = lin1 ^ (((lin1 >> 7) & 7) << 4);
    const int srow0 = ph0 >> 7, scol0 = (ph0 & 127) >> 1;
    const int srow1 = ph1v >> 7, scol1 = (ph1v & 127) >> 1;
    const int dst0 = (wid * 2 + 0) * 1024;
    const int dst1 = (wid * 2 + 1) * 1024;

#define STAGE(t, mat, h) do { \
        char* base_ = smem + (((t) & 1) * 65536) + ((mat) * 32768) + ((h) * 16384); \
        const unsigned short* G_ = (mat) ? Bt : A; \
        const int ld_ = (mat) ? ldb : lda; \
        const int rb_ = ((mat) ? bcol : brow) + (h) * 128; \
        gload16(G_ + (size_t)(rb_ + srow0) * ld_ + (t) * 64 + scol0, base_ + dst0); \
        gload16(G_ + (size_t)(rb_ + srow1) * ld_ + (t) * 64 + scol1, base_ + dst1); \
    } while (0)
#define STAGE_G(t, mat, h) do { if ((t) < nkt) STAGE(t, mat, h); } while (0)

#define LDA_FRAG(dst, buf, m, kk) do { \
        int lin_ = ((m) * 16 + l15) * 128 + (kk) * 64 + lhi; \
        int ph_  = lin_ ^ (((lin_ >> 7) & 7) << 4); \
        dst = *(const short8*)(smem + (buf) * 65536 + wm * 16384 + ph_); \
    } while (0)
#define LDB_FRAG(dst, buf, n, kk) do { \
        int lin_ = ((wn & 1) * 64 + (n) * 16 + l15) * 128 + (kk) * 64 + lhi; \
        int ph_  = lin_ ^ (((lin_ >> 7) & 7) << 4); \
        dst = *(const short8*)(smem + (buf) * 65536 + 32768 + (wn >> 1) * 16384 + ph_); \
    } while (0)

    f32x4 acc[8][4] = {};
    short8 afr[8][2], bfr[4][2];

#define MFMA_Q(mq) do { \
        __builtin_amdgcn_s_setprio(1); \
        _Pragma("unroll") \
        for (int n_ = 0; n_ < 4; ++n_) { \
            acc[2*(mq)][n_]   = __builtin_amdgcn_mfma_f32_16x16x32_bf16(afr[2*(mq)][0],   bfr[n_][0], acc[2*(mq)][n_],   0,0,0); \
            acc[2*(mq)][n_]   = __builtin_amdgcn_mfma_f32_16x16x32_bf16(afr[2*(mq)][1],   bfr[n_][1], acc[2*(mq)][n_],   0,0,0); \
            acc[2*(mq)+1][n_] = __builtin_amdgcn_mfma_f32_16x16x32_bf16(afr[2*(mq)+1][0], bfr[n_][0], acc[2*(mq)+1][n_], 0,0,0); \
            acc[2*(mq)+1][n_] = __builtin_amdgcn_mfma_f32_16x16x32_bf16(afr[2*(mq)+1][1], bfr[n_][1], acc[2*(mq)+1][n_], 0,0,0); \
        } \
        __builtin_amdgcn_s_setprio(0); \
    } while (0)

#define READ_B(b) do { \
        _Pragma("unroll") \
        for (int n_ = 0; n_ < 4; ++n_) { LDB_FRAG(bfr[n_][0], b, n_, 0); LDB_FRAG(bfr[n_][1], b, n_, 1); } \
    } while (0)
#define READ_QA(b, mq) do { \
        LDA_FRAG(afr[2*(mq)][0],   b, 2*(mq),   0); LDA_FRAG(afr[2*(mq)][1],   b, 2*(mq),   1); \
        LDA_FRAG(afr[2*(mq)+1][0], b, 2*(mq)+1, 0); LDA_FRAG(afr[2*(mq)+1][1], b, 2*(mq)+1, 1); \
    } while (0)

    // ---- prologue: T0 full + T1.B (12 loads); drain T0, leave T1.B ----
    STAGE(0, 1, 0); STAGE(0, 1, 1); STAGE(0, 0, 0); STAGE(0, 0, 1);
    STAGE_G(1, 1, 0); STAGE_G(1, 1, 1);
    VMCNT4();
    BAR();

    const int niter = nkt >> 1;
    for (int it = 0; it < niter; ++it) {
        const int t0 = it * 2, t1 = t0 + 1;
        const bool lastIt = (it == niter - 1);

        // P1: reads B+Aq0+Aq1 (buf0); stage t1.A -> buf1
        READ_B(0); READ_QA(0, 0); READ_QA(0, 1);
        STAGE_G(t1, 0, 0); STAGE_G(t1, 0, 1);
        BAR();
        MFMA_Q(0); MFMA_Q(1);
        // P2: reads Aq2+Aq3 (buf0); stage t0+2.B -> buf0; alpha ckpt
        READ_QA(0, 2); READ_QA(0, 3);
        STAGE_G(t0 + 2, 1, 0); STAGE_G(t0 + 2, 1, 1);
        if (lastIt) { VMCNT0(); } else { VMCNT4(); }   // drain t1 for P3
        BAR();
        MFMA_Q(2); MFMA_Q(3);
        // P3: reads B+Aq0+Aq1 (buf1); stage t0+2.A -> buf0
        READ_B(1); READ_QA(1, 0); READ_QA(1, 1);
        STAGE_G(t0 + 2, 0, 0); STAGE_G(t0 + 2, 0, 1);
        BAR();
        MFMA_Q(0); MFMA_Q(1);
        // P4: reads Aq2+Aq3 (buf1); stage t1+2.B -> buf1; beta ckpt
        READ_QA(1, 2); READ_QA(1, 3);
        STAGE_G(t1 + 2, 1, 0); STAGE_G(t1 + 2, 1, 1);
        if (lastIt) { VMCNT0(); } else { VMCNT4(); }   // drain t0+2 for next P1
        BAR();
        MFMA_Q(2); MFMA_Q(3);
    }

    // ---- epilogue: C/D layout col = lane&15, row = (lane>>4)*4 + reg ----
    const int rl = (lane >> 4) * 4;
    const int cl = lane & 15;
    const int row0 = brow + wm * 128;

    if constexpr (EPI == 5) {
        const int col0 = bcol + wn * 64;
        if (!sub1) {
            float lsum = 0.f;
#pragma unroll
            for (int m = 0; m < 8; m++)
#pragma unroll
                for (int n = 0; n < 4; n++)
#pragma unroll
                    for (int rg = 0; rg < 4; rg++) {
                        int gr = row0 + m * 16 + rl + rg;
                        int gc = col0 + n * 16 + cl;
                        float d = acc[m][n][rg] - aux_f32[(size_t)gr * ldc + gc];
                        lsum += d * d;
                    }
#pragma unroll
            for (int msk = 1; msk < 64; msk <<= 1)
                lsum += __shfl_xor(lsum, msk, 64);
            if (lane == 0) atomicAdd(loss_accum, lsum);
        } else {
#pragma unroll
            for (int m = 0; m < 8; m++)
#pragma unroll
                for (int n = 0; n < 4; n++)
#pragma unroll
                    for (int rg = 0; rg < 4; rg++) {
                        int gr = row0 + m * 16 + rl + rg;
                        int gc = col0 + n * 16 + cl;
                        size_t idxo = (size_t)gr * ldc + gc;
                        float gv = bf2f(aux_bf16[idxo]);
                        ((float*)Cptr)[idxo] = acc[m][n][rg] * gv;
                    }
        }
        return;
    }

    void* Ceff = Cptr;
    bool second = false;
    int bcol_l = bcol;
    if constexpr (EPI == 0 || EPI == 4) {
        if (bcol >= splitcol) { Ceff = Cptr2; bcol_l = bcol - splitcol; second = true; }
    }
    const int col0 = bcol_l + wn * 64;

#pragma unroll
    for (int m = 0; m < 8; m++)
#pragma unroll
        for (int n = 0; n < 4; n++)
#pragma unroll
            for (int rg = 0; rg < 4; rg++) {
                int gr = row0 + m * 16 + rl + rg;
                int gc = col0 + n * 16 + cl;
                size_t idxo = (size_t)gr * ldc + gc;
                if constexpr (EPI == 0) {
                    ((unsigned short*)Ceff)[idxo] = f2bf(acc[m][n][rg]);
                } else {  // EPI == 4
                    if (second) {
                        float t = acc[m][n][rg] + aux_f32[gc];
                        ((unsigned short*)Ceff)[idxo] = f2bf(1.f / (1.f + expf(-t)));
                    } else {
                        ((unsigned short*)Ceff)[idxo] = f2bf(acc[m][n][rg]);
                    }
                }
            }
#undef STAGE
#undef STAGE_G
#undef LDA_FRAG
#undef LDB_FRAG
#undef MFMA_Q
#undef READ_B
#undef READ_QA
}

// ---------- pmean[n][c] = mean_p prefix[n][p*2048 + c] ----------
__global__ __launch_bounds__(256) void pmean_kernel(
        const unsigned short* __restrict__ prefix, unsigned short* __restrict__ pm) {
    int i  = blockIdx.x * 256 + threadIdx.x;
    int n  = i >> 8;
    int c8 = (i & 255) * 8;
    float acc[8] = {0, 0, 0, 0, 0, 0, 0, 0};
#pragma unroll
    for (int p = 0; p < 8; p++) {
        const unsigned short* src = prefix + (size_t)n * 16384 + p * 2048 + c8;
        uint4 raw = *(const uint4*)src;
        unsigned w[4] = {raw.x, raw.y, raw.z, raw.w};
#pragma unroll
        for (int j = 0; j < 4; j++) {
            float2 fp = bfpair(w[j]);
            acc[2 * j] += fp.x; acc[2 * j + 1] += fp.y;
        }
    }
    uint4 o;
    unsigned* ow = (unsigned*)&o;
#pragma unroll
    for (int j = 0; j < 4; j++)
        ow[j] = (unsigned)f2bf(acc[2 * j] * 0.125f) |
                ((unsigned)f2bf(acc[2 * j + 1] * 0.125f) << 16);
    *(uint4*)(pm + (size_t)n * 2048 + c8) = o;
}

// ---------- attention: one wave per (n,h), P=8 keys, D=128 ----------
__global__ __launch_bounds__(256) void attn_kernel(
        const unsigned short* __restrict__ q, const unsigned short* __restrict__ k,
        const unsigned short* __restrict__ v, unsigned short* __restrict__ o) {
    int gw   = (blockIdx.x * 256 + threadIdx.x) >> 6;
    int lane = threadIdx.x & 63;
    int n = gw >> 4, h = gw & 15;
    size_t qoff = (size_t)n * 2048 + h * 128 + lane * 2;
    float2 qv = bfpair(*(const unsigned*)(q + qoff));
    float s[8];
#pragma unroll
    for (int p = 0; p < 8; p++) {
        size_t koff = (size_t)(n * 8 + p) * 2048 + h * 128 + lane * 2;
        float2 kv = bfpair(*(const unsigned*)(k + koff));
        float d = qv.x * kv.x + qv.y * kv.y;
#pragma unroll
        for (int msk = 1; msk < 64; msk <<= 1) d += __shfl_xor(d, msk, 64);
        s[p] = d * 0.08838834764831845f;
    }
    float mx = s[0];
#pragma unroll
    for (int p = 1; p < 8; p++) mx = fmaxf(mx, s[p]);
    float e[8], den = 0.f;
#pragma unroll
    for (int p = 0; p < 8; p++) { e[p] = expf(s[p] - mx); den += e[p]; }
    float inv = 1.f / den;
    float o0 = 0.f, o1 = 0.f;
#pragma unroll
    for (int p = 0; p < 8; p++) {
        size_t voff = (size_t)(n * 8 + p) * 2048 + h * 128 + lane * 2;
        float2 vv = bfpair(*(const unsigned*)(v + voff));
        float a = e[p] * inv;
        o0 += a * vv.x; o1 += a * vv.y;
    }
    *(unsigned*)(o + qoff) = (unsigned)f2bf(o0) | ((unsigned)f2bf(o1) << 16);
}

__global__ __launch_bounds__(64) void finalize_loss_kernel(
        const float* __restrict__ accum, float* __restrict__ dst) {
    if (threadIdx.x == 0) dst[0] = accum[0] * (1.0f / (4096.0f * 2048.0f));
}

// ---------- launch ----------
extern "C" void kernel_launch(void* const* d_in, const int* in_sizes, int n_in,
                              void* d_out, int out_size, void* d_ws, size_t ws_size,
                              hipStream_t stream) {
    const float* x    = (const float*)d_in[0];
    const float* rwkv = (const float*)d_in[1];
    const float* Wq   = (const float*)d_in[2];
    const float* Wk   = (const float*)d_in[3];
    const float* Wv   = (const float*)d_in[4];
    const float* Wo   = (const float*)d_in[5];
    const float* Wg   = (const float*)d_in[6];
    const float* bg   = (const float*)d_in[7];
    const float* Wb   = (const float*)d_in[8];
    const float* Wr   = (const float*)d_in[9];
    float* out = (float*)d_out;
    char*  ws  = (char*)d_ws;

    unsigned short* xs     = (unsigned short*)(ws + 0ull);
    unsigned short* wbT    = (unsigned short*)(ws + 33554432ull);    // 128MB, reused as kbuf
    unsigned short* wqT    = (unsigned short*)(ws + 167772160ull);
    unsigned short* wgT    = (unsigned short*)(ws + 176160768ull);
    unsigned short* wkT    = (unsigned short*)(ws + 184549376ull);
    unsigned short* wvT    = (unsigned short*)(ws + 192937984ull);
    unsigned short* wrT    = (unsigned short*)(ws + 201326592ull);
    unsigned short* woT    = (unsigned short*)(ws + 209715200ull);
    unsigned short* prefix = (unsigned short*)(ws + 218103808ull);   // 128MB
    unsigned short* vbuf   = (unsigned short*)(ws + 352321536ull);   // 128MB
    unsigned short* qbuf   = (unsigned short*)(ws + 486539264ull);
    unsigned short* gbuf   = (unsigned short*)(ws + 503316480ull);
    unsigned short* pmean  = (unsigned short*)(ws + 520093696ull);
    unsigned short* attno  = (unsigned short*)(ws + 536870912ull);
    float*          lossA  = (float*)(ws + 553648128ull);
    unsigned short* kbuf   = wbT;   // WbT dead after bridge GEMM

    const int SMEM = 131072;
    const int BIG = 1 << 30;
    hipFuncSetAttribute(reinterpret_cast<const void*>(gemm256<0>),
                        hipFuncAttributeMaxDynamicSharedMemorySize, SMEM);
    hipFuncSetAttribute(reinterpret_cast<const void*>(gemm256<4>),
                        hipFuncAttributeMaxDynamicSharedMemorySize, SMEM);
    hipFuncSetAttribute(reinterpret_cast<const void*>(gemm256<5>),
                        hipFuncAttributeMaxDynamicSharedMemorySize, SMEM);

    hipMemsetAsync(lossA, 0, 16, stream);

    // merged prep: pack_xs (16384) + Wb-T (65536) + six 2048^2 T (24576)
    prep_kernel<<<106496, 256, 0, stream>>>(
        x, rwkv, xs, Wb, wbT,
        Wq, Wg, Wk, Wv, Wr, Wo, wqT, wgT, wkT, wvT, wrT, woT);

    // prefix = xs @ Wb          M=4096 N=16384 K=4096 -> Mtiles=16 (bandH=2)
    gemm256<0><<<dim3(1024), 512, SMEM, stream>>>(xs, 4096, wbT, 4096,
        prefix, nullptr, 16384, BIG, 4096, 16, nullptr, nullptr, nullptr,
        nullptr, nullptr);
    // [k|v] = prefix @ [Wk|Wv]  M=32768 N=4096 K=2048 -> Mtiles=128 (bandH=16)
    gemm256<0><<<dim3(2048), 512, SMEM, stream>>>(prefix, 2048, wkT, 2048,
        kbuf, vbuf, 2048, 2048, 2048, 128, nullptr, nullptr, nullptr,
        nullptr, nullptr);
    // pmean = mean_p(prefix)
    pmean_kernel<<<4096, 256, 0, stream>>>(prefix, pmean);
    // [q|g] = x @ [Wq|Wg]       M=4096 N=4096 K=2048 -> Mtiles=16 (bandH=2)
    gemm256<4><<<dim3(256), 512, SMEM, stream>>>(xs, 4096, wqT, 2048,
        qbuf, gbuf, 2048, 2048, 2048, 16, bg, nullptr, nullptr,
        nullptr, nullptr);
    // attention
    attn_kernel<<<16384, 256, 0, stream>>>(qbuf, kbuf, vbuf, attno);
    // TAIL: blocks 0-127: loss; blocks 128-255: out = (attno@Wo)*g
    gemm256<5><<<dim3(256), 512, SMEM, stream>>>(pmean, 2048, wrT, 2048,
        out, nullptr, 2048, BIG, 2048, 16, x, gbuf, lossA,
        attno, woT);

    finalize_loss_kernel<<<1, 64, 0, stream>>>(lossA, out + 8388608);
}

// Round 15
// 1095.053 us; speedup vs baseline: 1.3156x; 1.1572x over previous
//
#include <hip/hip_runtime.h>

#define DEVFN static __device__ __forceinline__

typedef __attribute__((ext_vector_type(8))) short short8;
typedef __attribute__((ext_vector_type(4))) float f32x4;

// ---------- bf16 helpers (raw ushort storage) ----------
DEVFN unsigned short f2bf(float f) {
    union { float f; unsigned u; } a; a.f = f;
    unsigned u = a.u;
    unsigned r = (u + 0x7FFFu + ((u >> 16) & 1u)) >> 16;   // RNE
    return (unsigned short)r;
}
DEVFN float bf2f(unsigned short b) {
    union { unsigned u; float f; } a; a.u = ((unsigned)b) << 16;
    return a.f;
}

// ---------- async global->LDS (16B per lane, wave-uniform LDS base) ----------
DEVFN void gload16(const void* g, void* lds) {
    __builtin_amdgcn_global_load_lds(
        (const __attribute__((address_space(1))) unsigned int*)g,
        (__attribute__((address_space(3))) unsigned int*)lds, 16, 0, 0);
}

#define BAR() __builtin_amdgcn_s_barrier()
#define VMCNT4() asm volatile("s_waitcnt vmcnt(4)" ::: "memory")
#define VMCNT0() asm volatile("s_waitcnt vmcnt(0)" ::: "memory")

// ---------- merged prep kernel bodies ----------
DEVFN void pack_xs_body(const float* __restrict__ x, const float* __restrict__ r,
                        unsigned short* __restrict__ xs, int blk) {
    int i = blk * 256 + threadIdx.x;
    int n  = i >> 10;
    int cw = i & 1023;
    const float* src = (cw < 512) ? (x + (size_t)n * 2048 + cw * 4)
                                  : (r + (size_t)n * 2048 + (cw - 512) * 4);
    float4 v = *(const float4*)src;
    ushort4 o;
    o.x = f2bf(v.x); o.y = f2bf(v.y); o.z = f2bf(v.z); o.w = f2bf(v.w);
    *(ushort4*)(xs + (size_t)n * 4096 + cw * 4) = o;
}

DEVFN void transpose_body(const float* __restrict__ in,
                          unsigned short* __restrict__ out,
                          int R, int Cc, int bx, int by) {
    __shared__ float tile[32][33];
    const int t  = threadIdx.x;
    const int r  = t >> 3;
    const int c4 = (t & 7) * 4;
    const int tr = by * 32, tc = bx * 32;
    float4 v = *(const float4*)(in + (size_t)(tr + r) * Cc + tc + c4);
    tile[r][c4 + 0] = v.x; tile[r][c4 + 1] = v.y;
    tile[r][c4 + 2] = v.z; tile[r][c4 + 3] = v.w;
    __syncthreads();
    const int orow = r, oc = c4;
    ushort4 o;
    o.x = f2bf(tile[oc + 0][orow]);
    o.y = f2bf(tile[oc + 1][orow]);
    o.z = f2bf(tile[oc + 2][orow]);
    o.w = f2bf(tile[oc + 3][orow]);
    *(ushort4*)(out + (size_t)(tc + orow) * R + tr + oc) = o;
}

DEVFN void cast_body(const float* __restrict__ in,
                     unsigned short* __restrict__ out, int blk) {
    int i = blk * 1024 + threadIdx.x * 4;
    float4 v = *(const float4*)(in + i);
    ushort4 o;
    o.x = f2bf(v.x); o.y = f2bf(v.y); o.z = f2bf(v.z); o.w = f2bf(v.w);
    *(ushort4*)(out + i) = o;
}

// one launch: pack_xs(16384) + WbT(65536) + 5 transposes(5*4096) + Wk cast(4096)
__global__ __launch_bounds__(256) void prep_kernel(
        const float* __restrict__ x, const float* __restrict__ rwkv,
        unsigned short* __restrict__ xs,
        const float* __restrict__ Wb, unsigned short* __restrict__ wbT,
        const float* __restrict__ i0, const float* __restrict__ i1,
        const float* __restrict__ i2, const float* __restrict__ i3,
        const float* __restrict__ i4,
        unsigned short* __restrict__ o0, unsigned short* __restrict__ o1,
        unsigned short* __restrict__ o2, unsigned short* __restrict__ o3,
        unsigned short* __restrict__ o4,
        const float* __restrict__ Wk, unsigned short* __restrict__ wkC) {
    int b = blockIdx.x;
    if (b < 16384) { pack_xs_body(x, rwkv, xs, b); return; }
    b -= 16384;
    if (b < 65536) { transpose_body(Wb, wbT, 4096, 16384, b & 511, b >> 9); return; }
    b -= 65536;
    const int z = b >> 12, rem = b & 4095;
    if (z == 5) { cast_body(Wk, wkC, rem); return; }
    const float* in; unsigned short* out;
    switch (z) {
        case 0: in = i0; out = o0; break;
        case 1: in = i1; out = o1; break;
        case 2: in = i2; out = o2; break;
        case 3: in = i3; out = o3; break;
        default: in = i4; out = o4; break;
    }
    transpose_body(in, out, 2048, 2048, rem & 63, rem >> 6);
}

// ============================================================================
// 256x256 GEMM, 4-phase schedule (frozen R14 core). EPI:
//  0 = bf16 store (col split); 4 = split plain|sigmoid; 5 = tail merge;
//  6 = qt mode (R15): bid = (tile<<4)|h; A += h*128 (q h-slice), Bt += h*128
//      (Wk h-cols); C = per-h 16MB chunk (h<8: Cptr, else Cptr2), bf16.
// ============================================================================
template <int EPI>
__global__ __launch_bounds__(512, 2) void gemm256(
        const unsigned short* __restrict__ A, int lda,
        const unsigned short* __restrict__ Bt, int ldb,
        void* __restrict__ Cptr, void* __restrict__ Cptr2,
        int ldc, int splitcol, int K, int Mtiles,
        const float* __restrict__ aux_f32,
        const unsigned short* __restrict__ aux_bf16,
        float* __restrict__ loss_accum,
        const unsigned short* __restrict__ A2,
        const unsigned short* __restrict__ Bt2) {
    extern __shared__ char smem[];   // 131072 B
    const int tid  = threadIdx.x;
    const int wid  = tid >> 6, lane = tid & 63;
    const int wm   = wid >> 2, wn = wid & 3;
    const int l15  = lane & 15;
    const int lhi  = (lane >> 4) * 16;
    const int nkt  = K >> 6;

    int bid = blockIdx.x;
    bool sub1 = false;
    unsigned short* Cq = nullptr;
    if constexpr (EPI == 5) {
        const int half = gridDim.x >> 1;
        if (bid >= half) { sub1 = true; bid -= half; A = A2; Bt = Bt2; }
    }
    if constexpr (EPI == 6) {
        const int h = bid & 15; bid >>= 4;
        A  += h * 128;
        Bt += h * 128;
        Cq = (h < 8) ? (unsigned short*)Cptr  + (size_t)h * 8388608
                     : (unsigned short*)Cptr2 + (size_t)(h - 8) * 8388608;
    }

    // banded XCD mapping
    const int bandH = Mtiles >> 3;
    const int xcd = bid & 7, idx = bid >> 3;
    const int brow = (xcd * bandH + (idx % bandH)) << 8;
    const int bcol = (idx / bandH) << 8;

    const int lin0 = (wid * 2 + 0) * 1024 + lane * 16;
    const int lin1 = (wid * 2 + 1) * 1024 + lane * 16;
    const int ph0 = lin0 ^ (((lin0 >> 7) & 7) << 4);
    const int ph1v = lin1 ^ (((lin1 >> 7) & 7) << 4);
    const int srow0 = ph0 >> 7, scol0 = (ph0 & 127) >> 1;
    const int srow1 = ph1v >> 7, scol1 = (ph1v & 127) >> 1;
    const int dst0 = (wid * 2 + 0) * 1024;
    const int dst1 = (wid * 2 + 1) * 1024;

#define STAGE(t, mat, h_) do { \
        char* base_ = smem + (((t) & 1) * 65536) + ((mat) * 32768) + ((h_) * 16384); \
        const unsigned short* G_ = (mat) ? Bt : A; \
        const int ld_ = (mat) ? ldb : lda; \
        const int rb_ = ((mat) ? bcol : brow) + (h_) * 128; \
        gload16(G_ + (size_t)(rb_ + srow0) * ld_ + (t) * 64 + scol0, base_ + dst0); \
        gload16(G_ + (size_t)(rb_ + srow1) * ld_ + (t) * 64 + scol1, base_ + dst1); \
    } while (0)
#define STAGE_G(t, mat, h_) do { if ((t) < nkt) STAGE(t, mat, h_); } while (0)

#define LDA_FRAG(dst, buf, m, kk) do { \
        int lin_ = ((m) * 16 + l15) * 128 + (kk) * 64 + lhi; \
        int ph_  = lin_ ^ (((lin_ >> 7) & 7) << 4); \
        dst = *(const short8*)(smem + (buf) * 65536 + wm * 16384 + ph_); \
    } while (0)
#define LDB_FRAG(dst, buf, n, kk) do { \
        int lin_ = ((wn & 1) * 64 + (n) * 16 + l15) * 128 + (kk) * 64 + lhi; \
        int ph_  = lin_ ^ (((lin_ >> 7) & 7) << 4); \
        dst = *(const short8*)(smem + (buf) * 65536 + 32768 + (wn >> 1) * 16384 + ph_); \
    } while (0)

    f32x4 acc[8][4] = {};
    short8 afr[8][2], bfr[4][2];

#define MFMA_Q(mq) do { \
        __builtin_amdgcn_s_setprio(1); \
        _Pragma("unroll") \
        for (int n_ = 0; n_ < 4; ++n_) { \
            acc[2*(mq)][n_]   = __builtin_amdgcn_mfma_f32_16x16x32_bf16(afr[2*(mq)][0],   bfr[n_][0], acc[2*(mq)][n_],   0,0,0); \
            acc[2*(mq)][n_]   = __builtin_amdgcn_mfma_f32_16x16x32_bf16(afr[2*(mq)][1],   bfr[n_][1], acc[2*(mq)][n_],   0,0,0); \
            acc[2*(mq)+1][n_] = __builtin_amdgcn_mfma_f32_16x16x32_bf16(afr[2*(mq)+1][0], bfr[n_][0], acc[2*(mq)+1][n_], 0,0,0); \
            acc[2*(mq)+1][n_] = __builtin_amdgcn_mfma_f32_16x16x32_bf16(afr[2*(mq)+1][1], bfr[n_][1], acc[2*(mq)+1][n_], 0,0,0); \
        } \
        __builtin_amdgcn_s_setprio(0); \
    } while (0)

#define READ_B(b) do { \
        _Pragma("unroll") \
        for (int n_ = 0; n_ < 4; ++n_) { LDB_FRAG(bfr[n_][0], b, n_, 0); LDB_FRAG(bfr[n_][1], b, n_, 1); } \
    } while (0)
#define READ_QA(b, mq) do { \
        LDA_FRAG(afr[2*(mq)][0],   b, 2*(mq),   0); LDA_FRAG(afr[2*(mq)][1],   b, 2*(mq),   1); \
        LDA_FRAG(afr[2*(mq)+1][0], b, 2*(mq)+1, 0); LDA_FRAG(afr[2*(mq)+1][1], b, 2*(mq)+1, 1); \
    } while (0)

    // ---- prologue: T0 full + T1.B (12 loads) ----
    STAGE(0, 1, 0); STAGE(0, 1, 1); STAGE(0, 0, 0); STAGE(0, 0, 1);
    STAGE_G(1, 1, 0); STAGE_G(1, 1, 1);
    VMCNT4();
    BAR();

    const int niter = nkt >> 1;
    for (int it = 0; it < niter; ++it) {
        const int t0 = it * 2, t1 = t0 + 1;
        const bool lastIt = (it == niter - 1);

        READ_B(0); READ_QA(0, 0); READ_QA(0, 1);
        STAGE_G(t1, 0, 0); STAGE_G(t1, 0, 1);
        BAR();
        MFMA_Q(0); MFMA_Q(1);
        READ_QA(0, 2); READ_QA(0, 3);
        STAGE_G(t0 + 2, 1, 0); STAGE_G(t0 + 2, 1, 1);
        if (lastIt) { VMCNT0(); } else { VMCNT4(); }
        BAR();
        MFMA_Q(2); MFMA_Q(3);
        READ_B(1); READ_QA(1, 0); READ_QA(1, 1);
        STAGE_G(t0 + 2, 0, 0); STAGE_G(t0 + 2, 0, 1);
        BAR();
        MFMA_Q(0); MFMA_Q(1);
        READ_QA(1, 2); READ_QA(1, 3);
        STAGE_G(t1 + 2, 1, 0); STAGE_G(t1 + 2, 1, 1);
        if (lastIt) { VMCNT0(); } else { VMCNT4(); }
        BAR();
        MFMA_Q(2); MFMA_Q(3);
    }

    const int rl = (lane >> 4) * 4;
    const int cl = lane & 15;
    const int row0 = brow + wm * 128;

    if constexpr (EPI == 6) {
        const int col0 = bcol + wn * 64;
#pragma unroll
        for (int m = 0; m < 8; m++)
#pragma unroll
            for (int n = 0; n < 4; n++)
#pragma unroll
                for (int rg = 0; rg < 4; rg++) {
                    int gr = row0 + m * 16 + rl + rg;
                    int gc = col0 + n * 16 + cl;
                    Cq[(size_t)gr * 2048 + gc] = f2bf(acc[m][n][rg]);
                }
        return;
    }

    if constexpr (EPI == 5) {
        const int col0 = bcol + wn * 64;
        if (!sub1) {
            float lsum = 0.f;
#pragma unroll
            for (int m = 0; m < 8; m++)
#pragma unroll
                for (int n = 0; n < 4; n++)
#pragma unroll
                    for (int rg = 0; rg < 4; rg++) {
                        int gr = row0 + m * 16 + rl + rg;
                        int gc = col0 + n * 16 + cl;
                        float d = acc[m][n][rg] - aux_f32[(size_t)gr * ldc + gc];
                        lsum += d * d;
                    }
#pragma unroll
            for (int msk = 1; msk < 64; msk <<= 1)
                lsum += __shfl_xor(lsum, msk, 64);
            if (lane == 0) atomicAdd(loss_accum, lsum);
        } else {
#pragma unroll
            for (int m = 0; m < 8; m++)
#pragma unroll
                for (int n = 0; n < 4; n++)
#pragma unroll
                    for (int rg = 0; rg < 4; rg++) {
                        int gr = row0 + m * 16 + rl + rg;
                        int gc = col0 + n * 16 + cl;
                        size_t idxo = (size_t)gr * ldc + gc;
                        float gv = bf2f(aux_bf16[idxo]);
                        ((float*)Cptr)[idxo] = acc[m][n][rg] * gv;
                    }
        }
        return;
    }

    void* Ceff = Cptr;
    bool second = false;
    int bcol_l = bcol;
    if constexpr (EPI == 0 || EPI == 4) {
        if (bcol >= splitcol) { Ceff = Cptr2; bcol_l = bcol - splitcol; second = true; }
    }
    const int col0 = bcol_l + wn * 64;

#pragma unroll
    for (int m = 0; m < 8; m++)
#pragma unroll
        for (int n = 0; n < 4; n++)
#pragma unroll
            for (int rg = 0; rg < 4; rg++) {
                int gr = row0 + m * 16 + rl + rg;
                int gc = col0 + n * 16 + cl;
                size_t idxo = (size_t)gr * ldc + gc;
                if constexpr (EPI == 0) {
                    ((unsigned short*)Ceff)[idxo] = f2bf(acc[m][n][rg]);
                } else {  // EPI == 4
                    if (second) {
                        float t = acc[m][n][rg] + aux_f32[gc];
                        ((unsigned short*)Ceff)[idxo] = f2bf(1.f / (1.f + expf(-t)));
                    } else {
                        ((unsigned short*)Ceff)[idxo] = f2bf(acc[m][n][rg]);
                    }
                }
            }
#undef STAGE
#undef STAGE_G
#undef LDA_FRAG
#undef LDB_FRAG
#undef MFMA_Q
#undef READ_B
#undef READ_QA
}

// ---------- pmean[n][c] = mean_p prefix[n][p*2048 + c] ----------
__global__ __launch_bounds__(256) void pmean_kernel(
        const unsigned short* __restrict__ prefix, unsigned short* __restrict__ pm) {
    int i  = blockIdx.x * 256 + threadIdx.x;
    int n  = i >> 8;
    int c8 = (i & 255) * 8;
    float acc[8] = {0, 0, 0, 0, 0, 0, 0, 0};
#pragma unroll
    for (int p = 0; p < 8; p++) {
        const unsigned short* src = prefix + (size_t)n * 16384 + p * 2048 + c8;
        uint4 raw = *(const uint4*)src;
        unsigned w[4] = {raw.x, raw.y, raw.z, raw.w};
#pragma unroll
        for (int j = 0; j < 4; j++) {
            acc[2 * j]     += bf2f((unsigned short)(w[j] & 0xFFFFu));
            acc[2 * j + 1] += bf2f((unsigned short)(w[j] >> 16));
        }
    }
    uint4 o;
    unsigned* ow = (unsigned*)&o;
#pragma unroll
    for (int j = 0; j < 4; j++)
        ow[j] = (unsigned)f2bf(acc[2 * j] * 0.125f) |
                ((unsigned)f2bf(acc[2 * j + 1] * 0.125f) << 16);
    *(uint4*)(pm + (size_t)n * 2048 + c8) = o;
}

// ---------- attention v2 (R15): scores from qt·prefix, w in-place over qt ----
// block per n (256 thr = 4 waves, wave handles 4 h). prefix[n] in LDS (32KB).
__global__ __launch_bounds__(256) void attn2_kernel(
        const unsigned short* __restrict__ prefix,
        unsigned short* __restrict__ qtA, unsigned short* __restrict__ qtB) {
    __shared__ __align__(16) unsigned short pfx[8][2048];
    const int n = blockIdx.x, tid = threadIdx.x;
    const int wid = tid >> 6, lane = tid & 63;
#pragma unroll
    for (int r = 0; r < 8; ++r)
        *(uint4*)&pfx[r][tid * 8] =
            *(const uint4*)(prefix + (size_t)n * 16384 + r * 2048 + tid * 8);
    __syncthreads();
#pragma unroll
    for (int hh = 0; hh < 4; ++hh) {
        const int h = wid * 4 + hh;
        unsigned short* qrow = ((h < 8) ? qtA + (size_t)h * 8388608
                                        : qtB + (size_t)(h - 8) * 8388608)
                               + (size_t)n * 2048;
        short8 qv[4];
#pragma unroll
        for (int k = 0; k < 4; ++k)
            qv[k] = *(const short8*)(qrow + lane * 8 + k * 512);
        float s[8];
#pragma unroll
        for (int p = 0; p < 8; ++p) {
            float d = 0.f;
#pragma unroll
            for (int k = 0; k < 4; ++k) {
                short8 pv = *(const short8*)&pfx[p][lane * 8 + k * 512];
#pragma unroll
                for (int j = 0; j < 8; ++j)
                    d += bf2f((unsigned short)qv[k][j]) * bf2f((unsigned short)pv[j]);
            }
#pragma unroll
            for (int msk = 1; msk < 64; msk <<= 1) d += __shfl_xor(d, msk, 64);
            s[p] = d * 0.08838834764831845f;   // 1/sqrt(128)
        }
        float mx = s[0];
#pragma unroll
        for (int p = 1; p < 8; ++p) mx = fmaxf(mx, s[p]);
        float e[8], den = 0.f;
#pragma unroll
        for (int p = 0; p < 8; ++p) { e[p] = expf(s[p] - mx); den += e[p]; }
        float inv = 1.f / den;
#pragma unroll
        for (int k = 0; k < 4; ++k) {
            float wa[8] = {0, 0, 0, 0, 0, 0, 0, 0};
#pragma unroll
            for (int p = 0; p < 8; ++p) {
                float a = e[p] * inv;
                short8 pv = *(const short8*)&pfx[p][lane * 8 + k * 512];
#pragma unroll
                for (int j = 0; j < 8; ++j)
                    wa[j] += a * bf2f((unsigned short)pv[j]);
            }
            short8 ov;
#pragma unroll
            for (int j = 0; j < 8; ++j) ov[j] = (short)f2bf(wa[j]);
            *(short8*)(qrow + lane * 8 + k * 512) = ov;   // w in-place over qt
        }
    }
}

// ---------- wv GEMM (R15): attno[n, h*128+d] = w[h][n] @ WvT rows ---------
// block: h = bid>>4, mt = bid&15. BM=256, BN=128, K=2048. 8 waves 4m x 2n.
__global__ __launch_bounds__(512) void gemmwv_kernel(
        const unsigned short* __restrict__ qtA,
        const unsigned short* __restrict__ qtB,
        const unsigned short* __restrict__ wvT,
        unsigned short* __restrict__ attno) {
    __shared__ __align__(16) unsigned short Atile[256 * 64];
    __shared__ __align__(16) unsigned short Btile[128 * 64];
    const int tid = threadIdx.x, wid = tid >> 6, lane = tid & 63;
    const int wm = wid >> 1, wn = wid & 1;
    const int l15 = lane & 15, lhi = (lane >> 4) * 16;
    const int h = blockIdx.x >> 4, mt = blockIdx.x & 15;
    const unsigned short* A = (h < 8) ? qtA + (size_t)h * 8388608
                                      : qtB + (size_t)(h - 8) * 8388608;
    const unsigned short* B = wvT + (size_t)(h * 128) * 2048;
    const int brow = mt << 8;

#define WVST(buf, c, kt, G, ld, rbase) do { \
        int linc = (c) * 8192 + wid * 1024 + lane * 16; \
        int phc = linc ^ (((linc >> 7) & 7) << 4); \
        gload16((G) + (size_t)((rbase) + (phc >> 7)) * (ld) + (kt) * 64 + ((phc & 127) >> 1), \
                (char*)(buf) + (c) * 8192 + wid * 1024); \
    } while (0)

    f32x4 acc[4][4] = {};
    for (int kt = 0; kt < 32; ++kt) {
        WVST(Atile, 0, kt, A, 2048, brow); WVST(Atile, 1, kt, A, 2048, brow);
        WVST(Atile, 2, kt, A, 2048, brow); WVST(Atile, 3, kt, A, 2048, brow);
        WVST(Btile, 0, kt, B, 2048, 0);    WVST(Btile, 1, kt, B, 2048, 0);
        VMCNT0();
        BAR();
        short8 af[4][2], bf[4][2];
#pragma unroll
        for (int m = 0; m < 4; ++m)
#pragma unroll
            for (int kk = 0; kk < 2; ++kk) {
                int lin = (wm * 64 + m * 16 + l15) * 128 + kk * 64 + lhi;
                int ph = lin ^ (((lin >> 7) & 7) << 4);
                af[m][kk] = *(const short8*)((char*)Atile + ph);
            }
#pragma unroll
        for (int nn = 0; nn < 4; ++nn)
#pragma unroll
            for (int kk = 0; kk < 2; ++kk) {
                int lin = (wn * 64 + nn * 16 + l15) * 128 + kk * 64 + lhi;
                int ph = lin ^ (((lin >> 7) & 7) << 4);
                bf[nn][kk] = *(const short8*)((char*)Btile + ph);
            }
        __builtin_amdgcn_s_setprio(1);
#pragma unroll
        for (int m = 0; m < 4; ++m)
#pragma unroll
            for (int nn = 0; nn < 4; ++nn) {
                acc[m][nn] = __builtin_amdgcn_mfma_f32_16x16x32_bf16(af[m][0], bf[nn][0], acc[m][nn], 0, 0, 0);
                acc[m][nn] = __builtin_amdgcn_mfma_f32_16x16x32_bf16(af[m][1], bf[nn][1], acc[m][nn], 0, 0, 0);
            }
        __builtin_amdgcn_s_setprio(0);
        BAR();   // all reads retired before next stage overwrites
    }
    const int rl = (lane >> 4) * 4, cl = lane & 15;
#pragma unroll
    for (int m = 0; m < 4; ++m)
#pragma unroll
        for (int nn = 0; nn < 4; ++nn)
#pragma unroll
            for (int rg = 0; rg < 4; ++rg) {
                int gr = brow + wm * 64 + m * 16 + rl + rg;
                int gc = h * 128 + wn * 64 + nn * 16 + cl;
                attno[(size_t)gr * 2048 + gc] = f2bf(acc[m][nn][rg]);
            }
#undef WVST
}

__global__ __launch_bounds__(64) void finalize_loss_kernel(
        const float* __restrict__ accum, float* __restrict__ dst) {
    if (threadIdx.x == 0) dst[0] = accum[0] * (1.0f / (4096.0f * 2048.0f));
}

// ---------- launch ----------
extern "C" void kernel_launch(void* const* d_in, const int* in_sizes, int n_in,
                              void* d_out, int out_size, void* d_ws, size_t ws_size,
                              hipStream_t stream) {
    const float* x    = (const float*)d_in[0];
    const float* rwkv = (const float*)d_in[1];
    const float* Wq   = (const float*)d_in[2];
    const float* Wk   = (const float*)d_in[3];
    const float* Wv   = (const float*)d_in[4];
    const float* Wo   = (const float*)d_in[5];
    const float* Wg   = (const float*)d_in[6];
    const float* bg   = (const float*)d_in[7];
    const float* Wb   = (const float*)d_in[8];
    const float* Wr   = (const float*)d_in[9];
    float* out = (float*)d_out;
    char*  ws  = (char*)d_ws;

    unsigned short* xs     = (unsigned short*)(ws + 0ull);
    unsigned short* wbT    = (unsigned short*)(ws + 33554432ull);    // dead after bridge
    unsigned short* qtA    = (unsigned short*)(ws + 33554432ull);    // 128MB (h 0-7)
    unsigned short* wqT    = (unsigned short*)(ws + 167772160ull);
    unsigned short* wgT    = (unsigned short*)(ws + 176160768ull);
    unsigned short* wkC    = (unsigned short*)(ws + 184549376ull);   // Wk cast (no T)
    unsigned short* wvT    = (unsigned short*)(ws + 192937984ull);
    unsigned short* wrT    = (unsigned short*)(ws + 201326592ull);
    unsigned short* woT    = (unsigned short*)(ws + 209715200ull);
    unsigned short* prefix = (unsigned short*)(ws + 218103808ull);   // 128MB
    unsigned short* qtB    = (unsigned short*)(ws + 352321536ull);   // 128MB (h 8-15)
    unsigned short* qbuf   = (unsigned short*)(ws + 486539264ull);
    unsigned short* gbuf   = (unsigned short*)(ws + 503316480ull);
    unsigned short* pmean  = (unsigned short*)(ws + 520093696ull);
    unsigned short* attno  = (unsigned short*)(ws + 536870912ull);
    float*          lossA  = (float*)(ws + 553648128ull);

    const int SMEM = 131072;
    const int BIG = 1 << 30;
    hipFuncSetAttribute(reinterpret_cast<const void*>(gemm256<0>),
                        hipFuncAttributeMaxDynamicSharedMemorySize, SMEM);
    hipFuncSetAttribute(reinterpret_cast<const void*>(gemm256<4>),
                        hipFuncAttributeMaxDynamicSharedMemorySize, SMEM);
    hipFuncSetAttribute(reinterpret_cast<const void*>(gemm256<5>),
                        hipFuncAttributeMaxDynamicSharedMemorySize, SMEM);
    hipFuncSetAttribute(reinterpret_cast<const void*>(gemm256<6>),
                        hipFuncAttributeMaxDynamicSharedMemorySize, SMEM);

    hipMemsetAsync(lossA, 0, 16, stream);

    // prep: pack_xs + WbT + {Wq,Wg,Wv,Wr,Wo} transposes + Wk cast
    prep_kernel<<<106496, 256, 0, stream>>>(
        x, rwkv, xs, Wb, wbT,
        Wq, Wg, Wv, Wr, Wo, wqT, wgT, wvT, wrT, woT, Wk, wkC);

    // prefix = xs @ Wb          M=4096 N=16384 K=4096
    gemm256<0><<<dim3(1024), 512, SMEM, stream>>>(xs, 4096, wbT, 4096,
        prefix, nullptr, 16384, BIG, 4096, 16, nullptr, nullptr, nullptr,
        nullptr, nullptr);
    // pmean = mean_p(prefix)
    pmean_kernel<<<4096, 256, 0, stream>>>(prefix, pmean);
    // [q|g] = x @ [Wq|Wg]       M=4096 N=4096 K=2048, split @2048
    gemm256<4><<<dim3(256), 512, SMEM, stream>>>(xs, 4096, wqT, 2048,
        qbuf, gbuf, 2048, 2048, 2048, 16, bg, nullptr, nullptr,
        nullptr, nullptr);
    // qt[h] = q_h @ Wk_h^T      per h: M=4096 N=2048 K=128 (16h x 128 tiles)
    gemm256<6><<<dim3(2048), 512, SMEM, stream>>>(qbuf, 2048, wkC, 2048,
        qtA, qtB, 2048, BIG, 128, 16, nullptr, nullptr, nullptr,
        nullptr, nullptr);
    // attention: scores = qt.prefix, softmax, w = attn-weighted prefix (in-place)
    attn2_kernel<<<4096, 256, 0, stream>>>(prefix, qtA, qtB);
    // attno[n, hs] = w[h][n] @ Wv[:, hs]
    gemmwv_kernel<<<256, 512, 0, stream>>>(qtA, qtB, wvT, attno);
    // TAIL: blocks 0-127: loss; blocks 128-255: out = (attno@Wo)*g
    gemm256<5><<<dim3(256), 512, SMEM, stream>>>(pmean, 2048, wrT, 2048,
        out, nullptr, 2048, BIG, 2048, 16, x, gbuf, lossA,
        attno, woT);

    finalize_loss_kernel<<<1, 64, 0, stream>>>(lossA, out + 8388608);
}

// Round 16
// 1075.480 us; speedup vs baseline: 1.3396x; 1.0182x over previous
//
#include <hip/hip_runtime.h>

#define DEVFN static __device__ __forceinline__

typedef __attribute__((ext_vector_type(8))) short short8;
typedef __attribute__((ext_vector_type(4))) float f32x4;

// ---------- bf16 helpers (raw ushort storage) ----------
DEVFN unsigned short f2bf(float f) {
    union { float f; unsigned u; } a; a.f = f;
    unsigned u = a.u;
    unsigned r = (u + 0x7FFFu + ((u >> 16) & 1u)) >> 16;   // RNE
    return (unsigned short)r;
}
DEVFN float bf2f(unsigned short b) {
    union { unsigned u; float f; } a; a.u = ((unsigned)b) << 16;
    return a.f;
}

// ---------- async global->LDS (16B per lane, wave-uniform LDS base) ----------
DEVFN void gload16(const void* g, void* lds) {
    __builtin_amdgcn_global_load_lds(
        (const __attribute__((address_space(1))) unsigned int*)g,
        (__attribute__((address_space(3))) unsigned int*)lds, 16, 0, 0);
}

#define BAR() __builtin_amdgcn_s_barrier()
#define VMCNT4() asm volatile("s_waitcnt vmcnt(4)" ::: "memory")
#define VMCNT0() asm volatile("s_waitcnt vmcnt(0)" ::: "memory")

// ---------- merged prep kernel bodies ----------
DEVFN void pack_xs_body(const float* __restrict__ x, const float* __restrict__ r,
                        unsigned short* __restrict__ xs, int blk) {
    int i = blk * 256 + threadIdx.x;
    int n  = i >> 10;
    int cw = i & 1023;
    const float* src = (cw < 512) ? (x + (size_t)n * 2048 + cw * 4)
                                  : (r + (size_t)n * 2048 + (cw - 512) * 4);
    float4 v = *(const float4*)src;
    ushort4 o;
    o.x = f2bf(v.x); o.y = f2bf(v.y); o.z = f2bf(v.z); o.w = f2bf(v.w);
    *(ushort4*)(xs + (size_t)n * 4096 + cw * 4) = o;
}

DEVFN void transpose_body(const float* __restrict__ in,
                          unsigned short* __restrict__ out,
                          int R, int Cc, int bx, int by) {
    __shared__ float tile[32][33];
    const int t  = threadIdx.x;
    const int r  = t >> 3;
    const int c4 = (t & 7) * 4;
    const int tr = by * 32, tc = bx * 32;
    float4 v = *(const float4*)(in + (size_t)(tr + r) * Cc + tc + c4);
    tile[r][c4 + 0] = v.x; tile[r][c4 + 1] = v.y;
    tile[r][c4 + 2] = v.z; tile[r][c4 + 3] = v.w;
    __syncthreads();
    const int orow = r, oc = c4;
    ushort4 o;
    o.x = f2bf(tile[oc + 0][orow]);
    o.y = f2bf(tile[oc + 1][orow]);
    o.z = f2bf(tile[oc + 2][orow]);
    o.w = f2bf(tile[oc + 3][orow]);
    *(ushort4*)(out + (size_t)(tc + orow) * R + tr + oc) = o;
}

DEVFN void cast_body(const float* __restrict__ in,
                     unsigned short* __restrict__ out, int blk) {
    int i = blk * 1024 + threadIdx.x * 4;
    float4 v = *(const float4*)(in + i);
    ushort4 o;
    o.x = f2bf(v.x); o.y = f2bf(v.y); o.z = f2bf(v.z); o.w = f2bf(v.w);
    *(ushort4*)(out + i) = o;
}

// one launch: pack_xs(16384) + WbT(65536) + 5 transposes(5*4096) + Wk cast(4096)
__global__ __launch_bounds__(256) void prep_kernel(
        const float* __restrict__ x, const float* __restrict__ rwkv,
        unsigned short* __restrict__ xs,
        const float* __restrict__ Wb, unsigned short* __restrict__ wbT,
        const float* __restrict__ i0, const float* __restrict__ i1,
        const float* __restrict__ i2, const float* __restrict__ i3,
        const float* __restrict__ i4,
        unsigned short* __restrict__ o0, unsigned short* __restrict__ o1,
        unsigned short* __restrict__ o2, unsigned short* __restrict__ o3,
        unsigned short* __restrict__ o4,
        const float* __restrict__ Wk, unsigned short* __restrict__ wkC) {
    int b = blockIdx.x;
    if (b < 16384) { pack_xs_body(x, rwkv, xs, b); return; }
    b -= 16384;
    if (b < 65536) { transpose_body(Wb, wbT, 4096, 16384, b & 511, b >> 9); return; }
    b -= 65536;
    const int z = b >> 12, rem = b & 4095;
    if (z == 5) { cast_body(Wk, wkC, rem); return; }
    const float* in; unsigned short* out;
    switch (z) {
        case 0: in = i0; out = o0; break;
        case 1: in = i1; out = o1; break;
        case 2: in = i2; out = o2; break;
        case 3: in = i3; out = o3; break;
        default: in = i4; out = o4; break;
    }
    transpose_body(in, out, 2048, 2048, rem & 63, rem >> 6);
}

// ============================================================================
// 256x256 GEMM, 4-phase schedule (frozen R14 core). EPI:
//  0 = bf16 store (col split); 4 = split plain|sigmoid; 5 = tail merge;
//  6 = qt mode: bid = (tile<<4)|h; A += h*128, Bt += h*128; C = per-h chunk.
// ============================================================================
template <int EPI>
__global__ __launch_bounds__(512, 2) void gemm256(
        const unsigned short* __restrict__ A, int lda,
        const unsigned short* __restrict__ Bt, int ldb,
        void* __restrict__ Cptr, void* __restrict__ Cptr2,
        int ldc, int splitcol, int K, int Mtiles,
        const float* __restrict__ aux_f32,
        const unsigned short* __restrict__ aux_bf16,
        float* __restrict__ loss_accum,
        const unsigned short* __restrict__ A2,
        const unsigned short* __restrict__ Bt2) {
    extern __shared__ char smem[];   // 131072 B
    const int tid  = threadIdx.x;
    const int wid  = tid >> 6, lane = tid & 63;
    const int wm   = wid >> 2, wn = wid & 3;
    const int l15  = lane & 15;
    const int lhi  = (lane >> 4) * 16;
    const int nkt  = K >> 6;

    int bid = blockIdx.x;
    bool sub1 = false;
    unsigned short* Cq = nullptr;
    if constexpr (EPI == 5) {
        const int half = gridDim.x >> 1;
        if (bid >= half) { sub1 = true; bid -= half; A = A2; Bt = Bt2; }
    }
    if constexpr (EPI == 6) {
        const int h = bid & 15; bid >>= 4;
        A  += h * 128;
        Bt += h * 128;
        Cq = (h < 8) ? (unsigned short*)Cptr  + (size_t)h * 8388608
                     : (unsigned short*)Cptr2 + (size_t)(h - 8) * 8388608;
    }

    // banded XCD mapping
    const int bandH = Mtiles >> 3;
    const int xcd = bid & 7, idx = bid >> 3;
    const int brow = (xcd * bandH + (idx % bandH)) << 8;
    const int bcol = (idx / bandH) << 8;

    const int lin0 = (wid * 2 + 0) * 1024 + lane * 16;
    const int lin1 = (wid * 2 + 1) * 1024 + lane * 16;
    const int ph0 = lin0 ^ (((lin0 >> 7) & 7) << 4);
    const int ph1v = lin1 ^ (((lin1 >> 7) & 7) << 4);
    const int srow0 = ph0 >> 7, scol0 = (ph0 & 127) >> 1;
    const int srow1 = ph1v >> 7, scol1 = (ph1v & 127) >> 1;
    const int dst0 = (wid * 2 + 0) * 1024;
    const int dst1 = (wid * 2 + 1) * 1024;

#define STAGE(t, mat, h_) do { \
        char* base_ = smem + (((t) & 1) * 65536) + ((mat) * 32768) + ((h_) * 16384); \
        const unsigned short* G_ = (mat) ? Bt : A; \
        const int ld_ = (mat) ? ldb : lda; \
        const int rb_ = ((mat) ? bcol : brow) + (h_) * 128; \
        gload16(G_ + (size_t)(rb_ + srow0) * ld_ + (t) * 64 + scol0, base_ + dst0); \
        gload16(G_ + (size_t)(rb_ + srow1) * ld_ + (t) * 64 + scol1, base_ + dst1); \
    } while (0)
#define STAGE_G(t, mat, h_) do { if ((t) < nkt) STAGE(t, mat, h_); } while (0)

#define LDA_FRAG(dst, buf, m, kk) do { \
        int lin_ = ((m) * 16 + l15) * 128 + (kk) * 64 + lhi; \
        int ph_  = lin_ ^ (((lin_ >> 7) & 7) << 4); \
        dst = *(const short8*)(smem + (buf) * 65536 + wm * 16384 + ph_); \
    } while (0)
#define LDB_FRAG(dst, buf, n, kk) do { \
        int lin_ = ((wn & 1) * 64 + (n) * 16 + l15) * 128 + (kk) * 64 + lhi; \
        int ph_  = lin_ ^ (((lin_ >> 7) & 7) << 4); \
        dst = *(const short8*)(smem + (buf) * 65536 + 32768 + (wn >> 1) * 16384 + ph_); \
    } while (0)

    f32x4 acc[8][4] = {};
    short8 afr[8][2], bfr[4][2];

#define MFMA_Q(mq) do { \
        __builtin_amdgcn_s_setprio(1); \
        _Pragma("unroll") \
        for (int n_ = 0; n_ < 4; ++n_) { \
            acc[2*(mq)][n_]   = __builtin_amdgcn_mfma_f32_16x16x32_bf16(afr[2*(mq)][0],   bfr[n_][0], acc[2*(mq)][n_],   0,0,0); \
            acc[2*(mq)][n_]   = __builtin_amdgcn_mfma_f32_16x16x32_bf16(afr[2*(mq)][1],   bfr[n_][1], acc[2*(mq)][n_],   0,0,0); \
            acc[2*(mq)+1][n_] = __builtin_amdgcn_mfma_f32_16x16x32_bf16(afr[2*(mq)+1][0], bfr[n_][0], acc[2*(mq)+1][n_], 0,0,0); \
            acc[2*(mq)+1][n_] = __builtin_amdgcn_mfma_f32_16x16x32_bf16(afr[2*(mq)+1][1], bfr[n_][1], acc[2*(mq)+1][n_], 0,0,0); \
        } \
        __builtin_amdgcn_s_setprio(0); \
    } while (0)

#define READ_B(b) do { \
        _Pragma("unroll") \
        for (int n_ = 0; n_ < 4; ++n_) { LDB_FRAG(bfr[n_][0], b, n_, 0); LDB_FRAG(bfr[n_][1], b, n_, 1); } \
    } while (0)
#define READ_QA(b, mq) do { \
        LDA_FRAG(afr[2*(mq)][0],   b, 2*(mq),   0); LDA_FRAG(afr[2*(mq)][1],   b, 2*(mq),   1); \
        LDA_FRAG(afr[2*(mq)+1][0], b, 2*(mq)+1, 0); LDA_FRAG(afr[2*(mq)+1][1], b, 2*(mq)+1, 1); \
    } while (0)

    // ---- prologue: T0 full + T1.B (12 loads) ----
    STAGE(0, 1, 0); STAGE(0, 1, 1); STAGE(0, 0, 0); STAGE(0, 0, 1);
    STAGE_G(1, 1, 0); STAGE_G(1, 1, 1);
    VMCNT4();
    BAR();

    const int niter = nkt >> 1;
    for (int it = 0; it < niter; ++it) {
        const int t0 = it * 2, t1 = t0 + 1;
        const bool lastIt = (it == niter - 1);

        READ_B(0); READ_QA(0, 0); READ_QA(0, 1);
        STAGE_G(t1, 0, 0); STAGE_G(t1, 0, 1);
        BAR();
        MFMA_Q(0); MFMA_Q(1);
        READ_QA(0, 2); READ_QA(0, 3);
        STAGE_G(t0 + 2, 1, 0); STAGE_G(t0 + 2, 1, 1);
        if (lastIt) { VMCNT0(); } else { VMCNT4(); }
        BAR();
        MFMA_Q(2); MFMA_Q(3);
        READ_B(1); READ_QA(1, 0); READ_QA(1, 1);
        STAGE_G(t0 + 2, 0, 0); STAGE_G(t0 + 2, 0, 1);
        BAR();
        MFMA_Q(0); MFMA_Q(1);
        READ_QA(1, 2); READ_QA(1, 3);
        STAGE_G(t1 + 2, 1, 0); STAGE_G(t1 + 2, 1, 1);
        if (lastIt) { VMCNT0(); } else { VMCNT4(); }
        BAR();
        MFMA_Q(2); MFMA_Q(3);
    }

    const int rl = (lane >> 4) * 4;
    const int cl = lane & 15;
    const int row0 = brow + wm * 128;

    if constexpr (EPI == 6) {
        const int col0 = bcol + wn * 64;
#pragma unroll
        for (int m = 0; m < 8; m++)
#pragma unroll
            for (int n = 0; n < 4; n++)
#pragma unroll
                for (int rg = 0; rg < 4; rg++) {
                    int gr = row0 + m * 16 + rl + rg;
                    int gc = col0 + n * 16 + cl;
                    Cq[(size_t)gr * 2048 + gc] = f2bf(acc[m][n][rg]);
                }
        return;
    }

    if constexpr (EPI == 5) {
        const int col0 = bcol + wn * 64;
        if (!sub1) {
            float lsum = 0.f;
#pragma unroll
            for (int m = 0; m < 8; m++)
#pragma unroll
                for (int n = 0; n < 4; n++)
#pragma unroll
                    for (int rg = 0; rg < 4; rg++) {
                        int gr = row0 + m * 16 + rl + rg;
                        int gc = col0 + n * 16 + cl;
                        float d = acc[m][n][rg] - aux_f32[(size_t)gr * ldc + gc];
                        lsum += d * d;
                    }
#pragma unroll
            for (int msk = 1; msk < 64; msk <<= 1)
                lsum += __shfl_xor(lsum, msk, 64);
            if (lane == 0) atomicAdd(loss_accum, lsum);
        } else {
#pragma unroll
            for (int m = 0; m < 8; m++)
#pragma unroll
                for (int n = 0; n < 4; n++)
#pragma unroll
                    for (int rg = 0; rg < 4; rg++) {
                        int gr = row0 + m * 16 + rl + rg;
                        int gc = col0 + n * 16 + cl;
                        size_t idxo = (size_t)gr * ldc + gc;
                        float gv = bf2f(aux_bf16[idxo]);
                        ((float*)Cptr)[idxo] = acc[m][n][rg] * gv;
                    }
        }
        return;
    }

    void* Ceff = Cptr;
    bool second = false;
    int bcol_l = bcol;
    if constexpr (EPI == 0 || EPI == 4) {
        if (bcol >= splitcol) { Ceff = Cptr2; bcol_l = bcol - splitcol; second = true; }
    }
    const int col0 = bcol_l + wn * 64;

#pragma unroll
    for (int m = 0; m < 8; m++)
#pragma unroll
        for (int n = 0; n < 4; n++)
#pragma unroll
            for (int rg = 0; rg < 4; rg++) {
                int gr = row0 + m * 16 + rl + rg;
                int gc = col0 + n * 16 + cl;
                size_t idxo = (size_t)gr * ldc + gc;
                if constexpr (EPI == 0) {
                    ((unsigned short*)Ceff)[idxo] = f2bf(acc[m][n][rg]);
                } else {  // EPI == 4
                    if (second) {
                        float t = acc[m][n][rg] + aux_f32[gc];
                        ((unsigned short*)Ceff)[idxo] = f2bf(1.f / (1.f + expf(-t)));
                    } else {
                        ((unsigned short*)Ceff)[idxo] = f2bf(acc[m][n][rg]);
                    }
                }
            }
#undef STAGE
#undef STAGE_G
#undef LDA_FRAG
#undef LDB_FRAG
#undef MFMA_Q
#undef READ_B
#undef READ_QA
}

// ---------- attention v2 + fused pmean (R16) ----------
// block per n (256 thr = 4 waves, wave handles 4 h). prefix[n] in LDS (32KB).
// pmean[n][c] computed from the already-staged LDS rows (bit-identical to the
// old pmean kernel: fp32 accumulate p=0..7 ascending, *0.125, RNE cast).
__global__ __launch_bounds__(256) void attn2_kernel(
        const unsigned short* __restrict__ prefix,
        unsigned short* __restrict__ qtA, unsigned short* __restrict__ qtB,
        unsigned short* __restrict__ pmean) {
    __shared__ __align__(16) unsigned short pfx[8][2048];
    const int n = blockIdx.x, tid = threadIdx.x;
    const int wid = tid >> 6, lane = tid & 63;
#pragma unroll
    for (int r = 0; r < 8; ++r)
        *(uint4*)&pfx[r][tid * 8] =
            *(const uint4*)(prefix + (size_t)n * 16384 + r * 2048 + tid * 8);
    __syncthreads();

    // fused pmean: each thread owns cols [tid*8, tid*8+8)
    {
        float pacc[8] = {0, 0, 0, 0, 0, 0, 0, 0};
#pragma unroll
        for (int p = 0; p < 8; ++p) {
            short8 pv = *(const short8*)&pfx[p][tid * 8];
#pragma unroll
            for (int j = 0; j < 8; ++j)
                pacc[j] += bf2f((unsigned short)pv[j]);
        }
        uint4 o;
        unsigned* ow = (unsigned*)&o;
#pragma unroll
        for (int j = 0; j < 4; ++j)
            ow[j] = (unsigned)f2bf(pacc[2 * j] * 0.125f) |
                    ((unsigned)f2bf(pacc[2 * j + 1] * 0.125f) << 16);
        *(uint4*)(pmean + (size_t)n * 2048 + tid * 8) = o;
    }

#pragma unroll
    for (int hh = 0; hh < 4; ++hh) {
        const int h = wid * 4 + hh;
        unsigned short* qrow = ((h < 8) ? qtA + (size_t)h * 8388608
                                        : qtB + (size_t)(h - 8) * 8388608)
                               + (size_t)n * 2048;
        short8 qv[4];
#pragma unroll
        for (int k = 0; k < 4; ++k)
            qv[k] = *(const short8*)(qrow + lane * 8 + k * 512);
        float s[8];
#pragma unroll
        for (int p = 0; p < 8; ++p) {
            float d = 0.f;
#pragma unroll
            for (int k = 0; k < 4; ++k) {
                short8 pv = *(const short8*)&pfx[p][lane * 8 + k * 512];
#pragma unroll
                for (int j = 0; j < 8; ++j)
                    d += bf2f((unsigned short)qv[k][j]) * bf2f((unsigned short)pv[j]);
            }
#pragma unroll
            for (int msk = 1; msk < 64; msk <<= 1) d += __shfl_xor(d, msk, 64);
            s[p] = d * 0.08838834764831845f;   // 1/sqrt(128)
        }
        float mx = s[0];
#pragma unroll
        for (int p = 1; p < 8; ++p) mx = fmaxf(mx, s[p]);
        float e[8], den = 0.f;
#pragma unroll
        for (int p = 0; p < 8; ++p) { e[p] = expf(s[p] - mx); den += e[p]; }
        float inv = 1.f / den;
#pragma unroll
        for (int k = 0; k < 4; ++k) {
            float wa[8] = {0, 0, 0, 0, 0, 0, 0, 0};
#pragma unroll
            for (int p = 0; p < 8; ++p) {
                float a = e[p] * inv;
                short8 pv = *(const short8*)&pfx[p][lane * 8 + k * 512];
#pragma unroll
                for (int j = 0; j < 8; ++j)
                    wa[j] += a * bf2f((unsigned short)pv[j]);
            }
            short8 ov;
#pragma unroll
            for (int j = 0; j < 8; ++j) ov[j] = (short)f2bf(wa[j]);
            *(short8*)(qrow + lane * 8 + k * 512) = ov;   // w in-place over qt
        }
    }
}

// ---------- wv GEMM: attno[n, h*128+d] = w[h][n] @ WvT rows ---------
__global__ __launch_bounds__(512) void gemmwv_kernel(
        const unsigned short* __restrict__ qtA,
        const unsigned short* __restrict__ qtB,
        const unsigned short* __restrict__ wvT,
        unsigned short* __restrict__ attno) {
    __shared__ __align__(16) unsigned short Atile[256 * 64];
    __shared__ __align__(16) unsigned short Btile[128 * 64];
    const int tid = threadIdx.x, wid = tid >> 6, lane = tid & 63;
    const int wm = wid >> 1, wn = wid & 1;
    const int l15 = lane & 15, lhi = (lane >> 4) * 16;
    const int h = blockIdx.x >> 4, mt = blockIdx.x & 15;
    const unsigned short* A = (h < 8) ? qtA + (size_t)h * 8388608
                                      : qtB + (size_t)(h - 8) * 8388608;
    const unsigned short* B = wvT + (size_t)(h * 128) * 2048;
    const int brow = mt << 8;

#define WVST(buf, c, kt, G, ld, rbase) do { \
        int linc = (c) * 8192 + wid * 1024 + lane * 16; \
        int phc = linc ^ (((linc >> 7) & 7) << 4); \
        gload16((G) + (size_t)((rbase) + (phc >> 7)) * (ld) + (kt) * 64 + ((phc & 127) >> 1), \
                (char*)(buf) + (c) * 8192 + wid * 1024); \
    } while (0)

    f32x4 acc[4][4] = {};
    for (int kt = 0; kt < 32; ++kt) {
        WVST(Atile, 0, kt, A, 2048, brow); WVST(Atile, 1, kt, A, 2048, brow);
        WVST(Atile, 2, kt, A, 2048, brow); WVST(Atile, 3, kt, A, 2048, brow);
        WVST(Btile, 0, kt, B, 2048, 0);    WVST(Btile, 1, kt, B, 2048, 0);
        VMCNT0();
        BAR();
        short8 af[4][2], bf[4][2];
#pragma unroll
        for (int m = 0; m < 4; ++m)
#pragma unroll
            for (int kk = 0; kk < 2; ++kk) {
                int lin = (wm * 64 + m * 16 + l15) * 128 + kk * 64 + lhi;
                int ph = lin ^ (((lin >> 7) & 7) << 4);
                af[m][kk] = *(const short8*)((char*)Atile + ph);
            }
#pragma unroll
        for (int nn = 0; nn < 4; ++nn)
#pragma unroll
            for (int kk = 0; kk < 2; ++kk) {
                int lin = (wn * 64 + nn * 16 + l15) * 128 + kk * 64 + lhi;
                int ph = lin ^ (((lin >> 7) & 7) << 4);
                bf[nn][kk] = *(const short8*)((char*)Btile + ph);
            }
        __builtin_amdgcn_s_setprio(1);
#pragma unroll
        for (int m = 0; m < 4; ++m)
#pragma unroll
            for (int nn = 0; nn < 4; ++nn) {
                acc[m][nn] = __builtin_amdgcn_mfma_f32_16x16x32_bf16(af[m][0], bf[nn][0], acc[m][nn], 0, 0, 0);
                acc[m][nn] = __builtin_amdgcn_mfma_f32_16x16x32_bf16(af[m][1], bf[nn][1], acc[m][nn], 0, 0, 0);
            }
        __builtin_amdgcn_s_setprio(0);
        BAR();   // all reads retired before next stage overwrites
    }
    const int rl = (lane >> 4) * 4, cl = lane & 15;
#pragma unroll
    for (int m = 0; m < 4; ++m)
#pragma unroll
        for (int nn = 0; nn < 4; ++nn)
#pragma unroll
            for (int rg = 0; rg < 4; ++rg) {
                int gr = brow + wm * 64 + m * 16 + rl + rg;
                int gc = h * 128 + wn * 64 + nn * 16 + cl;
                attno[(size_t)gr * 2048 + gc] = f2bf(acc[m][nn][rg]);
            }
#undef WVST
}

__global__ __launch_bounds__(64) void finalize_loss_kernel(
        const float* __restrict__ accum, float* __restrict__ dst) {
    if (threadIdx.x == 0) dst[0] = accum[0] * (1.0f / (4096.0f * 2048.0f));
}

// ---------- launch ----------
extern "C" void kernel_launch(void* const* d_in, const int* in_sizes, int n_in,
                              void* d_out, int out_size, void* d_ws, size_t ws_size,
                              hipStream_t stream) {
    const float* x    = (const float*)d_in[0];
    const float* rwkv = (const float*)d_in[1];
    const float* Wq   = (const float*)d_in[2];
    const float* Wk   = (const float*)d_in[3];
    const float* Wv   = (const float*)d_in[4];
    const float* Wo   = (const float*)d_in[5];
    const float* Wg   = (const float*)d_in[6];
    const float* bg   = (const float*)d_in[7];
    const float* Wb   = (const float*)d_in[8];
    const float* Wr   = (const float*)d_in[9];
    float* out = (float*)d_out;
    char*  ws  = (char*)d_ws;

    unsigned short* xs     = (unsigned short*)(ws + 0ull);
    unsigned short* wbT    = (unsigned short*)(ws + 33554432ull);    // dead after bridge
    unsigned short* qtA    = (unsigned short*)(ws + 33554432ull);    // 128MB (h 0-7)
    unsigned short* wqT    = (unsigned short*)(ws + 167772160ull);
    unsigned short* wgT    = (unsigned short*)(ws + 176160768ull);
    unsigned short* wkC    = (unsigned short*)(ws + 184549376ull);   // Wk cast (no T)
    unsigned short* wvT    = (unsigned short*)(ws + 192937984ull);
    unsigned short* wrT    = (unsigned short*)(ws + 201326592ull);
    unsigned short* woT    = (unsigned short*)(ws + 209715200ull);
    unsigned short* prefix = (unsigned short*)(ws + 218103808ull);   // 128MB
    unsigned short* qtB    = (unsigned short*)(ws + 352321536ull);   // 128MB (h 8-15)
    unsigned short* qbuf   = (unsigned short*)(ws + 486539264ull);
    unsigned short* gbuf   = (unsigned short*)(ws + 503316480ull);
    unsigned short* pmean  = (unsigned short*)(ws + 520093696ull);
    unsigned short* attno  = (unsigned short*)(ws + 536870912ull);
    float*          lossA  = (float*)(ws + 553648128ull);

    const int SMEM = 131072;
    const int BIG = 1 << 30;
    hipFuncSetAttribute(reinterpret_cast<const void*>(gemm256<0>),
                        hipFuncAttributeMaxDynamicSharedMemorySize, SMEM);
    hipFuncSetAttribute(reinterpret_cast<const void*>(gemm256<4>),
                        hipFuncAttributeMaxDynamicSharedMemorySize, SMEM);
    hipFuncSetAttribute(reinterpret_cast<const void*>(gemm256<5>),
                        hipFuncAttributeMaxDynamicSharedMemorySize, SMEM);
    hipFuncSetAttribute(reinterpret_cast<const void*>(gemm256<6>),
                        hipFuncAttributeMaxDynamicSharedMemorySize, SMEM);

    hipMemsetAsync(lossA, 0, 16, stream);

    // prep: pack_xs + WbT + {Wq,Wg,Wv,Wr,Wo} transposes + Wk cast
    prep_kernel<<<106496, 256, 0, stream>>>(
        x, rwkv, xs, Wb, wbT,
        Wq, Wg, Wv, Wr, Wo, wqT, wgT, wvT, wrT, woT, Wk, wkC);

    // prefix = xs @ Wb          M=4096 N=16384 K=4096
    gemm256<0><<<dim3(1024), 512, SMEM, stream>>>(xs, 4096, wbT, 4096,
        prefix, nullptr, 16384, BIG, 4096, 16, nullptr, nullptr, nullptr,
        nullptr, nullptr);
    // [q|g] = x @ [Wq|Wg]       M=4096 N=4096 K=2048, split @2048
    gemm256<4><<<dim3(256), 512, SMEM, stream>>>(xs, 4096, wqT, 2048,
        qbuf, gbuf, 2048, 2048, 2048, 16, bg, nullptr, nullptr,
        nullptr, nullptr);
    // qt[h] = q_h @ Wk_h^T      per h: M=4096 N=2048 K=128
    gemm256<6><<<dim3(2048), 512, SMEM, stream>>>(qbuf, 2048, wkC, 2048,
        qtA, qtB, 2048, BIG, 128, 16, nullptr, nullptr, nullptr,
        nullptr, nullptr);
    // attention + fused pmean: scores = qt.prefix, softmax, w in-place, pmean
    attn2_kernel<<<4096, 256, 0, stream>>>(prefix, qtA, qtB, pmean);
    // attno[n, hs] = w[h][n] @ Wv[:, hs]
    gemmwv_kernel<<<256, 512, 0, stream>>>(qtA, qtB, wvT, attno);
    // TAIL: blocks 0-127: loss; blocks 128-255: out = (attno@Wo)*g
    gemm256<5><<<dim3(256), 512, SMEM, stream>>>(pmean, 2048, wrT, 2048,
        out, nullptr, 2048, BIG, 2048, 16, x, gbuf, lossA,
        attno, woT);

    finalize_loss_kernel<<<1, 64, 0, stream>>>(lossA, out + 8388608);
}